// Round 1
// baseline (1453.675 us; speedup 1.0000x reference)
//
#include <hip/hip_runtime.h>
#include <math.h>

// ---------------------------------------------------------------------------
// Net_1503238553644: 2-layer ChebConv(K=2) GNN + linear skips + edge recon loss
// Sizes: N=13627 nodes, E=504378 edges, F=64, H1=300, H2=100, LIN=100
// Outputs (concat): out (N), r_loss (1), c1 (1), c2 (1)
// ---------------------------------------------------------------------------

// deg[src[e]] += 1   (out-degree by src)
__global__ void deg_kernel(const int* __restrict__ src, float* __restrict__ deg, int E) {
    int stride = gridDim.x * blockDim.x;
    for (int e = blockIdx.x * blockDim.x + threadIdx.x; e < E; e += stride)
        atomicAdd(&deg[src[e]], 1.0f);
}

// deg -> dinv in place: deg>0 ? 1/sqrt(max(deg,1)) : 0
__global__ void dinv_kernel(float* __restrict__ deg, int n) {
    int i = blockIdx.x * blockDim.x + threadIdx.x;
    if (i < n) {
        float d = deg[i];
        deg[i] = (d > 0.0f) ? (1.0f / sqrtf(fmaxf(d, 1.0f))) : 0.0f;
    }
}

// norm[e] = -dinv[src[e]] * dinv[dst[e]]
__global__ void norm_kernel(const int* __restrict__ ei, const float* __restrict__ dinv,
                            float* __restrict__ norm, int E) {
    int e = blockIdx.x * blockDim.x + threadIdx.x;
    if (e < E)
        norm[e] = -dinv[ei[e]] * dinv[ei[E + e]];
}

// out[dst[e], :] += norm[e] * x[src[e], :]   — one wave (64 lanes) per edge
__global__ void segsum_kernel(const float* __restrict__ x, const int* __restrict__ ei,
                              const float* __restrict__ norm, float* __restrict__ out,
                              int E, int W) {
    int wave = (blockIdx.x * blockDim.x + threadIdx.x) >> 6;
    int lane = threadIdx.x & 63;
    if (wave >= E) return;
    int s = ei[wave];
    int d = ei[E + wave];
    float nv = norm[wave];
    const float* xr = x + (size_t)s * W;
    float* orow = out + (size_t)d * W;
    for (int f = lane; f < W; f += 64)
        atomicAdd(&orow[f], nv * xr[f]);
}

// C[i,:] = f( A[i,:]@W0 (+ T[i,:]@W1w) + bias )   one block per row i
// mode 0: none; mode 1: relu; mode 2: C = addin + relu(gemm)
__global__ void gemm_kernel(const float* __restrict__ A, const float* __restrict__ T,
                            const float* __restrict__ W0, const float* __restrict__ W1w,
                            const float* __restrict__ bias, const float* __restrict__ addin,
                            float* __restrict__ C, int K, int M, int mode) {
    extern __shared__ float sA[];  // K floats (2K if T)
    const int i = blockIdx.y;
    for (int k = threadIdx.x; k < K; k += blockDim.x) {
        sA[k] = A[(size_t)i * K + k];
        if (T) sA[K + k] = T[(size_t)i * K + k];
    }
    __syncthreads();
    int j = blockIdx.x * blockDim.x + threadIdx.x;
    if (j >= M) return;
    float acc = bias[j];
    if (T) {
#pragma unroll 4
        for (int k = 0; k < K; ++k)
            acc += sA[k] * W0[(size_t)k * M + j] + sA[K + k] * W1w[(size_t)k * M + j];
    } else {
#pragma unroll 4
        for (int k = 0; k < K; ++k)
            acc += sA[k] * W0[(size_t)k * M + j];
    }
    float outv;
    if (mode == 2)      outv = addin[(size_t)i * M + j] + fmaxf(acc, 0.0f);
    else if (mode == 1) outv = fmaxf(acc, 0.0f);
    else                outv = acc;
    C[(size_t)i * M + j] = outv;
}

// accumulate sum of log(sigmoid(dot)) (mode 0) / log(1-sigmoid(dot)) (mode 1)
__global__ void edge_loss_kernel(const float* __restrict__ z, const int* __restrict__ ei,
                                 int E, int mode, float* __restrict__ acc) {
    float sum = 0.0f;
    int stride = gridDim.x * blockDim.x;
    for (int e = blockIdx.x * blockDim.x + threadIdx.x; e < E; e += stride) {
        int a = ei[e];
        int b = ei[E + e];
        const float4* za = (const float4*)(z + (size_t)a * 100);
        const float4* zb = (const float4*)(z + (size_t)b * 100);
        float dot = 0.0f;
#pragma unroll
        for (int q = 0; q < 25; ++q) {
            float4 va = za[q], vb = zb[q];
            dot += va.x * vb.x + va.y * vb.y + va.z * vb.z + va.w * vb.w;
        }
        float sg = 1.0f / (1.0f + expf(-dot));
        sum += mode ? logf(1.0f - sg + 1e-15f) : logf(sg + 1e-15f);
    }
    __shared__ float red[256];
    red[threadIdx.x] = sum;
    __syncthreads();
    for (int s = 128; s > 0; s >>= 1) {
        if (threadIdx.x < s) red[threadIdx.x] += red[threadIdx.x + s];
        __syncthreads();
    }
    if (threadIdx.x == 0) atomicAdd(&acc[mode], red[0]);
}

// out[i] = xo[i,:]@W3[0] + txo[i,:]@W3[1] + b3
__global__ void final_kernel(const float* __restrict__ xo, const float* __restrict__ txo,
                             const float* __restrict__ W3, const float* __restrict__ b3,
                             float* __restrict__ out, int Nn) {
    int i = blockIdx.x * blockDim.x + threadIdx.x;
    if (i >= Nn) return;
    const float4* a  = (const float4*)(xo + (size_t)i * 100);
    const float4* t  = (const float4*)(txo + (size_t)i * 100);
    const float4* w0 = (const float4*)(W3);
    const float4* w1 = (const float4*)(W3 + 100);
    float acc = b3[0];
#pragma unroll
    for (int q = 0; q < 25; ++q) {
        float4 va = a[q], vw0 = w0[q];
        float4 vt = t[q], vw1 = w1[q];
        acc += va.x * vw0.x + va.y * vw0.y + va.z * vw0.z + va.w * vw0.w;
        acc += vt.x * vw1.x + vt.y * vw1.y + vt.z * vw1.z + vt.w * vw1.w;
    }
    out[i] = acc;
}

__global__ void finalize_kernel(float* __restrict__ out, const float* __restrict__ acc,
                                const float* __restrict__ c1, const float* __restrict__ c2,
                                int Nn, int E) {
    out[Nn]     = -(acc[0] + acc[1]) / (float)E;
    out[Nn + 1] = c1[0];
    out[Nn + 2] = c2[0];
}

extern "C" void kernel_launch(void* const* d_in, const int* in_sizes, int n_in,
                              void* d_out, int out_size, void* d_ws, size_t ws_size,
                              hipStream_t stream) {
    (void)n_in; (void)out_size; (void)ws_size;
    const float* x   = (const float*)d_in[0];
    const int*   ei  = (const int*)d_in[1];
    const int*   nei = (const int*)d_in[2];
    const float* W1  = (const float*)d_in[3];
    const float* b1  = (const float*)d_in[4];
    const float* W2  = (const float*)d_in[5];
    const float* b2  = (const float*)d_in[6];
    const float* W3  = (const float*)d_in[7];
    const float* b3  = (const float*)d_in[8];
    const float* lw1 = (const float*)d_in[9];
    const float* lb1 = (const float*)d_in[10];
    const float* lw2 = (const float*)d_in[11];
    const float* lb2 = (const float*)d_in[12];
    const float* c1  = (const float*)d_in[13];
    const float* c2  = (const float*)d_in[14];

    const int Nn = in_sizes[0] / 64;   // 13627
    const int E  = in_sizes[1] / 2;    // 504378

    // workspace layout (floats, all offsets multiple of 4 for float4 use)
    float* ws   = (float*)d_ws;
    float* dinv = ws;                              // N (deg -> dinv in place)
    float* norm = dinv + ((Nn + 3) & ~3);          // E
    float* TX   = norm + ((E + 3) & ~3);           // N*300 (reused: tx64 / tx300 / tx100)
    float* h    = TX + (size_t)Nn * 300;           // N*300
    float* x1   = h  + (size_t)Nn * 300;           // N*100
    float* xo   = x1 + (size_t)Nn * 100;           // N*100
    float* z    = xo + (size_t)Nn * 100;           // N*100
    float* acc  = z  + (size_t)Nn * 100;           // 2

    // --- norm ---
    hipMemsetAsync(dinv, 0, (size_t)Nn * sizeof(float), stream);
    hipMemsetAsync(acc, 0, 2 * sizeof(float), stream);
    deg_kernel<<<1024, 256, 0, stream>>>(ei, dinv, E);
    dinv_kernel<<<(Nn + 255) / 256, 256, 0, stream>>>(dinv, Nn);
    norm_kernel<<<(E + 255) / 256, 256, 0, stream>>>(ei, dinv, norm, E);

    // --- conv1: h = relu(x@W1[0] + segsum(norm*x[src],dst)@W1[1] + b1) ---
    hipMemsetAsync(TX, 0, (size_t)Nn * 64 * sizeof(float), stream);
    segsum_kernel<<<(E + 3) / 4, 256, 0, stream>>>(x, ei, norm, TX, E, 64);
    gemm_kernel<<<dim3(2, Nn), 192, 2 * 64 * sizeof(float), stream>>>(
        x, TX, W1, W1 + 64 * 300, b1, nullptr, h, 64, 300, 1);

    // --- conv2: x1 = relu(h@W2[0] + segsum(norm*h[src],dst)@W2[1] + b2) ---
    hipMemsetAsync(TX, 0, (size_t)Nn * 300 * sizeof(float), stream);
    segsum_kernel<<<(E + 3) / 4, 256, 0, stream>>>(h, ei, norm, TX, E, 300);
    gemm_kernel<<<dim3(1, Nn), 128, 2 * 300 * sizeof(float), stream>>>(
        h, TX, W2, W2 + 300 * 100, b2, nullptr, x1, 300, 100, 1);

    // --- linear skips: xo = x1 + relu(x@lw1+lb1); z = x1 + relu(x@lw2+lb2) ---
    gemm_kernel<<<dim3(1, Nn), 128, 64 * sizeof(float), stream>>>(
        x, nullptr, lw1, nullptr, lb1, x1, xo, 64, 100, 2);
    gemm_kernel<<<dim3(1, Nn), 128, 64 * sizeof(float), stream>>>(
        x, nullptr, lw2, nullptr, lb2, x1, z, 64, 100, 2);

    // --- edge reconstruction losses on z ---
    edge_loss_kernel<<<2048, 256, 0, stream>>>(z, ei, E, 0, acc);
    edge_loss_kernel<<<2048, 256, 0, stream>>>(z, nei, E, 1, acc);

    // --- conv3 (width 1): out = xo@W3[0] + segsum(norm*xo[src],dst)@W3[1] + b3 ---
    hipMemsetAsync(TX, 0, (size_t)Nn * 100 * sizeof(float), stream);
    segsum_kernel<<<(E + 3) / 4, 256, 0, stream>>>(xo, ei, norm, TX, E, 100);
    final_kernel<<<(Nn + 255) / 256, 256, 0, stream>>>(xo, TX, W3, b3, (float*)d_out, Nn);

    finalize_kernel<<<1, 1, 0, stream>>>((float*)d_out, acc, c1, c2, Nn, E);
}

// Round 2
// 743.256 us; speedup vs baseline: 1.9558x; 1.9558x over previous
//
#include <hip/hip_runtime.h>
#include <math.h>

// ---------------------------------------------------------------------------
// Net_1503238553644: 2-layer ChebConv(K=2) GNN + linear skips + edge recon loss
// N=13627, E=504378, F=64, H1=300, H2=100, LIN=100
// R2: linearity transform (GEMM before scatter: widths 64/100/1 instead of
//     64/300/100) + per-call CSR build -> gather segsum, zero f32 atomics.
// ---------------------------------------------------------------------------

// deg[src[e]] += 1 (float, by src) ; cnt[dst[e]+1] += 1 (int, CSR histogram)
__global__ void deg_hist_kernel(const int* __restrict__ ei, float* __restrict__ deg,
                                int* __restrict__ cnt, int E) {
    int stride = gridDim.x * blockDim.x;
    for (int e = blockIdx.x * blockDim.x + threadIdx.x; e < E; e += stride) {
        atomicAdd(&deg[ei[e]], 1.0f);
        atomicAdd(&cnt[ei[E + e] + 1], 1);
    }
}

__global__ void dinv_kernel(float* __restrict__ deg, int n) {
    int i = blockIdx.x * blockDim.x + threadIdx.x;
    if (i < n) {
        float d = deg[i];
        deg[i] = (d > 0.0f) ? (1.0f / sqrtf(fmaxf(d, 1.0f))) : 0.0f;
    }
}

// single-block exclusive scan: rowptr[i+1] := sum of counts[0..i]; rowptr[0]=0
__global__ void scan_kernel(int* __restrict__ rowptr, int n) {
    __shared__ int sums[1024];
    __shared__ int carry;
    if (threadIdx.x == 0) carry = 0;
    __syncthreads();
    int chunks = (n + 1023) / 1024;
    for (int c = 0; c < chunks; ++c) {
        int i = c * 1024 + threadIdx.x;
        int v = (i < n) ? rowptr[i + 1] : 0;
        sums[threadIdx.x] = v;
        __syncthreads();
        for (int off = 1; off < 1024; off <<= 1) {
            int t = (threadIdx.x >= off) ? sums[threadIdx.x - off] : 0;
            __syncthreads();
            sums[threadIdx.x] += t;
            __syncthreads();
        }
        int inc = sums[threadIdx.x] + carry;
        if (i < n) rowptr[i + 1] = inc;
        __syncthreads();
        if (threadIdx.x == 1023) carry = inc;
        __syncthreads();
    }
}

__global__ void cursor_kernel(const int* __restrict__ rowptr, int* __restrict__ cursor, int n) {
    int i = blockIdx.x * blockDim.x + threadIdx.x;
    if (i < n) cursor[i] = rowptr[i];
}

// scatter edges into dst-sorted CSR slots; wnorm = -dinv[src]*dinv[dst]
__global__ void fill_kernel(const int* __restrict__ ei, const float* __restrict__ dinv,
                            int* __restrict__ cursor, int* __restrict__ colidx,
                            float* __restrict__ wnorm, int E) {
    int stride = gridDim.x * blockDim.x;
    for (int e = blockIdx.x * blockDim.x + threadIdx.x; e < E; e += stride) {
        int s = ei[e];
        int d = ei[E + e];
        int slot = atomicAdd(&cursor[d], 1);
        colidx[slot] = s;
        wnorm[slot] = -dinv[s] * dinv[d];
    }
}

// out[node,lane] = sum_j wnorm[j] * x[colidx[j], lane]  — one wave per node, W=64
__global__ void csr_segsum64_kernel(const float* __restrict__ x, const int* __restrict__ rowptr,
                                    const int* __restrict__ colidx, const float* __restrict__ wnorm,
                                    float* __restrict__ out, int n) {
    int node = (blockIdx.x * blockDim.x + threadIdx.x) >> 6;
    int lane = threadIdx.x & 63;
    if (node >= n) return;
    int j0 = rowptr[node], j1 = rowptr[node + 1];
    float a = 0.0f;
    for (int j = j0; j < j1; ++j)
        a += wnorm[j] * x[(size_t)colidx[j] * 64 + lane];
    out[(size_t)node * 64 + lane] = a;
}

// one block (128 thr) per node, f<100
__global__ void csr_segsum100_kernel(const float* __restrict__ x, const int* __restrict__ rowptr,
                                     const int* __restrict__ colidx, const float* __restrict__ wnorm,
                                     float* __restrict__ out, int n) {
    int node = blockIdx.x;
    int f = threadIdx.x;
    if (f >= 100) return;
    int j0 = rowptr[node], j1 = rowptr[node + 1];
    float a = 0.0f;
    for (int j = j0; j < j1; ++j)
        a += wnorm[j] * x[(size_t)colidx[j] * 100 + f];
    out[(size_t)node * 100 + f] = a;
}

// C[i,:] = f( A[i,:]@W0 (+ T[i,:]@W1w) + bias )   one block-row per node
// mode 0: none; 1: relu; 2: C = addin + relu(gemm); 3: C = relu(gemm + addin)
__global__ void gemm_kernel(const float* __restrict__ A, const float* __restrict__ T,
                            const float* __restrict__ W0, const float* __restrict__ W1w,
                            const float* __restrict__ bias, const float* __restrict__ addin,
                            float* __restrict__ C, int K, int M, int mode) {
    extern __shared__ float sA[];
    const int i = blockIdx.y;
    for (int k = threadIdx.x; k < K; k += blockDim.x) {
        sA[k] = A[(size_t)i * K + k];
        if (T) sA[K + k] = T[(size_t)i * K + k];
    }
    __syncthreads();
    int j = blockIdx.x * blockDim.x + threadIdx.x;
    if (j >= M) return;
    float acc = bias ? bias[j] : 0.0f;
    if (T) {
#pragma unroll 4
        for (int k = 0; k < K; ++k)
            acc += sA[k] * W0[(size_t)k * M + j] + sA[K + k] * W1w[(size_t)k * M + j];
    } else {
#pragma unroll 4
        for (int k = 0; k < K; ++k)
            acc += sA[k] * W0[(size_t)k * M + j];
    }
    float outv;
    if (mode == 3)      outv = fmaxf(acc + addin[(size_t)i * M + j], 0.0f);
    else if (mode == 2) outv = addin[(size_t)i * M + j] + fmaxf(acc, 0.0f);
    else if (mode == 1) outv = fmaxf(acc, 0.0f);
    else                outv = acc;
    C[(size_t)i * M + j] = outv;
}

// accumulate sum of log(sigmoid(dot)) (mode 0) / log(1-sigmoid(dot)) (mode 1)
__global__ void edge_loss_kernel(const float* __restrict__ z, const int* __restrict__ ei,
                                 int E, int mode, float* __restrict__ acc) {
    float sum = 0.0f;
    int stride = gridDim.x * blockDim.x;
    for (int e = blockIdx.x * blockDim.x + threadIdx.x; e < E; e += stride) {
        int a = ei[e];
        int b = ei[E + e];
        const float4* za = (const float4*)(z + (size_t)a * 100);
        const float4* zb = (const float4*)(z + (size_t)b * 100);
        float dot = 0.0f;
#pragma unroll
        for (int q = 0; q < 25; ++q) {
            float4 va = za[q], vb = zb[q];
            dot += va.x * vb.x + va.y * vb.y + va.z * vb.z + va.w * vb.w;
        }
        float sg = 1.0f / (1.0f + expf(-dot));
        sum += mode ? logf(1.0f - sg + 1e-15f) : logf(sg + 1e-15f);
    }
    __shared__ float red[256];
    red[threadIdx.x] = sum;
    __syncthreads();
    for (int s = 128; s > 0; s >>= 1) {
        if (threadIdx.x < s) red[threadIdx.x] += red[threadIdx.x + s];
        __syncthreads();
    }
    if (threadIdx.x == 0) atomicAdd(&acc[mode], red[0]);
}

// s[i] = xo[i,:] @ w (100-dim dot)
__global__ void rowdot_kernel(const float* __restrict__ xo, const float* __restrict__ w,
                              float* __restrict__ s, int n) {
    int i = blockIdx.x * blockDim.x + threadIdx.x;
    if (i >= n) return;
    const float4* a = (const float4*)(xo + (size_t)i * 100);
    const float4* wv = (const float4*)w;
    float acc = 0.0f;
#pragma unroll
    for (int q = 0; q < 25; ++q) {
        float4 va = a[q], vw = wv[q];
        acc += va.x * vw.x + va.y * vw.y + va.z * vw.z + va.w * vw.w;
    }
    s[i] = acc;
}

// out[i] = xo[i,:]@W3[0] + b3 + sum_j wnorm[j]*s[colidx[j]]
__global__ void out_kernel(const float* __restrict__ xo, const float* __restrict__ W3,
                           const float* __restrict__ b3, const int* __restrict__ rowptr,
                           const int* __restrict__ colidx, const float* __restrict__ wnorm,
                           const float* __restrict__ s, float* __restrict__ out, int n) {
    int i = blockIdx.x * blockDim.x + threadIdx.x;
    if (i >= n) return;
    const float4* a = (const float4*)(xo + (size_t)i * 100);
    const float4* wv = (const float4*)W3;
    float acc = b3[0];
#pragma unroll
    for (int q = 0; q < 25; ++q) {
        float4 va = a[q], vw = wv[q];
        acc += va.x * vw.x + va.y * vw.y + va.z * vw.z + va.w * vw.w;
    }
    int j1 = rowptr[i + 1];
    for (int j = rowptr[i]; j < j1; ++j)
        acc += wnorm[j] * s[colidx[j]];
    out[i] = acc;
}

__global__ void finalize_kernel(float* __restrict__ out, const float* __restrict__ acc,
                                const float* __restrict__ c1, const float* __restrict__ c2,
                                int Nn, int E) {
    out[Nn]     = -(acc[0] + acc[1]) / (float)E;
    out[Nn + 1] = c1[0];
    out[Nn + 2] = c2[0];
}

extern "C" void kernel_launch(void* const* d_in, const int* in_sizes, int n_in,
                              void* d_out, int out_size, void* d_ws, size_t ws_size,
                              hipStream_t stream) {
    (void)n_in; (void)out_size; (void)ws_size;
    const float* x   = (const float*)d_in[0];
    const int*   ei  = (const int*)d_in[1];
    const int*   nei = (const int*)d_in[2];
    const float* W1  = (const float*)d_in[3];
    const float* b1  = (const float*)d_in[4];
    const float* W2  = (const float*)d_in[5];
    const float* b2  = (const float*)d_in[6];
    const float* W3  = (const float*)d_in[7];
    const float* b3  = (const float*)d_in[8];
    const float* lw1 = (const float*)d_in[9];
    const float* lb1 = (const float*)d_in[10];
    const float* lw2 = (const float*)d_in[11];
    const float* lb2 = (const float*)d_in[12];
    const float* c1  = (const float*)d_in[13];
    const float* c2  = (const float*)d_in[14];

    const int Nn = in_sizes[0] / 64;   // 13627
    const int E  = in_sizes[1] / 2;    // 504378

    const size_t Nal = ((size_t)Nn + 4) & ~(size_t)3;   // room for N+1 ints, 16B aligned
    const size_t Eal = ((size_t)E + 3) & ~(size_t)3;

    float* ws     = (float*)d_ws;
    float* dinv   = ws;                          // N floats
    int*   rowptr = (int*)(dinv + Nal);          // N+1 ints
    int*   cursor = rowptr + Nal;                // N ints
    int*   colidx = cursor + Nal;                // E ints
    float* wnorm  = (float*)(colidx + Eal);      // E floats
    float* TX     = wnorm + Eal;                 // N*100 (reused: w64 then w100)
    float* h      = TX + (size_t)Nn * 100;       // N*300
    float* hW     = h  + (size_t)Nn * 300;       // N*100
    float* x1     = hW + (size_t)Nn * 100;       // N*100
    float* xo     = x1 + (size_t)Nn * 100;       // N*100
    float* z      = xo + (size_t)Nn * 100;       // N*100
    float* sv     = z  + (size_t)Nn * 100;       // N
    float* acc    = sv + Nal;                    // 2

    // --- norm + CSR build ---
    hipMemsetAsync(dinv, 0, (size_t)Nn * sizeof(float), stream);
    hipMemsetAsync(rowptr, 0, (size_t)(Nn + 1) * sizeof(int), stream);
    hipMemsetAsync(acc, 0, 2 * sizeof(float), stream);
    deg_hist_kernel<<<1024, 256, 0, stream>>>(ei, dinv, rowptr, E);
    dinv_kernel<<<(Nn + 255) / 256, 256, 0, stream>>>(dinv, Nn);
    scan_kernel<<<1, 1024, 0, stream>>>(rowptr, Nn);
    cursor_kernel<<<(Nn + 255) / 256, 256, 0, stream>>>(rowptr, cursor, Nn);
    fill_kernel<<<1024, 256, 0, stream>>>(ei, dinv, cursor, colidx, wnorm, E);

    // --- conv1: h = relu(x@W1[0] + segsum(x)@W1[1] + b1), scatter width 64 ---
    csr_segsum64_kernel<<<(Nn + 3) / 4, 256, 0, stream>>>(x, rowptr, colidx, wnorm, TX, Nn);
    gemm_kernel<<<dim3(2, Nn), 192, 2 * 64 * sizeof(float), stream>>>(
        x, TX, W1, W1 + 64 * 300, b1, nullptr, h, 64, 300, 1);

    // --- conv2 (linearity): hW = h@W2[1]; t = segsum(hW) width 100;
    //     x1 = relu(h@W2[0] + t + b2) ---
    gemm_kernel<<<dim3(1, Nn), 128, 300 * sizeof(float), stream>>>(
        h, nullptr, W2 + 300 * 100, nullptr, nullptr, nullptr, hW, 300, 100, 0);
    csr_segsum100_kernel<<<Nn, 128, 0, stream>>>(hW, rowptr, colidx, wnorm, TX, Nn);
    gemm_kernel<<<dim3(1, Nn), 128, 300 * sizeof(float), stream>>>(
        h, nullptr, W2, nullptr, b2, TX, x1, 300, 100, 3);

    // --- linear skips: xo = x1 + relu(x@lw1+lb1); z = x1 + relu(x@lw2+lb2) ---
    gemm_kernel<<<dim3(1, Nn), 128, 64 * sizeof(float), stream>>>(
        x, nullptr, lw1, nullptr, lb1, x1, xo, 64, 100, 2);
    gemm_kernel<<<dim3(1, Nn), 128, 64 * sizeof(float), stream>>>(
        x, nullptr, lw2, nullptr, lb2, x1, z, 64, 100, 2);

    // --- edge reconstruction losses on z ---
    edge_loss_kernel<<<2048, 256, 0, stream>>>(z, ei, E, 0, acc);
    edge_loss_kernel<<<2048, 256, 0, stream>>>(z, nei, E, 1, acc);

    // --- conv3 (linearity, width 1): sv = xo@W3[1]; out = xo@W3[0] + segsum(sv) + b3 ---
    rowdot_kernel<<<(Nn + 255) / 256, 256, 0, stream>>>(xo, W3 + 100, sv, Nn);
    out_kernel<<<(Nn + 255) / 256, 256, 0, stream>>>(xo, W3, b3, rowptr, colidx, wnorm,
                                                     sv, (float*)d_out, Nn);

    finalize_kernel<<<1, 1, 0, stream>>>((float*)d_out, acc, c1, c2, Nn, E);
}

// Round 3
// 519.849 us; speedup vs baseline: 2.7963x; 1.4298x over previous
//
#include <hip/hip_runtime.h>
#include <math.h>

// ---------------------------------------------------------------------------
// Net_1503238553644: 2-layer ChebConv(K=2) GNN + linear skips + edge recon loss
// N=13627, E=504378, F=64, H1=300, H2=100, LIN=100
// R3: register-blocked tiled GEMM (64x64x32, 4x4 micro) + GEMM fusion via
//     column-concat B-split; fused pos/neg edge loss; shuffle scan.
// ---------------------------------------------------------------------------

#define BM 64
#define BN 64
#define BK 32
#define BMp 68
#define BNp 68

// deg[src[e]] += 1 (float); cnt[dst[e]+1] += 1 (CSR histogram)
__global__ void deg_hist_kernel(const int* __restrict__ ei, float* __restrict__ deg,
                                int* __restrict__ cnt, int E) {
    int stride = gridDim.x * blockDim.x;
    for (int e = blockIdx.x * blockDim.x + threadIdx.x; e < E; e += stride) {
        atomicAdd(&deg[ei[e]], 1.0f);
        atomicAdd(&cnt[ei[E + e] + 1], 1);
    }
}

__global__ void dinv_kernel(float* __restrict__ deg, int n) {
    int i = blockIdx.x * blockDim.x + threadIdx.x;
    if (i < n) {
        float d = deg[i];
        deg[i] = (d > 0.0f) ? (1.0f / sqrtf(fmaxf(d, 1.0f))) : 0.0f;
    }
}

// single-block scan: rowptr[i+1] = inclusive sum; cursor[i] = exclusive sum
__global__ void scan_kernel(int* __restrict__ rowptr, int* __restrict__ cursor, int n) {
    __shared__ int wsum[16];
    __shared__ int carry_s;
    if (threadIdx.x == 0) carry_s = 0;
    __syncthreads();
    int nchunk = (n + 1023) / 1024;
    int wid = threadIdx.x >> 6, lane = threadIdx.x & 63;
    for (int c = 0; c < nchunk; ++c) {
        int i = c * 1024 + threadIdx.x;
        int v = (i < n) ? rowptr[i + 1] : 0;
        int s = v;
        for (int off = 1; off < 64; off <<= 1) {
            int t = __shfl_up(s, off, 64);
            if (lane >= off) s += t;
        }
        if (lane == 63) wsum[wid] = s;
        __syncthreads();
        if (wid == 0 && lane < 16) {
            int wsv = wsum[lane];
            for (int off = 1; off < 16; off <<= 1) {
                int t = __shfl_up(wsv, off, 64);
                if (lane >= off) wsv += t;
            }
            wsum[lane] = wsv;
        }
        __syncthreads();
        int base = carry_s + (wid > 0 ? wsum[wid - 1] : 0);
        int inc = base + s;
        if (i < n) { rowptr[i + 1] = inc; cursor[i] = inc - v; }
        __syncthreads();
        if (threadIdx.x == 1023) carry_s = inc;
        __syncthreads();
    }
}

// scatter edges into dst-sorted CSR slots; wnorm = -dinv[src]*dinv[dst]
__global__ void fill_kernel(const int* __restrict__ ei, const float* __restrict__ dinv,
                            int* __restrict__ cursor, int* __restrict__ colidx,
                            float* __restrict__ wnorm, int E) {
    int stride = gridDim.x * blockDim.x;
    for (int e = blockIdx.x * blockDim.x + threadIdx.x; e < E; e += stride) {
        int s = ei[e];
        int d = ei[E + e];
        int slot = atomicAdd(&cursor[d], 1);
        colidx[slot] = s;
        wnorm[slot] = -dinv[s] * dinv[d];
    }
}

// XT[node] = [ x[node] (64) | segsum64(x)[node] (64) ]  — one wave per node
__global__ void xt_kernel(const float* __restrict__ x, const int* __restrict__ rowptr,
                          const int* __restrict__ colidx, const float* __restrict__ wnorm,
                          float* __restrict__ XT, int n) {
    int node = (blockIdx.x * blockDim.x + threadIdx.x) >> 6;
    int lane = threadIdx.x & 63;
    if (node >= n) return;
    int j0 = rowptr[node], j1 = rowptr[node + 1];
    float a = 0.0f;
    for (int j = j0; j < j1; ++j)
        a += wnorm[j] * x[(size_t)colidx[j] * 64 + lane];
    XT[(size_t)node * 128 + lane] = x[(size_t)node * 64 + lane];
    XT[(size_t)node * 128 + 64 + lane] = a;
}

// C[Nrows x Ncols] = relu?( A[Nrows x K] @ Bcat + biascat )
// Bcat columns [0,split) come from B0 (K x split), [split,Ncols) from B1.
__global__ __launch_bounds__(256) void gemm_tiled(
    const float* __restrict__ A, int lda,
    const float* __restrict__ B0, const float* __restrict__ B1,
    const float* __restrict__ bias0, const float* __restrict__ bias1,
    float* __restrict__ C, int Nrows, int K, int Ncols, int split, int relu) {
    __shared__ float As[BK * BMp];  // transposed: As[k][m]
    __shared__ float Bs[BK * BNp];  // Bs[k][n]
    const int bm = blockIdx.y * BM, bn = blockIdx.x * BN;
    const int tid = threadIdx.x;
    const int tx = tid & 15, ty = tid >> 4;
    const int kq = tid & 7, mrow = tid >> 3;   // A loader
    const int nq = tid & 15, krow = tid >> 4;  // B loader
    const int ldb0 = split, ldb1 = Ncols - split;
    float acc[4][4] = {};
    for (int k0 = 0; k0 < K; k0 += BK) {
#pragma unroll
        for (int half = 0; half < 2; ++half) {
            int m = mrow + half * 32;
            int row = bm + m;
            int kk = k0 + kq * 4;
            float4 v = {0, 0, 0, 0};
            if (row < Nrows) {
                if (kk + 3 < K) v = *(const float4*)&A[(size_t)row * lda + kk];
                else if (kk < K) {
                    float t[4] = {0, 0, 0, 0};
                    for (int i = 0; i < 4; ++i) if (kk + i < K) t[i] = A[(size_t)row * lda + kk + i];
                    v.x = t[0]; v.y = t[1]; v.z = t[2]; v.w = t[3];
                }
            }
            As[(kq * 4 + 0) * BMp + m] = v.x;
            As[(kq * 4 + 1) * BMp + m] = v.y;
            As[(kq * 4 + 2) * BMp + m] = v.z;
            As[(kq * 4 + 3) * BMp + m] = v.w;
        }
#pragma unroll
        for (int half = 0; half < 2; ++half) {
            int k = krow + half * 16;
            int kk = k0 + k;
            int col = bn + nq * 4;
            float4 v = {0, 0, 0, 0};
            if (kk < K && col < Ncols) {
                if (col < split) v = *(const float4*)&B0[(size_t)kk * ldb0 + col];
                else             v = *(const float4*)&B1[(size_t)kk * ldb1 + (col - split)];
            }
            *(float4*)&Bs[k * BNp + nq * 4] = v;
        }
        __syncthreads();
#pragma unroll
        for (int k = 0; k < BK; ++k) {
            float4 av = *(const float4*)&As[k * BMp + ty * 4];
            float4 bv = *(const float4*)&Bs[k * BNp + tx * 4];
            acc[0][0] += av.x * bv.x; acc[0][1] += av.x * bv.y; acc[0][2] += av.x * bv.z; acc[0][3] += av.x * bv.w;
            acc[1][0] += av.y * bv.x; acc[1][1] += av.y * bv.y; acc[1][2] += av.y * bv.z; acc[1][3] += av.y * bv.w;
            acc[2][0] += av.z * bv.x; acc[2][1] += av.z * bv.y; acc[2][2] += av.z * bv.z; acc[2][3] += av.z * bv.w;
            acc[3][0] += av.w * bv.x; acc[3][1] += av.w * bv.y; acc[3][2] += av.w * bv.z; acc[3][3] += av.w * bv.w;
        }
        __syncthreads();
    }
    const int c = bn + tx * 4;
    if (c >= Ncols) return;
    float bvals[4];
#pragma unroll
    for (int j = 0; j < 4; ++j) {
        int cj = c + j;
        bvals[j] = (cj < split) ? (bias0 ? bias0[cj] : 0.0f)
                                : (bias1 ? bias1[cj - split] : 0.0f);
    }
#pragma unroll
    for (int i = 0; i < 4; ++i) {
        int r = bm + ty * 4 + i;
        if (r >= Nrows) break;
        float4 o;
        o.x = acc[i][0] + bvals[0];
        o.y = acc[i][1] + bvals[1];
        o.z = acc[i][2] + bvals[2];
        o.w = acc[i][3] + bvals[3];
        if (relu) {
            o.x = fmaxf(o.x, 0.0f); o.y = fmaxf(o.y, 0.0f);
            o.z = fmaxf(o.z, 0.0f); o.w = fmaxf(o.w, 0.0f);
        }
        *(float4*)&C[(size_t)r * Ncols + c] = o;
    }
}

// t[node,f] = sum_j wnorm[j] * src[colidx[j]*ld + f], f<100; one block per node
__global__ void csr_segsum100_kernel(const float* __restrict__ src, int ld,
                                     const int* __restrict__ rowptr, const int* __restrict__ colidx,
                                     const float* __restrict__ wnorm, float* __restrict__ out, int n) {
    int node = blockIdx.x;
    int f = threadIdx.x;
    if (f >= 100) return;
    int j0 = rowptr[node], j1 = rowptr[node + 1];
    float a = 0.0f;
    for (int j = j0; j < j1; ++j)
        a += wnorm[j] * src[(size_t)colidx[j] * ld + f];
    out[(size_t)node * 100 + f] = a;
}

// x1 = relu(G2[:,0:100] + t + b2)
__global__ void combine1_kernel(const float* __restrict__ G2, const float* __restrict__ t,
                                const float* __restrict__ b2, float* __restrict__ x1, int n) {
    int idx = blockIdx.x * blockDim.x + threadIdx.x;
    if (idx >= n * 25) return;
    int i = idx / 25, q = idx % 25;
    float4 g = *(const float4*)&G2[(size_t)i * 200 + q * 4];
    float4 tv = *(const float4*)&t[(size_t)i * 100 + q * 4];
    float4 bv = *(const float4*)&b2[q * 4];
    float4 o;
    o.x = fmaxf(g.x + tv.x + bv.x, 0.0f);
    o.y = fmaxf(g.y + tv.y + bv.y, 0.0f);
    o.z = fmaxf(g.z + tv.z + bv.z, 0.0f);
    o.w = fmaxf(g.w + tv.w + bv.w, 0.0f);
    *(float4*)&x1[(size_t)i * 100 + q * 4] = o;
}

// xo = x1 + relu(S[:,0:100]); z = x1 + relu(S[:,100:200])   (lb folded into S)
__global__ void combine2_kernel(const float* __restrict__ S, const float* __restrict__ x1,
                                float* __restrict__ xo, float* __restrict__ z, int n) {
    int idx = blockIdx.x * blockDim.x + threadIdx.x;
    if (idx >= n * 25) return;
    int i = idx / 25, q = idx % 25;
    float4 s1 = *(const float4*)&S[(size_t)i * 200 + q * 4];
    float4 s2 = *(const float4*)&S[(size_t)i * 200 + 100 + q * 4];
    float4 xv = *(const float4*)&x1[(size_t)i * 100 + q * 4];
    float4 a, b;
    a.x = xv.x + fmaxf(s1.x, 0.0f); a.y = xv.y + fmaxf(s1.y, 0.0f);
    a.z = xv.z + fmaxf(s1.z, 0.0f); a.w = xv.w + fmaxf(s1.w, 0.0f);
    b.x = xv.x + fmaxf(s2.x, 0.0f); b.y = xv.y + fmaxf(s2.y, 0.0f);
    b.z = xv.z + fmaxf(s2.z, 0.0f); b.w = xv.w + fmaxf(s2.w, 0.0f);
    *(float4*)&xo[(size_t)i * 100 + q * 4] = a;
    *(float4*)&z[(size_t)i * 100 + q * 4] = b;
}

// fused pos+neg loss: acc[0] += sum log(sig(dot_pos)+eps), acc[1] += sum log(1-sig(dot_neg)+eps)
__global__ void edge_loss_kernel(const float* __restrict__ z, const int* __restrict__ ei,
                                 const int* __restrict__ nei, int E, float* __restrict__ acc) {
    float s0 = 0.0f, s1 = 0.0f;
    int total = 2 * E;
    int stride = gridDim.x * blockDim.x;
    for (int idx = blockIdx.x * blockDim.x + threadIdx.x; idx < total; idx += stride) {
        const int* lst = (idx < E) ? ei : nei;
        int e = (idx < E) ? idx : idx - E;
        int a = lst[e];
        int b = lst[E + e];
        const float4* za = (const float4*)(z + (size_t)a * 100);
        const float4* zb = (const float4*)(z + (size_t)b * 100);
        float dot = 0.0f;
#pragma unroll
        for (int q = 0; q < 25; ++q) {
            float4 va = za[q], vb = zb[q];
            dot += va.x * vb.x + va.y * vb.y + va.z * vb.z + va.w * vb.w;
        }
        float sg = 1.0f / (1.0f + expf(-dot));
        if (idx < E) s0 += logf(sg + 1e-15f);
        else         s1 += logf(1.0f - sg + 1e-15f);
    }
    __shared__ float r0[256], r1[256];
    r0[threadIdx.x] = s0; r1[threadIdx.x] = s1;
    __syncthreads();
    for (int s = 128; s > 0; s >>= 1) {
        if (threadIdx.x < s) { r0[threadIdx.x] += r0[threadIdx.x + s]; r1[threadIdx.x] += r1[threadIdx.x + s]; }
        __syncthreads();
    }
    if (threadIdx.x == 0) { atomicAdd(&acc[0], r0[0]); atomicAdd(&acc[1], r1[0]); }
}

// sv[i] = xo[i,:] @ w (100-dim)
__global__ void rowdot_kernel(const float* __restrict__ xo, const float* __restrict__ w,
                              float* __restrict__ s, int n) {
    int i = blockIdx.x * blockDim.x + threadIdx.x;
    if (i >= n) return;
    const float4* a = (const float4*)(xo + (size_t)i * 100);
    const float4* wv = (const float4*)w;
    float acc = 0.0f;
#pragma unroll
    for (int q = 0; q < 25; ++q) {
        float4 va = a[q], vw = wv[q];
        acc += va.x * vw.x + va.y * vw.y + va.z * vw.z + va.w * vw.w;
    }
    s[i] = acc;
}

// out[i] = xo[i,:]@W3[0] + b3 + sum_j wnorm[j]*sv[colidx[j]]
__global__ void out_kernel(const float* __restrict__ xo, const float* __restrict__ W3,
                           const float* __restrict__ b3, const int* __restrict__ rowptr,
                           const int* __restrict__ colidx, const float* __restrict__ wnorm,
                           const float* __restrict__ sv, float* __restrict__ out, int n) {
    int i = blockIdx.x * blockDim.x + threadIdx.x;
    if (i >= n) return;
    const float4* a = (const float4*)(xo + (size_t)i * 100);
    const float4* wv = (const float4*)W3;
    float acc = b3[0];
#pragma unroll
    for (int q = 0; q < 25; ++q) {
        float4 va = a[q], vw = wv[q];
        acc += va.x * vw.x + va.y * vw.y + va.z * vw.z + va.w * vw.w;
    }
    int j1 = rowptr[i + 1];
    for (int j = rowptr[i]; j < j1; ++j)
        acc += wnorm[j] * sv[colidx[j]];
    out[i] = acc;
}

__global__ void finalize_kernel(float* __restrict__ out, const float* __restrict__ acc,
                                const float* __restrict__ c1, const float* __restrict__ c2,
                                int Nn, int E) {
    out[Nn]     = -(acc[0] + acc[1]) / (float)E;
    out[Nn + 1] = c1[0];
    out[Nn + 2] = c2[0];
}

extern "C" void kernel_launch(void* const* d_in, const int* in_sizes, int n_in,
                              void* d_out, int out_size, void* d_ws, size_t ws_size,
                              hipStream_t stream) {
    (void)n_in; (void)out_size; (void)ws_size;
    const float* x   = (const float*)d_in[0];
    const int*   ei  = (const int*)d_in[1];
    const int*   nei = (const int*)d_in[2];
    const float* W1  = (const float*)d_in[3];
    const float* b1  = (const float*)d_in[4];
    const float* W2  = (const float*)d_in[5];
    const float* b2  = (const float*)d_in[6];
    const float* W3  = (const float*)d_in[7];
    const float* b3  = (const float*)d_in[8];
    const float* lw1 = (const float*)d_in[9];
    const float* lb1 = (const float*)d_in[10];
    const float* lw2 = (const float*)d_in[11];
    const float* lb2 = (const float*)d_in[12];
    const float* c1  = (const float*)d_in[13];
    const float* c2  = (const float*)d_in[14];

    const int Nn = in_sizes[0] / 64;   // 13627
    const int E  = in_sizes[1] / 2;    // 504378

    const size_t Nal = ((size_t)Nn + 5) & ~(size_t)3;   // >= N+1, mult of 4
    const size_t Eal = ((size_t)E + 3) & ~(size_t)3;

    float* ws     = (float*)d_ws;
    float* dinv   = ws;                           // Nal floats
    int*   rowptr = (int*)(dinv + Nal);           // Nal ints (N+1 used)
    float* acc    = (float*)(rowptr + Nal);       // 4 floats
    int*   cursor = (int*)(acc + 4);              // Nal ints
    int*   colidx = cursor + Nal;                 // Eal ints
    float* wnorm  = (float*)(colidx + Eal);       // Eal floats
    float* XT     = wnorm + Eal;                  // N*128 (reused as t: N*100)
    float* h      = XT + (size_t)Nn * 128;        // N*300 (reused as S: N*200)
    float* G2     = h  + (size_t)Nn * 300;        // N*200
    float* x1     = G2 + (size_t)Nn * 200;        // N*100
    float* xo     = x1 + (size_t)Nn * 100;        // N*100
    float* z      = xo + (size_t)Nn * 100;        // N*100
    float* sv     = z  + (size_t)Nn * 100;        // Nal
    float* t      = XT;                           // alias (XT dead after conv1)
    float* S      = h;                            // alias (h dead after conv2 gemm)

    // --- zero dinv + rowptr + acc in one memset ---
    hipMemsetAsync(dinv, 0, (2 * Nal + 4) * sizeof(float), stream);

    // --- CSR build + norm ---
    deg_hist_kernel<<<1024, 256, 0, stream>>>(ei, dinv, rowptr, E);
    dinv_kernel<<<(Nn + 255) / 256, 256, 0, stream>>>(dinv, Nn);
    scan_kernel<<<1, 1024, 0, stream>>>(rowptr, cursor, Nn);
    fill_kernel<<<1024, 256, 0, stream>>>(ei, dinv, cursor, colidx, wnorm, E);

    // --- conv1: XT = [x | segsum64(x)]; h = relu(XT @ W1cat + b1) ---
    xt_kernel<<<(Nn + 3) / 4, 256, 0, stream>>>(x, rowptr, colidx, wnorm, XT, Nn);
    gemm_tiled<<<dim3(5, (Nn + BM - 1) / BM), 256, 0, stream>>>(
        XT, 128, W1, nullptr, b1, nullptr, h, Nn, 128, 300, 300, 1);

    // --- conv2 fused: G2 = h @ [W2[0] | W2[1]] ---
    gemm_tiled<<<dim3(4, (Nn + BM - 1) / BM), 256, 0, stream>>>(
        h, 300, W2, W2 + 300 * 100, nullptr, nullptr, G2, Nn, 300, 200, 100, 0);
    // t = segsum(G2[:,100:200]); x1 = relu(G2[:,0:100] + t + b2)
    csr_segsum100_kernel<<<Nn, 128, 0, stream>>>(G2 + 100, 200, rowptr, colidx, wnorm, t, Nn);
    combine1_kernel<<<(Nn * 25 + 255) / 256, 256, 0, stream>>>(G2, t, b2, x1, Nn);

    // --- skips fused: S = x @ [lw1|lw2] + [lb1|lb2]; xo/z = x1 + relu(S halves) ---
    gemm_tiled<<<dim3(4, (Nn + BM - 1) / BM), 256, 0, stream>>>(
        x, 64, lw1, lw2, lb1, lb2, S, Nn, 64, 200, 100, 0);
    combine2_kernel<<<(Nn * 25 + 255) / 256, 256, 0, stream>>>(S, x1, xo, z, Nn);

    // --- edge reconstruction losses (pos+neg fused) ---
    edge_loss_kernel<<<2048, 256, 0, stream>>>(z, ei, nei, E, acc);

    // --- conv3 (width 1): sv = xo@W3[1]; out = xo@W3[0] + segsum(sv) + b3 ---
    rowdot_kernel<<<(Nn + 255) / 256, 256, 0, stream>>>(xo, W3 + 100, sv, Nn);
    out_kernel<<<(Nn + 255) / 256, 256, 0, stream>>>(xo, W3, b3, rowptr, colidx, wnorm,
                                                     sv, (float*)d_out, Nn);

    finalize_kernel<<<1, 1, 0, stream>>>((float*)d_out, acc, c1, c2, Nn, E);
}

// Round 4
// 480.143 us; speedup vs baseline: 3.0276x; 1.0827x over previous
//
#include <hip/hip_runtime.h>
#include <math.h>

// ---------------------------------------------------------------------------
// Net_1503238553644: 2-layer ChebConv(K=2) GNN + linear skips + edge recon loss
// N=13627, E=504378, F=64, H1=300, H2=100, LIN=100
// R4: edge loss restructured to 32-lanes-per-edge (coalesced row reads +
//     shfl_xor dot reduce) — was thread-per-edge with 64-way scattered loads.
// ---------------------------------------------------------------------------

#define BM 64
#define BN 64
#define BK 32
#define BMp 68
#define BNp 68

// deg[src[e]] += 1 (float); cnt[dst[e]+1] += 1 (CSR histogram)
__global__ void deg_hist_kernel(const int* __restrict__ ei, float* __restrict__ deg,
                                int* __restrict__ cnt, int E) {
    int stride = gridDim.x * blockDim.x;
    for (int e = blockIdx.x * blockDim.x + threadIdx.x; e < E; e += stride) {
        atomicAdd(&deg[ei[e]], 1.0f);
        atomicAdd(&cnt[ei[E + e] + 1], 1);
    }
}

__global__ void dinv_kernel(float* __restrict__ deg, int n) {
    int i = blockIdx.x * blockDim.x + threadIdx.x;
    if (i < n) {
        float d = deg[i];
        deg[i] = (d > 0.0f) ? (1.0f / sqrtf(fmaxf(d, 1.0f))) : 0.0f;
    }
}

// single-block scan: rowptr[i+1] = inclusive sum; cursor[i] = exclusive sum
__global__ void scan_kernel(int* __restrict__ rowptr, int* __restrict__ cursor, int n) {
    __shared__ int wsum[16];
    __shared__ int carry_s;
    if (threadIdx.x == 0) carry_s = 0;
    __syncthreads();
    int nchunk = (n + 1023) / 1024;
    int wid = threadIdx.x >> 6, lane = threadIdx.x & 63;
    for (int c = 0; c < nchunk; ++c) {
        int i = c * 1024 + threadIdx.x;
        int v = (i < n) ? rowptr[i + 1] : 0;
        int s = v;
        for (int off = 1; off < 64; off <<= 1) {
            int t = __shfl_up(s, off, 64);
            if (lane >= off) s += t;
        }
        if (lane == 63) wsum[wid] = s;
        __syncthreads();
        if (wid == 0 && lane < 16) {
            int wsv = wsum[lane];
            for (int off = 1; off < 16; off <<= 1) {
                int t = __shfl_up(wsv, off, 64);
                if (lane >= off) wsv += t;
            }
            wsum[lane] = wsv;
        }
        __syncthreads();
        int base = carry_s + (wid > 0 ? wsum[wid - 1] : 0);
        int inc = base + s;
        if (i < n) { rowptr[i + 1] = inc; cursor[i] = inc - v; }
        __syncthreads();
        if (threadIdx.x == 1023) carry_s = inc;
        __syncthreads();
    }
}

// scatter edges into dst-sorted CSR slots; wnorm = -dinv[src]*dinv[dst]
__global__ void fill_kernel(const int* __restrict__ ei, const float* __restrict__ dinv,
                            int* __restrict__ cursor, int* __restrict__ colidx,
                            float* __restrict__ wnorm, int E) {
    int stride = gridDim.x * blockDim.x;
    for (int e = blockIdx.x * blockDim.x + threadIdx.x; e < E; e += stride) {
        int s = ei[e];
        int d = ei[E + e];
        int slot = atomicAdd(&cursor[d], 1);
        colidx[slot] = s;
        wnorm[slot] = -dinv[s] * dinv[d];
    }
}

// XT[node] = [ x[node] (64) | segsum64(x)[node] (64) ]  — one wave per node
__global__ void xt_kernel(const float* __restrict__ x, const int* __restrict__ rowptr,
                          const int* __restrict__ colidx, const float* __restrict__ wnorm,
                          float* __restrict__ XT, int n) {
    int node = (blockIdx.x * blockDim.x + threadIdx.x) >> 6;
    int lane = threadIdx.x & 63;
    if (node >= n) return;
    int j0 = rowptr[node], j1 = rowptr[node + 1];
    float a = 0.0f;
    for (int j = j0; j < j1; ++j)
        a += wnorm[j] * x[(size_t)colidx[j] * 64 + lane];
    XT[(size_t)node * 128 + lane] = x[(size_t)node * 64 + lane];
    XT[(size_t)node * 128 + 64 + lane] = a;
}

// C[Nrows x Ncols] = relu?( A[Nrows x K] @ Bcat + biascat )
// Bcat columns [0,split) come from B0 (K x split), [split,Ncols) from B1.
__global__ __launch_bounds__(256) void gemm_tiled(
    const float* __restrict__ A, int lda,
    const float* __restrict__ B0, const float* __restrict__ B1,
    const float* __restrict__ bias0, const float* __restrict__ bias1,
    float* __restrict__ C, int Nrows, int K, int Ncols, int split, int relu) {
    __shared__ float As[BK * BMp];  // transposed: As[k][m]
    __shared__ float Bs[BK * BNp];  // Bs[k][n]
    const int bm = blockIdx.y * BM, bn = blockIdx.x * BN;
    const int tid = threadIdx.x;
    const int tx = tid & 15, ty = tid >> 4;
    const int kq = tid & 7, mrow = tid >> 3;   // A loader
    const int nq = tid & 15, krow = tid >> 4;  // B loader
    const int ldb0 = split, ldb1 = Ncols - split;
    float acc[4][4] = {};
    for (int k0 = 0; k0 < K; k0 += BK) {
#pragma unroll
        for (int half = 0; half < 2; ++half) {
            int m = mrow + half * 32;
            int row = bm + m;
            int kk = k0 + kq * 4;
            float4 v = {0, 0, 0, 0};
            if (row < Nrows) {
                if (kk + 3 < K) v = *(const float4*)&A[(size_t)row * lda + kk];
                else if (kk < K) {
                    float t[4] = {0, 0, 0, 0};
                    for (int i = 0; i < 4; ++i) if (kk + i < K) t[i] = A[(size_t)row * lda + kk + i];
                    v.x = t[0]; v.y = t[1]; v.z = t[2]; v.w = t[3];
                }
            }
            As[(kq * 4 + 0) * BMp + m] = v.x;
            As[(kq * 4 + 1) * BMp + m] = v.y;
            As[(kq * 4 + 2) * BMp + m] = v.z;
            As[(kq * 4 + 3) * BMp + m] = v.w;
        }
#pragma unroll
        for (int half = 0; half < 2; ++half) {
            int k = krow + half * 16;
            int kk = k0 + k;
            int col = bn + nq * 4;
            float4 v = {0, 0, 0, 0};
            if (kk < K && col < Ncols) {
                if (col < split) v = *(const float4*)&B0[(size_t)kk * ldb0 + col];
                else             v = *(const float4*)&B1[(size_t)kk * ldb1 + (col - split)];
            }
            *(float4*)&Bs[k * BNp + nq * 4] = v;
        }
        __syncthreads();
#pragma unroll
        for (int k = 0; k < BK; ++k) {
            float4 av = *(const float4*)&As[k * BMp + ty * 4];
            float4 bv = *(const float4*)&Bs[k * BNp + tx * 4];
            acc[0][0] += av.x * bv.x; acc[0][1] += av.x * bv.y; acc[0][2] += av.x * bv.z; acc[0][3] += av.x * bv.w;
            acc[1][0] += av.y * bv.x; acc[1][1] += av.y * bv.y; acc[1][2] += av.y * bv.z; acc[1][3] += av.y * bv.w;
            acc[2][0] += av.z * bv.x; acc[2][1] += av.z * bv.y; acc[2][2] += av.z * bv.z; acc[2][3] += av.z * bv.w;
            acc[3][0] += av.w * bv.x; acc[3][1] += av.w * bv.y; acc[3][2] += av.w * bv.z; acc[3][3] += av.w * bv.w;
        }
        __syncthreads();
    }
    const int c = bn + tx * 4;
    if (c >= Ncols) return;
    float bvals[4];
#pragma unroll
    for (int j = 0; j < 4; ++j) {
        int cj = c + j;
        bvals[j] = (cj < split) ? (bias0 ? bias0[cj] : 0.0f)
                                : (bias1 ? bias1[cj - split] : 0.0f);
    }
#pragma unroll
    for (int i = 0; i < 4; ++i) {
        int r = bm + ty * 4 + i;
        if (r >= Nrows) break;
        float4 o;
        o.x = acc[i][0] + bvals[0];
        o.y = acc[i][1] + bvals[1];
        o.z = acc[i][2] + bvals[2];
        o.w = acc[i][3] + bvals[3];
        if (relu) {
            o.x = fmaxf(o.x, 0.0f); o.y = fmaxf(o.y, 0.0f);
            o.z = fmaxf(o.z, 0.0f); o.w = fmaxf(o.w, 0.0f);
        }
        *(float4*)&C[(size_t)r * Ncols + c] = o;
    }
}

// t[node,f] = sum_j wnorm[j] * src[colidx[j]*ld + f], f<100; one block per node
__global__ void csr_segsum100_kernel(const float* __restrict__ src, int ld,
                                     const int* __restrict__ rowptr, const int* __restrict__ colidx,
                                     const float* __restrict__ wnorm, float* __restrict__ out, int n) {
    int node = blockIdx.x;
    int f = threadIdx.x;
    if (f >= 100) return;
    int j0 = rowptr[node], j1 = rowptr[node + 1];
    float a = 0.0f;
    for (int j = j0; j < j1; ++j)
        a += wnorm[j] * src[(size_t)colidx[j] * ld + f];
    out[(size_t)node * 100 + f] = a;
}

// x1 = relu(G2[:,0:100] + t + b2)
__global__ void combine1_kernel(const float* __restrict__ G2, const float* __restrict__ t,
                                const float* __restrict__ b2, float* __restrict__ x1, int n) {
    int idx = blockIdx.x * blockDim.x + threadIdx.x;
    if (idx >= n * 25) return;
    int i = idx / 25, q = idx % 25;
    float4 g = *(const float4*)&G2[(size_t)i * 200 + q * 4];
    float4 tv = *(const float4*)&t[(size_t)i * 100 + q * 4];
    float4 bv = *(const float4*)&b2[q * 4];
    float4 o;
    o.x = fmaxf(g.x + tv.x + bv.x, 0.0f);
    o.y = fmaxf(g.y + tv.y + bv.y, 0.0f);
    o.z = fmaxf(g.z + tv.z + bv.z, 0.0f);
    o.w = fmaxf(g.w + tv.w + bv.w, 0.0f);
    *(float4*)&x1[(size_t)i * 100 + q * 4] = o;
}

// xo = x1 + relu(S[:,0:100]); z = x1 + relu(S[:,100:200])   (lb folded into S)
__global__ void combine2_kernel(const float* __restrict__ S, const float* __restrict__ x1,
                                float* __restrict__ xo, float* __restrict__ z, int n) {
    int idx = blockIdx.x * blockDim.x + threadIdx.x;
    if (idx >= n * 25) return;
    int i = idx / 25, q = idx % 25;
    float4 s1 = *(const float4*)&S[(size_t)i * 200 + q * 4];
    float4 s2 = *(const float4*)&S[(size_t)i * 200 + 100 + q * 4];
    float4 xv = *(const float4*)&x1[(size_t)i * 100 + q * 4];
    float4 a, b;
    a.x = xv.x + fmaxf(s1.x, 0.0f); a.y = xv.y + fmaxf(s1.y, 0.0f);
    a.z = xv.z + fmaxf(s1.z, 0.0f); a.w = xv.w + fmaxf(s1.w, 0.0f);
    b.x = xv.x + fmaxf(s2.x, 0.0f); b.y = xv.y + fmaxf(s2.y, 0.0f);
    b.z = xv.z + fmaxf(s2.z, 0.0f); b.w = xv.w + fmaxf(s2.w, 0.0f);
    *(float4*)&xo[(size_t)i * 100 + q * 4] = a;
    *(float4*)&z[(size_t)i * 100 + q * 4] = b;
}

// fused pos+neg loss, 32 lanes per edge: coalesced float4 row reads + shfl dot
__global__ void edge_loss_kernel(const float* __restrict__ z, const int* __restrict__ ei,
                                 const int* __restrict__ nei, int E, float* __restrict__ acc) {
    const int l = threadIdx.x & 31;
    const int hw0 = (blockIdx.x * blockDim.x + threadIdx.x) >> 5;
    const int nhw = (gridDim.x * blockDim.x) >> 5;
    const int total = 2 * E;
    float s0 = 0.0f, s1 = 0.0f;
    for (int idx = hw0; idx < total; idx += nhw) {
        const int pos = (idx < E);
        const int* lst = pos ? ei : nei;
        const int e = pos ? idx : idx - E;
        const int a = lst[e];
        const int b = lst[E + e];
        float part = 0.0f;
        if (l < 25) {
            float4 va = ((const float4*)(z + (size_t)a * 100))[l];
            float4 vb = ((const float4*)(z + (size_t)b * 100))[l];
            part = va.x * vb.x + va.y * vb.y + va.z * vb.z + va.w * vb.w;
        }
#pragma unroll
        for (int off = 16; off > 0; off >>= 1)
            part += __shfl_xor(part, off, 32);
        if (l == 0) {
            float sg = 1.0f / (1.0f + expf(-part));
            if (pos) s0 += logf(sg + 1e-15f);
            else     s1 += logf(1.0f - sg + 1e-15f);
        }
    }
    __shared__ float r0[256], r1[256];
    r0[threadIdx.x] = s0; r1[threadIdx.x] = s1;
    __syncthreads();
    for (int s = 128; s > 0; s >>= 1) {
        if (threadIdx.x < s) { r0[threadIdx.x] += r0[threadIdx.x + s]; r1[threadIdx.x] += r1[threadIdx.x + s]; }
        __syncthreads();
    }
    if (threadIdx.x == 0) { atomicAdd(&acc[0], r0[0]); atomicAdd(&acc[1], r1[0]); }
}

// sv[i] = xo[i,:] @ w (100-dim)
__global__ void rowdot_kernel(const float* __restrict__ xo, const float* __restrict__ w,
                              float* __restrict__ s, int n) {
    int i = blockIdx.x * blockDim.x + threadIdx.x;
    if (i >= n) return;
    const float4* a = (const float4*)(xo + (size_t)i * 100);
    const float4* wv = (const float4*)w;
    float acc = 0.0f;
#pragma unroll
    for (int q = 0; q < 25; ++q) {
        float4 va = a[q], vw = wv[q];
        acc += va.x * vw.x + va.y * vw.y + va.z * vw.z + va.w * vw.w;
    }
    s[i] = acc;
}

// out[i] = xo[i,:]@W3[0] + b3 + sum_j wnorm[j]*sv[colidx[j]]
__global__ void out_kernel(const float* __restrict__ xo, const float* __restrict__ W3,
                           const float* __restrict__ b3, const int* __restrict__ rowptr,
                           const int* __restrict__ colidx, const float* __restrict__ wnorm,
                           const float* __restrict__ sv, float* __restrict__ out, int n) {
    int i = blockIdx.x * blockDim.x + threadIdx.x;
    if (i >= n) return;
    const float4* a = (const float4*)(xo + (size_t)i * 100);
    const float4* wv = (const float4*)W3;
    float acc = b3[0];
#pragma unroll
    for (int q = 0; q < 25; ++q) {
        float4 va = a[q], vw = wv[q];
        acc += va.x * vw.x + va.y * vw.y + va.z * vw.z + va.w * vw.w;
    }
    int j1 = rowptr[i + 1];
    for (int j = rowptr[i]; j < j1; ++j)
        acc += wnorm[j] * sv[colidx[j]];
    out[i] = acc;
}

__global__ void finalize_kernel(float* __restrict__ out, const float* __restrict__ acc,
                                const float* __restrict__ c1, const float* __restrict__ c2,
                                int Nn, int E) {
    out[Nn]     = -(acc[0] + acc[1]) / (float)E;
    out[Nn + 1] = c1[0];
    out[Nn + 2] = c2[0];
}

extern "C" void kernel_launch(void* const* d_in, const int* in_sizes, int n_in,
                              void* d_out, int out_size, void* d_ws, size_t ws_size,
                              hipStream_t stream) {
    (void)n_in; (void)out_size; (void)ws_size;
    const float* x   = (const float*)d_in[0];
    const int*   ei  = (const int*)d_in[1];
    const int*   nei = (const int*)d_in[2];
    const float* W1  = (const float*)d_in[3];
    const float* b1  = (const float*)d_in[4];
    const float* W2  = (const float*)d_in[5];
    const float* b2  = (const float*)d_in[6];
    const float* W3  = (const float*)d_in[7];
    const float* b3  = (const float*)d_in[8];
    const float* lw1 = (const float*)d_in[9];
    const float* lb1 = (const float*)d_in[10];
    const float* lw2 = (const float*)d_in[11];
    const float* lb2 = (const float*)d_in[12];
    const float* c1  = (const float*)d_in[13];
    const float* c2  = (const float*)d_in[14];

    const int Nn = in_sizes[0] / 64;   // 13627
    const int E  = in_sizes[1] / 2;    // 504378

    const size_t Nal = ((size_t)Nn + 5) & ~(size_t)3;   // >= N+1, mult of 4
    const size_t Eal = ((size_t)E + 3) & ~(size_t)3;

    float* ws     = (float*)d_ws;
    float* dinv   = ws;                           // Nal floats
    int*   rowptr = (int*)(dinv + Nal);           // Nal ints (N+1 used)
    float* acc    = (float*)(rowptr + Nal);       // 4 floats
    int*   cursor = (int*)(acc + 4);              // Nal ints
    int*   colidx = cursor + Nal;                 // Eal ints
    float* wnorm  = (float*)(colidx + Eal);       // Eal floats
    float* XT     = wnorm + Eal;                  // N*128 (reused as t: N*100)
    float* h      = XT + (size_t)Nn * 128;        // N*300 (reused as S: N*200)
    float* G2     = h  + (size_t)Nn * 300;        // N*200
    float* x1     = G2 + (size_t)Nn * 200;        // N*100
    float* xo     = x1 + (size_t)Nn * 100;        // N*100
    float* z      = xo + (size_t)Nn * 100;        // N*100
    float* sv     = z  + (size_t)Nn * 100;        // Nal
    float* t      = XT;                           // alias (XT dead after conv1)
    float* S      = h;                            // alias (h dead after conv2 gemm)

    // --- zero dinv + rowptr + acc in one memset ---
    hipMemsetAsync(dinv, 0, (2 * Nal + 4) * sizeof(float), stream);

    // --- CSR build + norm ---
    deg_hist_kernel<<<1024, 256, 0, stream>>>(ei, dinv, rowptr, E);
    dinv_kernel<<<(Nn + 255) / 256, 256, 0, stream>>>(dinv, Nn);
    scan_kernel<<<1, 1024, 0, stream>>>(rowptr, cursor, Nn);
    fill_kernel<<<1024, 256, 0, stream>>>(ei, dinv, cursor, colidx, wnorm, E);

    // --- conv1: XT = [x | segsum64(x)]; h = relu(XT @ W1cat + b1) ---
    xt_kernel<<<(Nn + 3) / 4, 256, 0, stream>>>(x, rowptr, colidx, wnorm, XT, Nn);
    gemm_tiled<<<dim3(5, (Nn + BM - 1) / BM), 256, 0, stream>>>(
        XT, 128, W1, nullptr, b1, nullptr, h, Nn, 128, 300, 300, 1);

    // --- conv2 fused: G2 = h @ [W2[0] | W2[1]] ---
    gemm_tiled<<<dim3(4, (Nn + BM - 1) / BM), 256, 0, stream>>>(
        h, 300, W2, W2 + 300 * 100, nullptr, nullptr, G2, Nn, 300, 200, 100, 0);
    // t = segsum(G2[:,100:200]); x1 = relu(G2[:,0:100] + t + b2)
    csr_segsum100_kernel<<<Nn, 128, 0, stream>>>(G2 + 100, 200, rowptr, colidx, wnorm, t, Nn);
    combine1_kernel<<<(Nn * 25 + 255) / 256, 256, 0, stream>>>(G2, t, b2, x1, Nn);

    // --- skips fused: S = x @ [lw1|lw2] + [lb1|lb2]; xo/z = x1 + relu(S halves) ---
    gemm_tiled<<<dim3(4, (Nn + BM - 1) / BM), 256, 0, stream>>>(
        x, 64, lw1, lw2, lb1, lb2, S, Nn, 64, 200, 100, 0);
    combine2_kernel<<<(Nn * 25 + 255) / 256, 256, 0, stream>>>(S, x1, xo, z, Nn);

    // --- edge reconstruction losses (pos+neg fused, 32 lanes/edge) ---
    edge_loss_kernel<<<4096, 256, 0, stream>>>(z, ei, nei, E, acc);

    // --- conv3 (width 1): sv = xo@W3[1]; out = xo@W3[0] + segsum(sv) + b3 ---
    rowdot_kernel<<<(Nn + 255) / 256, 256, 0, stream>>>(xo, W3 + 100, sv, Nn);
    out_kernel<<<(Nn + 255) / 256, 256, 0, stream>>>(xo, W3, b3, rowptr, colidx, wnorm,
                                                     sv, (float*)d_out, Nn);

    finalize_kernel<<<1, 1, 0, stream>>>((float*)d_out, acc, c1, c2, Nn, E);
}

// Round 5
// 463.849 us; speedup vs baseline: 3.1339x; 1.0351x over previous
//
#include <hip/hip_runtime.h>
#include <math.h>

// ---------------------------------------------------------------------------
// Net_1503238553644: 2-layer ChebConv(K=2) GNN + linear skips + edge recon loss
// N=13627, E=504378, F=64, H1=300, H2=100, LIN=100
// R5: z stored as bf16 padded to 128/row (256B = 2 cache lines, L2-resident
//     3.5MB) -> edge loss gathers 2 lines/row, 4 edges/wave, 16 lanes/edge.
// ---------------------------------------------------------------------------

#define BM 64
#define BN 64
#define BK 32
#define BMp 68
#define BNp 68

typedef unsigned short ushort_t;

__device__ inline ushort_t f2bf(float f) {           // RNE float->bf16
    unsigned u = __float_as_uint(f);
    u += 0x7fff + ((u >> 16) & 1);
    return (ushort_t)(u >> 16);
}
__device__ inline float bflo(unsigned w) { return __uint_as_float(w << 16); }
__device__ inline float bfhi(unsigned w) { return __uint_as_float(w & 0xffff0000u); }

// deg[src[e]] += 1 (float); cnt[dst[e]+1] += 1 (CSR histogram)
__global__ void deg_hist_kernel(const int* __restrict__ ei, float* __restrict__ deg,
                                int* __restrict__ cnt, int E) {
    int stride = gridDim.x * blockDim.x;
    for (int e = blockIdx.x * blockDim.x + threadIdx.x; e < E; e += stride) {
        atomicAdd(&deg[ei[e]], 1.0f);
        atomicAdd(&cnt[ei[E + e] + 1], 1);
    }
}

__global__ void dinv_kernel(float* __restrict__ deg, int n) {
    int i = blockIdx.x * blockDim.x + threadIdx.x;
    if (i < n) {
        float d = deg[i];
        deg[i] = (d > 0.0f) ? (1.0f / sqrtf(fmaxf(d, 1.0f))) : 0.0f;
    }
}

// single-block scan: rowptr[i+1] = inclusive sum; cursor[i] = exclusive sum
__global__ void scan_kernel(int* __restrict__ rowptr, int* __restrict__ cursor, int n) {
    __shared__ int wsum[16];
    __shared__ int carry_s;
    if (threadIdx.x == 0) carry_s = 0;
    __syncthreads();
    int nchunk = (n + 1023) / 1024;
    int wid = threadIdx.x >> 6, lane = threadIdx.x & 63;
    for (int c = 0; c < nchunk; ++c) {
        int i = c * 1024 + threadIdx.x;
        int v = (i < n) ? rowptr[i + 1] : 0;
        int s = v;
        for (int off = 1; off < 64; off <<= 1) {
            int t = __shfl_up(s, off, 64);
            if (lane >= off) s += t;
        }
        if (lane == 63) wsum[wid] = s;
        __syncthreads();
        if (wid == 0 && lane < 16) {
            int wsv = wsum[lane];
            for (int off = 1; off < 16; off <<= 1) {
                int t = __shfl_up(wsv, off, 64);
                if (lane >= off) wsv += t;
            }
            wsum[lane] = wsv;
        }
        __syncthreads();
        int base = carry_s + (wid > 0 ? wsum[wid - 1] : 0);
        int inc = base + s;
        if (i < n) { rowptr[i + 1] = inc; cursor[i] = inc - v; }
        __syncthreads();
        if (threadIdx.x == 1023) carry_s = inc;
        __syncthreads();
    }
}

// scatter edges into dst-sorted CSR slots; wnorm = -dinv[src]*dinv[dst]
__global__ void fill_kernel(const int* __restrict__ ei, const float* __restrict__ dinv,
                            int* __restrict__ cursor, int* __restrict__ colidx,
                            float* __restrict__ wnorm, int E) {
    int stride = gridDim.x * blockDim.x;
    for (int e = blockIdx.x * blockDim.x + threadIdx.x; e < E; e += stride) {
        int s = ei[e];
        int d = ei[E + e];
        int slot = atomicAdd(&cursor[d], 1);
        colidx[slot] = s;
        wnorm[slot] = -dinv[s] * dinv[d];
    }
}

// XT[node] = [ x[node] (64) | segsum64(x)[node] (64) ]  — one wave per node
__global__ void xt_kernel(const float* __restrict__ x, const int* __restrict__ rowptr,
                          const int* __restrict__ colidx, const float* __restrict__ wnorm,
                          float* __restrict__ XT, int n) {
    int node = (blockIdx.x * blockDim.x + threadIdx.x) >> 6;
    int lane = threadIdx.x & 63;
    if (node >= n) return;
    int j0 = rowptr[node], j1 = rowptr[node + 1];
    float a = 0.0f;
    for (int j = j0; j < j1; ++j)
        a += wnorm[j] * x[(size_t)colidx[j] * 64 + lane];
    XT[(size_t)node * 128 + lane] = x[(size_t)node * 64 + lane];
    XT[(size_t)node * 128 + 64 + lane] = a;
}

// C[Nrows x Ncols] = relu?( A[Nrows x K] @ Bcat + biascat )
// Bcat columns [0,split) come from B0 (K x split), [split,Ncols) from B1.
__global__ __launch_bounds__(256) void gemm_tiled(
    const float* __restrict__ A, int lda,
    const float* __restrict__ B0, const float* __restrict__ B1,
    const float* __restrict__ bias0, const float* __restrict__ bias1,
    float* __restrict__ C, int Nrows, int K, int Ncols, int split, int relu) {
    __shared__ float As[BK * BMp];  // transposed: As[k][m]
    __shared__ float Bs[BK * BNp];  // Bs[k][n]
    const int bm = blockIdx.y * BM, bn = blockIdx.x * BN;
    const int tid = threadIdx.x;
    const int tx = tid & 15, ty = tid >> 4;
    const int kq = tid & 7, mrow = tid >> 3;   // A loader
    const int nq = tid & 15, krow = tid >> 4;  // B loader
    const int ldb0 = split, ldb1 = Ncols - split;
    float acc[4][4] = {};
    for (int k0 = 0; k0 < K; k0 += BK) {
#pragma unroll
        for (int half = 0; half < 2; ++half) {
            int m = mrow + half * 32;
            int row = bm + m;
            int kk = k0 + kq * 4;
            float4 v = {0, 0, 0, 0};
            if (row < Nrows) {
                if (kk + 3 < K) v = *(const float4*)&A[(size_t)row * lda + kk];
                else if (kk < K) {
                    float t[4] = {0, 0, 0, 0};
                    for (int i = 0; i < 4; ++i) if (kk + i < K) t[i] = A[(size_t)row * lda + kk + i];
                    v.x = t[0]; v.y = t[1]; v.z = t[2]; v.w = t[3];
                }
            }
            As[(kq * 4 + 0) * BMp + m] = v.x;
            As[(kq * 4 + 1) * BMp + m] = v.y;
            As[(kq * 4 + 2) * BMp + m] = v.z;
            As[(kq * 4 + 3) * BMp + m] = v.w;
        }
#pragma unroll
        for (int half = 0; half < 2; ++half) {
            int k = krow + half * 16;
            int kk = k0 + k;
            int col = bn + nq * 4;
            float4 v = {0, 0, 0, 0};
            if (kk < K && col < Ncols) {
                if (col < split) v = *(const float4*)&B0[(size_t)kk * ldb0 + col];
                else             v = *(const float4*)&B1[(size_t)kk * ldb1 + (col - split)];
            }
            *(float4*)&Bs[k * BNp + nq * 4] = v;
        }
        __syncthreads();
#pragma unroll
        for (int k = 0; k < BK; ++k) {
            float4 av = *(const float4*)&As[k * BMp + ty * 4];
            float4 bv = *(const float4*)&Bs[k * BNp + tx * 4];
            acc[0][0] += av.x * bv.x; acc[0][1] += av.x * bv.y; acc[0][2] += av.x * bv.z; acc[0][3] += av.x * bv.w;
            acc[1][0] += av.y * bv.x; acc[1][1] += av.y * bv.y; acc[1][2] += av.y * bv.z; acc[1][3] += av.y * bv.w;
            acc[2][0] += av.z * bv.x; acc[2][1] += av.z * bv.y; acc[2][2] += av.z * bv.z; acc[2][3] += av.z * bv.w;
            acc[3][0] += av.w * bv.x; acc[3][1] += av.w * bv.y; acc[3][2] += av.w * bv.z; acc[3][3] += av.w * bv.w;
        }
        __syncthreads();
    }
    const int c = bn + tx * 4;
    if (c >= Ncols) return;
    float bvals[4];
#pragma unroll
    for (int j = 0; j < 4; ++j) {
        int cj = c + j;
        bvals[j] = (cj < split) ? (bias0 ? bias0[cj] : 0.0f)
                                : (bias1 ? bias1[cj - split] : 0.0f);
    }
#pragma unroll
    for (int i = 0; i < 4; ++i) {
        int r = bm + ty * 4 + i;
        if (r >= Nrows) break;
        float4 o;
        o.x = acc[i][0] + bvals[0];
        o.y = acc[i][1] + bvals[1];
        o.z = acc[i][2] + bvals[2];
        o.w = acc[i][3] + bvals[3];
        if (relu) {
            o.x = fmaxf(o.x, 0.0f); o.y = fmaxf(o.y, 0.0f);
            o.z = fmaxf(o.z, 0.0f); o.w = fmaxf(o.w, 0.0f);
        }
        *(float4*)&C[(size_t)r * Ncols + c] = o;
    }
}

// t[node,f] = sum_j wnorm[j] * src[colidx[j]*ld + f], f<100; one block per node
__global__ void csr_segsum100_kernel(const float* __restrict__ src, int ld,
                                     const int* __restrict__ rowptr, const int* __restrict__ colidx,
                                     const float* __restrict__ wnorm, float* __restrict__ out, int n) {
    int node = blockIdx.x;
    int f = threadIdx.x;
    if (f >= 100) return;
    int j0 = rowptr[node], j1 = rowptr[node + 1];
    float a = 0.0f;
    for (int j = j0; j < j1; ++j)
        a += wnorm[j] * src[(size_t)colidx[j] * ld + f];
    out[(size_t)node * 100 + f] = a;
}

// x1 = relu(G2[:,0:100] + t + b2)
__global__ void combine1_kernel(const float* __restrict__ G2, const float* __restrict__ t,
                                const float* __restrict__ b2, float* __restrict__ x1, int n) {
    int idx = blockIdx.x * blockDim.x + threadIdx.x;
    if (idx >= n * 25) return;
    int i = idx / 25, q = idx % 25;
    float4 g = *(const float4*)&G2[(size_t)i * 200 + q * 4];
    float4 tv = *(const float4*)&t[(size_t)i * 100 + q * 4];
    float4 bv = *(const float4*)&b2[q * 4];
    float4 o;
    o.x = fmaxf(g.x + tv.x + bv.x, 0.0f);
    o.y = fmaxf(g.y + tv.y + bv.y, 0.0f);
    o.z = fmaxf(g.z + tv.z + bv.z, 0.0f);
    o.w = fmaxf(g.w + tv.w + bv.w, 0.0f);
    *(float4*)&x1[(size_t)i * 100 + q * 4] = o;
}

// xo = x1 + relu(S[:,0:100]) (f32); zb = bf16(x1 + relu(S[:,100:200])), rows
// padded to 128 elements (256B) with zeros.
__global__ void combine2_kernel(const float* __restrict__ S, const float* __restrict__ x1,
                                float* __restrict__ xo, ushort_t* __restrict__ zb, int n) {
    int idx = blockIdx.x * blockDim.x + threadIdx.x;
    if (idx >= n * 32) return;
    int i = idx >> 5, q = idx & 31;
    if (q < 25) {
        float4 s1 = *(const float4*)&S[(size_t)i * 200 + q * 4];
        float4 s2 = *(const float4*)&S[(size_t)i * 200 + 100 + q * 4];
        float4 xv = *(const float4*)&x1[(size_t)i * 100 + q * 4];
        float4 a, b;
        a.x = xv.x + fmaxf(s1.x, 0.0f); a.y = xv.y + fmaxf(s1.y, 0.0f);
        a.z = xv.z + fmaxf(s1.z, 0.0f); a.w = xv.w + fmaxf(s1.w, 0.0f);
        b.x = xv.x + fmaxf(s2.x, 0.0f); b.y = xv.y + fmaxf(s2.y, 0.0f);
        b.z = xv.z + fmaxf(s2.z, 0.0f); b.w = xv.w + fmaxf(s2.w, 0.0f);
        *(float4*)&xo[(size_t)i * 100 + q * 4] = a;
        uint2 p;
        p.x = (unsigned)f2bf(b.x) | ((unsigned)f2bf(b.y) << 16);
        p.y = (unsigned)f2bf(b.z) | ((unsigned)f2bf(b.w) << 16);
        *(uint2*)&zb[(size_t)i * 128 + q * 4] = p;
    } else {
        uint2 p; p.x = 0u; p.y = 0u;
        *(uint2*)&zb[(size_t)i * 128 + q * 4] = p;
    }
}

// fused pos+neg loss, 16 lanes per edge over bf16 z rows (256B, 2 lines)
__global__ void edge_loss_kernel(const ushort_t* __restrict__ zb, const int* __restrict__ ei,
                                 const int* __restrict__ nei, int E, float* __restrict__ acc) {
    const int l = threadIdx.x & 15;
    const int g = (blockIdx.x * blockDim.x + threadIdx.x) >> 4;
    const int ng = (gridDim.x * blockDim.x) >> 4;
    const int total = 2 * E;
    float s0 = 0.0f, s1 = 0.0f;
    for (int idx = g; idx < total; idx += ng) {
        const int pos = (idx < E);
        const int* lst = pos ? ei : nei;
        const int e = pos ? idx : idx - E;
        const int a = lst[e];
        const int b = lst[E + e];
        uint4 wa = ((const uint4*)(zb + (size_t)a * 128))[l];
        uint4 wb = ((const uint4*)(zb + (size_t)b * 128))[l];
        float part = bflo(wa.x) * bflo(wb.x) + bfhi(wa.x) * bfhi(wb.x)
                   + bflo(wa.y) * bflo(wb.y) + bfhi(wa.y) * bfhi(wb.y)
                   + bflo(wa.z) * bflo(wb.z) + bfhi(wa.z) * bfhi(wb.z)
                   + bflo(wa.w) * bflo(wb.w) + bfhi(wa.w) * bfhi(wb.w);
#pragma unroll
        for (int off = 8; off > 0; off >>= 1)
            part += __shfl_xor(part, off, 16);
        if (l == 0) {
            float sg = 1.0f / (1.0f + expf(-part));
            if (pos) s0 += logf(sg + 1e-15f);
            else     s1 += logf(1.0f - sg + 1e-15f);
        }
    }
    __shared__ float r0[256], r1[256];
    r0[threadIdx.x] = s0; r1[threadIdx.x] = s1;
    __syncthreads();
    for (int s = 128; s > 0; s >>= 1) {
        if (threadIdx.x < s) { r0[threadIdx.x] += r0[threadIdx.x + s]; r1[threadIdx.x] += r1[threadIdx.x + s]; }
        __syncthreads();
    }
    if (threadIdx.x == 0) { atomicAdd(&acc[0], r0[0]); atomicAdd(&acc[1], r1[0]); }
}

// sv[i] = xo[i,:] @ w (100-dim)
__global__ void rowdot_kernel(const float* __restrict__ xo, const float* __restrict__ w,
                              float* __restrict__ s, int n) {
    int i = blockIdx.x * blockDim.x + threadIdx.x;
    if (i >= n) return;
    const float4* a = (const float4*)(xo + (size_t)i * 100);
    const float4* wv = (const float4*)w;
    float acc = 0.0f;
#pragma unroll
    for (int q = 0; q < 25; ++q) {
        float4 va = a[q], vw = wv[q];
        acc += va.x * vw.x + va.y * vw.y + va.z * vw.z + va.w * vw.w;
    }
    s[i] = acc;
}

// out[i] = xo[i,:]@W3[0] + b3 + sum_j wnorm[j]*sv[colidx[j]]
__global__ void out_kernel(const float* __restrict__ xo, const float* __restrict__ W3,
                           const float* __restrict__ b3, const int* __restrict__ rowptr,
                           const int* __restrict__ colidx, const float* __restrict__ wnorm,
                           const float* __restrict__ sv, float* __restrict__ out, int n) {
    int i = blockIdx.x * blockDim.x + threadIdx.x;
    if (i >= n) return;
    const float4* a = (const float4*)(xo + (size_t)i * 100);
    const float4* wv = (const float4*)W3;
    float acc = b3[0];
#pragma unroll
    for (int q = 0; q < 25; ++q) {
        float4 va = a[q], vw = wv[q];
        acc += va.x * vw.x + va.y * vw.y + va.z * vw.z + va.w * vw.w;
    }
    int j1 = rowptr[i + 1];
    for (int j = rowptr[i]; j < j1; ++j)
        acc += wnorm[j] * sv[colidx[j]];
    out[i] = acc;
}

__global__ void finalize_kernel(float* __restrict__ out, const float* __restrict__ acc,
                                const float* __restrict__ c1, const float* __restrict__ c2,
                                int Nn, int E) {
    out[Nn]     = -(acc[0] + acc[1]) / (float)E;
    out[Nn + 1] = c1[0];
    out[Nn + 2] = c2[0];
}

extern "C" void kernel_launch(void* const* d_in, const int* in_sizes, int n_in,
                              void* d_out, int out_size, void* d_ws, size_t ws_size,
                              hipStream_t stream) {
    (void)n_in; (void)out_size; (void)ws_size;
    const float* x   = (const float*)d_in[0];
    const int*   ei  = (const int*)d_in[1];
    const int*   nei = (const int*)d_in[2];
    const float* W1  = (const float*)d_in[3];
    const float* b1  = (const float*)d_in[4];
    const float* W2  = (const float*)d_in[5];
    const float* b2  = (const float*)d_in[6];
    const float* W3  = (const float*)d_in[7];
    const float* b3  = (const float*)d_in[8];
    const float* lw1 = (const float*)d_in[9];
    const float* lb1 = (const float*)d_in[10];
    const float* lw2 = (const float*)d_in[11];
    const float* lb2 = (const float*)d_in[12];
    const float* c1  = (const float*)d_in[13];
    const float* c2  = (const float*)d_in[14];

    const int Nn = in_sizes[0] / 64;   // 13627
    const int E  = in_sizes[1] / 2;    // 504378

    const size_t Nal = ((size_t)Nn + 5) & ~(size_t)3;   // >= N+1, mult of 4
    const size_t Eal = ((size_t)E + 3) & ~(size_t)3;

    float* ws     = (float*)d_ws;
    float* dinv   = ws;                           // Nal floats
    int*   rowptr = (int*)(dinv + Nal);           // Nal ints (N+1 used)
    float* acc    = (float*)(rowptr + Nal);       // 4 floats
    int*   cursor = (int*)(acc + 4);              // Nal ints
    int*   colidx = cursor + Nal;                 // Eal ints
    float* wnorm  = (float*)(colidx + Eal);       // Eal floats
    float* XT     = wnorm + Eal;                  // N*128 (reused as t: N*100)
    float* h      = XT + (size_t)Nn * 128;        // N*300 (reused as S: N*200)
    float* G2     = h  + (size_t)Nn * 300;        // N*200
    float* x1     = G2 + (size_t)Nn * 200;        // N*100
    float* xo     = x1 + (size_t)Nn * 100;        // N*100
    ushort_t* zb  = (ushort_t*)(xo + (size_t)Nn * 100);  // N*128 bf16 (= N*64 floats)
    float* sv     = (float*)(zb + (size_t)Nn * 128);     // Nal
    float* t      = XT;                           // alias (XT dead after conv1)
    float* S      = h;                            // alias (h dead after conv2 gemm)

    // --- zero dinv + rowptr + acc in one memset ---
    hipMemsetAsync(dinv, 0, (2 * Nal + 4) * sizeof(float), stream);

    // --- CSR build + norm ---
    deg_hist_kernel<<<1024, 256, 0, stream>>>(ei, dinv, rowptr, E);
    dinv_kernel<<<(Nn + 255) / 256, 256, 0, stream>>>(dinv, Nn);
    scan_kernel<<<1, 1024, 0, stream>>>(rowptr, cursor, Nn);
    fill_kernel<<<1024, 256, 0, stream>>>(ei, dinv, cursor, colidx, wnorm, E);

    // --- conv1: XT = [x | segsum64(x)]; h = relu(XT @ W1cat + b1) ---
    xt_kernel<<<(Nn + 3) / 4, 256, 0, stream>>>(x, rowptr, colidx, wnorm, XT, Nn);
    gemm_tiled<<<dim3(5, (Nn + BM - 1) / BM), 256, 0, stream>>>(
        XT, 128, W1, nullptr, b1, nullptr, h, Nn, 128, 300, 300, 1);

    // --- conv2 fused: G2 = h @ [W2[0] | W2[1]] ---
    gemm_tiled<<<dim3(4, (Nn + BM - 1) / BM), 256, 0, stream>>>(
        h, 300, W2, W2 + 300 * 100, nullptr, nullptr, G2, Nn, 300, 200, 100, 0);
    // t = segsum(G2[:,100:200]); x1 = relu(G2[:,0:100] + t + b2)
    csr_segsum100_kernel<<<Nn, 128, 0, stream>>>(G2 + 100, 200, rowptr, colidx, wnorm, t, Nn);
    combine1_kernel<<<(Nn * 25 + 255) / 256, 256, 0, stream>>>(G2, t, b2, x1, Nn);

    // --- skips fused: S = x @ [lw1|lw2] + [lb1|lb2]; xo = x1+relu(S0), zb = bf16(x1+relu(S1)) ---
    gemm_tiled<<<dim3(4, (Nn + BM - 1) / BM), 256, 0, stream>>>(
        x, 64, lw1, lw2, lb1, lb2, S, Nn, 64, 200, 100, 0);
    combine2_kernel<<<(Nn * 32 + 255) / 256, 256, 0, stream>>>(S, x1, xo, zb, Nn);

    // --- edge reconstruction losses (pos+neg fused, 16 lanes/edge, bf16 z) ---
    edge_loss_kernel<<<4096, 256, 0, stream>>>(zb, ei, nei, E, acc);

    // --- conv3 (width 1): sv = xo@W3[1]; out = xo@W3[0] + segsum(sv) + b3 ---
    rowdot_kernel<<<(Nn + 255) / 256, 256, 0, stream>>>(xo, W3 + 100, sv, Nn);
    out_kernel<<<(Nn + 255) / 256, 256, 0, stream>>>(xo, W3, b3, rowptr, colidx, wnorm,
                                                     sv, (float*)d_out, Nn);

    finalize_kernel<<<1, 1, 0, stream>>>((float*)d_out, acc, c1, c2, Nn, E);
}

// Round 6
// 426.907 us; speedup vs baseline: 3.4051x; 1.0865x over previous
//
#include <hip/hip_runtime.h>
#include <math.h>

// ---------------------------------------------------------------------------
// Net_1503238553644: 2-layer ChebConv(K=2) GNN + linear skips + edge recon loss
// N=13627, E=504378, F=64, H1=300, H2=100, LIN=100
// R6: edge_loss 2-edge ILP unroll; conv2 segsum -> bf16 L2-resident rows with
//     wave-per-node 4-edge-in-flight gather (was block-per-node f32, 202MB).
// ---------------------------------------------------------------------------

#define BM 64
#define BN 64
#define BK 32
#define BMp 68
#define BNp 68

typedef unsigned short ushort_t;

__device__ inline ushort_t f2bf(float f) {           // RNE float->bf16
    unsigned u = __float_as_uint(f);
    u += 0x7fff + ((u >> 16) & 1);
    return (ushort_t)(u >> 16);
}
__device__ inline float bflo(unsigned w) { return __uint_as_float(w << 16); }
__device__ inline float bfhi(unsigned w) { return __uint_as_float(w & 0xffff0000u); }

// deg[src[e]] += 1 (float); cnt[dst[e]+1] += 1 (CSR histogram)
__global__ void deg_hist_kernel(const int* __restrict__ ei, float* __restrict__ deg,
                                int* __restrict__ cnt, int E) {
    int stride = gridDim.x * blockDim.x;
    for (int e = blockIdx.x * blockDim.x + threadIdx.x; e < E; e += stride) {
        atomicAdd(&deg[ei[e]], 1.0f);
        atomicAdd(&cnt[ei[E + e] + 1], 1);
    }
}

__global__ void dinv_kernel(float* __restrict__ deg, int n) {
    int i = blockIdx.x * blockDim.x + threadIdx.x;
    if (i < n) {
        float d = deg[i];
        deg[i] = (d > 0.0f) ? (1.0f / sqrtf(fmaxf(d, 1.0f))) : 0.0f;
    }
}

// single-block scan: rowptr[i+1] = inclusive sum; cursor[i] = exclusive sum
__global__ void scan_kernel(int* __restrict__ rowptr, int* __restrict__ cursor, int n) {
    __shared__ int wsum[16];
    __shared__ int carry_s;
    if (threadIdx.x == 0) carry_s = 0;
    __syncthreads();
    int nchunk = (n + 1023) / 1024;
    int wid = threadIdx.x >> 6, lane = threadIdx.x & 63;
    for (int c = 0; c < nchunk; ++c) {
        int i = c * 1024 + threadIdx.x;
        int v = (i < n) ? rowptr[i + 1] : 0;
        int s = v;
        for (int off = 1; off < 64; off <<= 1) {
            int t = __shfl_up(s, off, 64);
            if (lane >= off) s += t;
        }
        if (lane == 63) wsum[wid] = s;
        __syncthreads();
        if (wid == 0 && lane < 16) {
            int wsv = wsum[lane];
            for (int off = 1; off < 16; off <<= 1) {
                int t = __shfl_up(wsv, off, 64);
                if (lane >= off) wsv += t;
            }
            wsum[lane] = wsv;
        }
        __syncthreads();
        int base = carry_s + (wid > 0 ? wsum[wid - 1] : 0);
        int inc = base + s;
        if (i < n) { rowptr[i + 1] = inc; cursor[i] = inc - v; }
        __syncthreads();
        if (threadIdx.x == 1023) carry_s = inc;
        __syncthreads();
    }
}

// scatter edges into dst-sorted CSR slots; wnorm = -dinv[src]*dinv[dst]
__global__ void fill_kernel(const int* __restrict__ ei, const float* __restrict__ dinv,
                            int* __restrict__ cursor, int* __restrict__ colidx,
                            float* __restrict__ wnorm, int E) {
    int stride = gridDim.x * blockDim.x;
    for (int e = blockIdx.x * blockDim.x + threadIdx.x; e < E; e += stride) {
        int s = ei[e];
        int d = ei[E + e];
        int slot = atomicAdd(&cursor[d], 1);
        colidx[slot] = s;
        wnorm[slot] = -dinv[s] * dinv[d];
    }
}

// XT[node] = [ x[node] (64) | segsum64(x)[node] (64) ]  — one wave per node
__global__ void xt_kernel(const float* __restrict__ x, const int* __restrict__ rowptr,
                          const int* __restrict__ colidx, const float* __restrict__ wnorm,
                          float* __restrict__ XT, int n) {
    int node = (blockIdx.x * blockDim.x + threadIdx.x) >> 6;
    int lane = threadIdx.x & 63;
    if (node >= n) return;
    int j0 = rowptr[node], j1 = rowptr[node + 1];
    float a = 0.0f;
    for (int j = j0; j < j1; ++j)
        a += wnorm[j] * x[(size_t)colidx[j] * 64 + lane];
    XT[(size_t)node * 128 + lane] = x[(size_t)node * 64 + lane];
    XT[(size_t)node * 128 + 64 + lane] = a;
}

// C[Nrows x Ncols] = relu?( A[Nrows x K] @ Bcat + biascat )
// Bcat columns [0,split) come from B0 (K x split), [split,Ncols) from B1.
__global__ __launch_bounds__(256) void gemm_tiled(
    const float* __restrict__ A, int lda,
    const float* __restrict__ B0, const float* __restrict__ B1,
    const float* __restrict__ bias0, const float* __restrict__ bias1,
    float* __restrict__ C, int Nrows, int K, int Ncols, int split, int relu) {
    __shared__ float As[BK * BMp];  // transposed: As[k][m]
    __shared__ float Bs[BK * BNp];  // Bs[k][n]
    const int bm = blockIdx.y * BM, bn = blockIdx.x * BN;
    const int tid = threadIdx.x;
    const int tx = tid & 15, ty = tid >> 4;
    const int kq = tid & 7, mrow = tid >> 3;   // A loader
    const int nq = tid & 15, krow = tid >> 4;  // B loader
    const int ldb0 = split, ldb1 = Ncols - split;
    float acc[4][4] = {};
    for (int k0 = 0; k0 < K; k0 += BK) {
#pragma unroll
        for (int half = 0; half < 2; ++half) {
            int m = mrow + half * 32;
            int row = bm + m;
            int kk = k0 + kq * 4;
            float4 v = {0, 0, 0, 0};
            if (row < Nrows) {
                if (kk + 3 < K) v = *(const float4*)&A[(size_t)row * lda + kk];
                else if (kk < K) {
                    float t[4] = {0, 0, 0, 0};
                    for (int i = 0; i < 4; ++i) if (kk + i < K) t[i] = A[(size_t)row * lda + kk + i];
                    v.x = t[0]; v.y = t[1]; v.z = t[2]; v.w = t[3];
                }
            }
            As[(kq * 4 + 0) * BMp + m] = v.x;
            As[(kq * 4 + 1) * BMp + m] = v.y;
            As[(kq * 4 + 2) * BMp + m] = v.z;
            As[(kq * 4 + 3) * BMp + m] = v.w;
        }
#pragma unroll
        for (int half = 0; half < 2; ++half) {
            int k = krow + half * 16;
            int kk = k0 + k;
            int col = bn + nq * 4;
            float4 v = {0, 0, 0, 0};
            if (kk < K && col < Ncols) {
                if (col < split) v = *(const float4*)&B0[(size_t)kk * ldb0 + col];
                else             v = *(const float4*)&B1[(size_t)kk * ldb1 + (col - split)];
            }
            *(float4*)&Bs[k * BNp + nq * 4] = v;
        }
        __syncthreads();
#pragma unroll
        for (int k = 0; k < BK; ++k) {
            float4 av = *(const float4*)&As[k * BMp + ty * 4];
            float4 bv = *(const float4*)&Bs[k * BNp + tx * 4];
            acc[0][0] += av.x * bv.x; acc[0][1] += av.x * bv.y; acc[0][2] += av.x * bv.z; acc[0][3] += av.x * bv.w;
            acc[1][0] += av.y * bv.x; acc[1][1] += av.y * bv.y; acc[1][2] += av.y * bv.z; acc[1][3] += av.y * bv.w;
            acc[2][0] += av.z * bv.x; acc[2][1] += av.z * bv.y; acc[2][2] += av.z * bv.z; acc[2][3] += av.z * bv.w;
            acc[3][0] += av.w * bv.x; acc[3][1] += av.w * bv.y; acc[3][2] += av.w * bv.z; acc[3][3] += av.w * bv.w;
        }
        __syncthreads();
    }
    const int c = bn + tx * 4;
    if (c >= Ncols) return;
    float bvals[4];
#pragma unroll
    for (int j = 0; j < 4; ++j) {
        int cj = c + j;
        bvals[j] = (cj < split) ? (bias0 ? bias0[cj] : 0.0f)
                                : (bias1 ? bias1[cj - split] : 0.0f);
    }
#pragma unroll
    for (int i = 0; i < 4; ++i) {
        int r = bm + ty * 4 + i;
        if (r >= Nrows) break;
        float4 o;
        o.x = acc[i][0] + bvals[0];
        o.y = acc[i][1] + bvals[1];
        o.z = acc[i][2] + bvals[2];
        o.w = acc[i][3] + bvals[3];
        if (relu) {
            o.x = fmaxf(o.x, 0.0f); o.y = fmaxf(o.y, 0.0f);
            o.z = fmaxf(o.z, 0.0f); o.w = fmaxf(o.w, 0.0f);
        }
        *(float4*)&C[(size_t)r * Ncols + c] = o;
    }
}

// pack src[:, off:off+w] (f32, stride ld) -> dst bf16 rows padded to 128 (zeros)
__global__ void pack_bf16_kernel(const float* __restrict__ src, int ld, int off, int w,
                                 ushort_t* __restrict__ dst, int n) {
    int idx = blockIdx.x * blockDim.x + threadIdx.x;
    if (idx >= n * 32) return;
    int i = idx >> 5, q = idx & 31;
    uint2 p = {0u, 0u};
    if (q * 4 < w) {
        float4 v = *(const float4*)&src[(size_t)i * ld + off + q * 4];
        p.x = (unsigned)f2bf(v.x) | ((unsigned)f2bf(v.y) << 16);
        p.y = (unsigned)f2bf(v.z) | ((unsigned)f2bf(v.w) << 16);
    }
    *(uint2*)&dst[(size_t)i * 128 + q * 4] = p;
}

// t[node,0:100] = sum_j wnorm[j] * hb[colidx[j], :] — bf16 rows of 128 (256B),
// one wave per node, 4 edges in flight (16-lane groups), cross-group reduce.
__global__ void csr_segsum_bf16_kernel(const ushort_t* __restrict__ hb,
                                       const int* __restrict__ rowptr, const int* __restrict__ colidx,
                                       const float* __restrict__ wnorm, float* __restrict__ t, int n) {
    int node = (blockIdx.x * blockDim.x + threadIdx.x) >> 6;
    if (node >= n) return;
    int lane = threadIdx.x & 63;
    int grp = lane >> 4;
    int l = lane & 15;
    int j0 = rowptr[node], j1 = rowptr[node + 1];
    float acc[8] = {};
    for (int j = j0 + grp; j < j1; j += 4) {
        int c = colidx[j];
        float w = wnorm[j];
        uint4 v = ((const uint4*)(hb + (size_t)c * 128))[l];
        acc[0] += w * bflo(v.x); acc[1] += w * bfhi(v.x);
        acc[2] += w * bflo(v.y); acc[3] += w * bfhi(v.y);
        acc[4] += w * bflo(v.z); acc[5] += w * bfhi(v.z);
        acc[6] += w * bflo(v.w); acc[7] += w * bfhi(v.w);
    }
#pragma unroll
    for (int k = 0; k < 8; ++k) {
        acc[k] += __shfl_xor(acc[k], 16, 64);
        acc[k] += __shfl_xor(acc[k], 32, 64);
    }
    if (grp == 0) {
        int f = l * 8;
        if (f + 8 <= 100) {
            float4 lo = {acc[0], acc[1], acc[2], acc[3]};
            float4 hi = {acc[4], acc[5], acc[6], acc[7]};
            *(float4*)&t[(size_t)node * 100 + f] = lo;
            *(float4*)&t[(size_t)node * 100 + f + 4] = hi;
        } else if (f < 100) {
            for (int k = 0; k < 8 && f + k < 100; ++k)
                t[(size_t)node * 100 + f + k] = acc[k];
        }
    }
}

// x1 = relu(G2[:,0:100] + t + b2)
__global__ void combine1_kernel(const float* __restrict__ G2, const float* __restrict__ t,
                                const float* __restrict__ b2, float* __restrict__ x1, int n) {
    int idx = blockIdx.x * blockDim.x + threadIdx.x;
    if (idx >= n * 25) return;
    int i = idx / 25, q = idx % 25;
    float4 g = *(const float4*)&G2[(size_t)i * 200 + q * 4];
    float4 tv = *(const float4*)&t[(size_t)i * 100 + q * 4];
    float4 bv = *(const float4*)&b2[q * 4];
    float4 o;
    o.x = fmaxf(g.x + tv.x + bv.x, 0.0f);
    o.y = fmaxf(g.y + tv.y + bv.y, 0.0f);
    o.z = fmaxf(g.z + tv.z + bv.z, 0.0f);
    o.w = fmaxf(g.w + tv.w + bv.w, 0.0f);
    *(float4*)&x1[(size_t)i * 100 + q * 4] = o;
}

// xo = x1 + relu(S[:,0:100]) (f32); zb = bf16(x1 + relu(S[:,100:200])), rows
// padded to 128 elements (256B) with zeros.
__global__ void combine2_kernel(const float* __restrict__ S, const float* __restrict__ x1,
                                float* __restrict__ xo, ushort_t* __restrict__ zb, int n) {
    int idx = blockIdx.x * blockDim.x + threadIdx.x;
    if (idx >= n * 32) return;
    int i = idx >> 5, q = idx & 31;
    if (q < 25) {
        float4 s1 = *(const float4*)&S[(size_t)i * 200 + q * 4];
        float4 s2 = *(const float4*)&S[(size_t)i * 200 + 100 + q * 4];
        float4 xv = *(const float4*)&x1[(size_t)i * 100 + q * 4];
        float4 a, b;
        a.x = xv.x + fmaxf(s1.x, 0.0f); a.y = xv.y + fmaxf(s1.y, 0.0f);
        a.z = xv.z + fmaxf(s1.z, 0.0f); a.w = xv.w + fmaxf(s1.w, 0.0f);
        b.x = xv.x + fmaxf(s2.x, 0.0f); b.y = xv.y + fmaxf(s2.y, 0.0f);
        b.z = xv.z + fmaxf(s2.z, 0.0f); b.w = xv.w + fmaxf(s2.w, 0.0f);
        *(float4*)&xo[(size_t)i * 100 + q * 4] = a;
        uint2 p;
        p.x = (unsigned)f2bf(b.x) | ((unsigned)f2bf(b.y) << 16);
        p.y = (unsigned)f2bf(b.z) | ((unsigned)f2bf(b.w) << 16);
        *(uint2*)&zb[(size_t)i * 128 + q * 4] = p;
    } else {
        uint2 p; p.x = 0u; p.y = 0u;
        *(uint2*)&zb[(size_t)i * 128 + q * 4] = p;
    }
}

// fused pos+neg loss, 16 lanes/edge, 2 edges in flight per group
__global__ void edge_loss_kernel(const ushort_t* __restrict__ zb, const int* __restrict__ ei,
                                 const int* __restrict__ nei, int E, float* __restrict__ acc) {
    const int l = threadIdx.x & 15;
    const int g = (blockIdx.x * blockDim.x + threadIdx.x) >> 4;
    const int ng = (gridDim.x * blockDim.x) >> 4;
    const int total = 2 * E;
    float s0 = 0.0f, s1 = 0.0f;
    for (int idx = g; idx < total; idx += 2 * ng) {
        const int idx2 = idx + ng;
        const bool has2 = (idx2 < total);
        const int pos1 = (idx < E);
        const int* lst1 = pos1 ? ei : nei;
        const int e1 = pos1 ? idx : idx - E;
        const int a1 = lst1[e1];
        const int b1 = lst1[E + e1];
        int pos2 = 0, a2 = 0, b2 = 0;
        if (has2) {
            pos2 = (idx2 < E);
            const int* lst2 = pos2 ? ei : nei;
            const int e2 = pos2 ? idx2 : idx2 - E;
            a2 = lst2[e2];
            b2 = lst2[E + e2];
        }
        uint4 wa1 = ((const uint4*)(zb + (size_t)a1 * 128))[l];
        uint4 wb1 = ((const uint4*)(zb + (size_t)b1 * 128))[l];
        uint4 wa2 = {0,0,0,0}, wb2 = {0,0,0,0};
        if (has2) {
            wa2 = ((const uint4*)(zb + (size_t)a2 * 128))[l];
            wb2 = ((const uint4*)(zb + (size_t)b2 * 128))[l];
        }
        float p1 = bflo(wa1.x) * bflo(wb1.x) + bfhi(wa1.x) * bfhi(wb1.x)
                 + bflo(wa1.y) * bflo(wb1.y) + bfhi(wa1.y) * bfhi(wb1.y)
                 + bflo(wa1.z) * bflo(wb1.z) + bfhi(wa1.z) * bfhi(wb1.z)
                 + bflo(wa1.w) * bflo(wb1.w) + bfhi(wa1.w) * bfhi(wb1.w);
        float p2 = bflo(wa2.x) * bflo(wb2.x) + bfhi(wa2.x) * bfhi(wb2.x)
                 + bflo(wa2.y) * bflo(wb2.y) + bfhi(wa2.y) * bfhi(wb2.y)
                 + bflo(wa2.z) * bflo(wb2.z) + bfhi(wa2.z) * bfhi(wb2.z)
                 + bflo(wa2.w) * bflo(wb2.w) + bfhi(wa2.w) * bfhi(wb2.w);
#pragma unroll
        for (int off = 8; off > 0; off >>= 1) {
            p1 += __shfl_xor(p1, off, 16);
            p2 += __shfl_xor(p2, off, 16);
        }
        if (l == 0) {
            float sg1 = 1.0f / (1.0f + expf(-p1));
            if (pos1) s0 += logf(sg1 + 1e-15f);
            else      s1 += logf(1.0f - sg1 + 1e-15f);
            if (has2) {
                float sg2 = 1.0f / (1.0f + expf(-p2));
                if (pos2) s0 += logf(sg2 + 1e-15f);
                else      s1 += logf(1.0f - sg2 + 1e-15f);
            }
        }
    }
    __shared__ float r0[256], r1[256];
    r0[threadIdx.x] = s0; r1[threadIdx.x] = s1;
    __syncthreads();
    for (int s = 128; s > 0; s >>= 1) {
        if (threadIdx.x < s) { r0[threadIdx.x] += r0[threadIdx.x + s]; r1[threadIdx.x] += r1[threadIdx.x + s]; }
        __syncthreads();
    }
    if (threadIdx.x == 0) { atomicAdd(&acc[0], r0[0]); atomicAdd(&acc[1], r1[0]); }
}

// sv[i] = xo[i,:] @ w (100-dim)
__global__ void rowdot_kernel(const float* __restrict__ xo, const float* __restrict__ w,
                              float* __restrict__ s, int n) {
    int i = blockIdx.x * blockDim.x + threadIdx.x;
    if (i >= n) return;
    const float4* a = (const float4*)(xo + (size_t)i * 100);
    const float4* wv = (const float4*)w;
    float acc = 0.0f;
#pragma unroll
    for (int q = 0; q < 25; ++q) {
        float4 va = a[q], vw = wv[q];
        acc += va.x * vw.x + va.y * vw.y + va.z * vw.z + va.w * vw.w;
    }
    s[i] = acc;
}

// out[i] = xo[i,:]@W3[0] + b3 + sum_j wnorm[j]*sv[colidx[j]]
__global__ void out_kernel(const float* __restrict__ xo, const float* __restrict__ W3,
                           const float* __restrict__ b3, const int* __restrict__ rowptr,
                           const int* __restrict__ colidx, const float* __restrict__ wnorm,
                           const float* __restrict__ sv, float* __restrict__ out, int n) {
    int i = blockIdx.x * blockDim.x + threadIdx.x;
    if (i >= n) return;
    const float4* a = (const float4*)(xo + (size_t)i * 100);
    const float4* wv = (const float4*)W3;
    float acc = b3[0];
#pragma unroll
    for (int q = 0; q < 25; ++q) {
        float4 va = a[q], vw = wv[q];
        acc += va.x * vw.x + va.y * vw.y + va.z * vw.z + va.w * vw.w;
    }
    int j1 = rowptr[i + 1];
    for (int j = rowptr[i]; j < j1; ++j)
        acc += wnorm[j] * sv[colidx[j]];
    out[i] = acc;
}

__global__ void finalize_kernel(float* __restrict__ out, const float* __restrict__ acc,
                                const float* __restrict__ c1, const float* __restrict__ c2,
                                int Nn, int E) {
    out[Nn]     = -(acc[0] + acc[1]) / (float)E;
    out[Nn + 1] = c1[0];
    out[Nn + 2] = c2[0];
}

extern "C" void kernel_launch(void* const* d_in, const int* in_sizes, int n_in,
                              void* d_out, int out_size, void* d_ws, size_t ws_size,
                              hipStream_t stream) {
    (void)n_in; (void)out_size; (void)ws_size;
    const float* x   = (const float*)d_in[0];
    const int*   ei  = (const int*)d_in[1];
    const int*   nei = (const int*)d_in[2];
    const float* W1  = (const float*)d_in[3];
    const float* b1  = (const float*)d_in[4];
    const float* W2  = (const float*)d_in[5];
    const float* b2  = (const float*)d_in[6];
    const float* W3  = (const float*)d_in[7];
    const float* b3  = (const float*)d_in[8];
    const float* lw1 = (const float*)d_in[9];
    const float* lb1 = (const float*)d_in[10];
    const float* lw2 = (const float*)d_in[11];
    const float* lb2 = (const float*)d_in[12];
    const float* c1  = (const float*)d_in[13];
    const float* c2  = (const float*)d_in[14];

    const int Nn = in_sizes[0] / 64;   // 13627
    const int E  = in_sizes[1] / 2;    // 504378

    const size_t Nal = ((size_t)Nn + 5) & ~(size_t)3;   // >= N+1, mult of 4
    const size_t Eal = ((size_t)E + 3) & ~(size_t)3;

    float* ws     = (float*)d_ws;
    float* dinv   = ws;                           // Nal floats
    int*   rowptr = (int*)(dinv + Nal);           // Nal ints (N+1 used)
    float* acc    = (float*)(rowptr + Nal);       // 4 floats
    int*   cursor = (int*)(acc + 4);              // Nal ints
    int*   colidx = cursor + Nal;                 // Eal ints
    float* wnorm  = (float*)(colidx + Eal);       // Eal floats
    float* XT     = wnorm + Eal;                  // N*128 (reused as t: N*100)
    float* h      = XT + (size_t)Nn * 128;        // N*300 (reused as S: N*200)
    float* G2     = h  + (size_t)Nn * 300;        // N*200
    float* x1     = G2 + (size_t)Nn * 200;        // N*100
    float* xo     = x1 + (size_t)Nn * 100;        // N*100
    ushort_t* zb  = (ushort_t*)(xo + (size_t)Nn * 100);  // N*128 bf16
    ushort_t* hWb = zb + (size_t)Nn * 128;                // N*128 bf16
    float* sv     = (float*)(hWb + (size_t)Nn * 128);     // Nal
    float* t      = XT;                           // alias (XT dead after conv1)
    float* S      = h;                            // alias (h dead after conv2 gemm)

    // --- zero dinv + rowptr + acc in one memset ---
    hipMemsetAsync(dinv, 0, (2 * Nal + 4) * sizeof(float), stream);

    // --- CSR build + norm ---
    deg_hist_kernel<<<1024, 256, 0, stream>>>(ei, dinv, rowptr, E);
    dinv_kernel<<<(Nn + 255) / 256, 256, 0, stream>>>(dinv, Nn);
    scan_kernel<<<1, 1024, 0, stream>>>(rowptr, cursor, Nn);
    fill_kernel<<<1024, 256, 0, stream>>>(ei, dinv, cursor, colidx, wnorm, E);

    // --- conv1: XT = [x | segsum64(x)]; h = relu(XT @ W1cat + b1) ---
    xt_kernel<<<(Nn + 3) / 4, 256, 0, stream>>>(x, rowptr, colidx, wnorm, XT, Nn);
    gemm_tiled<<<dim3(5, (Nn + BM - 1) / BM), 256, 0, stream>>>(
        XT, 128, W1, nullptr, b1, nullptr, h, Nn, 128, 300, 300, 1);

    // --- conv2 fused: G2 = h @ [W2[0] | W2[1]] ---
    gemm_tiled<<<dim3(4, (Nn + BM - 1) / BM), 256, 0, stream>>>(
        h, 300, W2, W2 + 300 * 100, nullptr, nullptr, G2, Nn, 300, 200, 100, 0);
    // hWb = bf16(G2[:,100:200]) L2-resident; t = segsum(hWb); x1 = relu(G2[:,0:100]+t+b2)
    pack_bf16_kernel<<<(Nn * 32 + 255) / 256, 256, 0, stream>>>(G2, 200, 100, 100, hWb, Nn);
    csr_segsum_bf16_kernel<<<(Nn + 3) / 4, 256, 0, stream>>>(hWb, rowptr, colidx, wnorm, t, Nn);
    combine1_kernel<<<(Nn * 25 + 255) / 256, 256, 0, stream>>>(G2, t, b2, x1, Nn);

    // --- skips fused: S = x @ [lw1|lw2] + [lb1|lb2]; xo = x1+relu(S0), zb = bf16(x1+relu(S1)) ---
    gemm_tiled<<<dim3(4, (Nn + BM - 1) / BM), 256, 0, stream>>>(
        x, 64, lw1, lw2, lb1, lb2, S, Nn, 64, 200, 100, 0);
    combine2_kernel<<<(Nn * 32 + 255) / 256, 256, 0, stream>>>(S, x1, xo, zb, Nn);

    // --- edge reconstruction losses (pos+neg fused, 16 lanes/edge, 2 edges in flight) ---
    edge_loss_kernel<<<4096, 256, 0, stream>>>(zb, ei, nei, E, acc);

    // --- conv3 (width 1): sv = xo@W3[1]; out = xo@W3[0] + segsum(sv) + b3 ---
    rowdot_kernel<<<(Nn + 255) / 256, 256, 0, stream>>>(xo, W3 + 100, sv, Nn);
    out_kernel<<<(Nn + 255) / 256, 256, 0, stream>>>(xo, W3, b3, rowptr, colidx, wnorm,
                                                     sv, (float*)d_out, Nn);

    finalize_kernel<<<1, 1, 0, stream>>>((float*)d_out, acc, c1, c2, Nn, E);
}

// Round 8
// 346.497 us; speedup vs baseline: 4.1954x; 1.2321x over previous
//
#include <hip/hip_runtime.h>
#include <math.h>

// ---------------------------------------------------------------------------
// Net_1503238553644: 2-layer ChebConv(K=2) GNN + linear skips + edge recon loss
// N=13627, E=504378, F=64, H1=300, H2=100, LIN=100
// R8: fix R7's edge-loss read truncation (8 lanes x uint2 = 64 elems) ->
//     8 lanes x uint4 = 128 fp8 = full 128B row. Pipeline/pairs unchanged.
// ---------------------------------------------------------------------------

#define BM 64
#define BN 64
#define BK 32
#define BMp 68
#define BNp 68

typedef unsigned short ushort_t;
typedef float v2f __attribute__((ext_vector_type(2)));

__device__ inline ushort_t f2bf(float f) {           // RNE float->bf16
    unsigned u = __float_as_uint(f);
    u += 0x7fff + ((u >> 16) & 1);
    return (ushort_t)(u >> 16);
}
__device__ inline float bflo(unsigned w) { return __uint_as_float(w << 16); }
__device__ inline float bfhi(unsigned w) { return __uint_as_float(w & 0xffff0000u); }

// deg[ei0[e]] += 1 (float); cnt[ei1[e]+1] += 1 (CSR histogram);
// pack edge pairs: pp[e] = (ei0[e], ei1[e]), pn[e] = (nei0[e], nei1[e])
__global__ void deg_hist_pairs_kernel(const int* __restrict__ ei, const int* __restrict__ nei,
                                      float* __restrict__ deg, int* __restrict__ cnt,
                                      int2* __restrict__ pp, int2* __restrict__ pn, int E) {
    int stride = gridDim.x * blockDim.x;
    for (int e = blockIdx.x * blockDim.x + threadIdx.x; e < E; e += stride) {
        int a = ei[e], b = ei[E + e];
        atomicAdd(&deg[a], 1.0f);
        atomicAdd(&cnt[b + 1], 1);
        pp[e] = make_int2(a, b);
        pn[e] = make_int2(nei[e], nei[E + e]);
    }
}

__global__ void dinv_kernel(float* __restrict__ deg, int n) {
    int i = blockIdx.x * blockDim.x + threadIdx.x;
    if (i < n) {
        float d = deg[i];
        deg[i] = (d > 0.0f) ? (1.0f / sqrtf(fmaxf(d, 1.0f))) : 0.0f;
    }
}

// single-block scan: rowptr[i+1] = inclusive sum; cursor[i] = exclusive sum
__global__ void scan_kernel(int* __restrict__ rowptr, int* __restrict__ cursor, int n) {
    __shared__ int wsum[16];
    __shared__ int carry_s;
    if (threadIdx.x == 0) carry_s = 0;
    __syncthreads();
    int nchunk = (n + 1023) / 1024;
    int wid = threadIdx.x >> 6, lane = threadIdx.x & 63;
    for (int c = 0; c < nchunk; ++c) {
        int i = c * 1024 + threadIdx.x;
        int v = (i < n) ? rowptr[i + 1] : 0;
        int s = v;
        for (int off = 1; off < 64; off <<= 1) {
            int t = __shfl_up(s, off, 64);
            if (lane >= off) s += t;
        }
        if (lane == 63) wsum[wid] = s;
        __syncthreads();
        if (wid == 0 && lane < 16) {
            int wsv = wsum[lane];
            for (int off = 1; off < 16; off <<= 1) {
                int t = __shfl_up(wsv, off, 64);
                if (lane >= off) wsv += t;
            }
            wsum[lane] = wsv;
        }
        __syncthreads();
        int base = carry_s + (wid > 0 ? wsum[wid - 1] : 0);
        int inc = base + s;
        if (i < n) { rowptr[i + 1] = inc; cursor[i] = inc - v; }
        __syncthreads();
        if (threadIdx.x == 1023) carry_s = inc;
        __syncthreads();
    }
}

// scatter edges into dst-sorted CSR slots; wnorm = -dinv[src]*dinv[dst]
__global__ void fill_kernel(const int* __restrict__ ei, const float* __restrict__ dinv,
                            int* __restrict__ cursor, int* __restrict__ colidx,
                            float* __restrict__ wnorm, int E) {
    int stride = gridDim.x * blockDim.x;
    for (int e = blockIdx.x * blockDim.x + threadIdx.x; e < E; e += stride) {
        int s = ei[e];
        int d = ei[E + e];
        int slot = atomicAdd(&cursor[d], 1);
        colidx[slot] = s;
        wnorm[slot] = -dinv[s] * dinv[d];
    }
}

// XT[node] = [ x[node] (64) | segsum64(x)[node] (64) ]  — one wave per node
__global__ void xt_kernel(const float* __restrict__ x, const int* __restrict__ rowptr,
                          const int* __restrict__ colidx, const float* __restrict__ wnorm,
                          float* __restrict__ XT, int n) {
    int node = (blockIdx.x * blockDim.x + threadIdx.x) >> 6;
    int lane = threadIdx.x & 63;
    if (node >= n) return;
    int j0 = rowptr[node], j1 = rowptr[node + 1];
    float a = 0.0f;
    for (int j = j0; j < j1; ++j)
        a += wnorm[j] * x[(size_t)colidx[j] * 64 + lane];
    XT[(size_t)node * 128 + lane] = x[(size_t)node * 64 + lane];
    XT[(size_t)node * 128 + 64 + lane] = a;
}

// C[Nrows x Ncols] = relu?( A[Nrows x K] @ Bcat + biascat )
// Bcat columns [0,split) come from B0 (K x split), [split,Ncols) from B1.
__global__ __launch_bounds__(256) void gemm_tiled(
    const float* __restrict__ A, int lda,
    const float* __restrict__ B0, const float* __restrict__ B1,
    const float* __restrict__ bias0, const float* __restrict__ bias1,
    float* __restrict__ C, int Nrows, int K, int Ncols, int split, int relu) {
    __shared__ float As[BK * BMp];  // transposed: As[k][m]
    __shared__ float Bs[BK * BNp];  // Bs[k][n]
    const int bm = blockIdx.y * BM, bn = blockIdx.x * BN;
    const int tid = threadIdx.x;
    const int tx = tid & 15, ty = tid >> 4;
    const int kq = tid & 7, mrow = tid >> 3;   // A loader
    const int nq = tid & 15, krow = tid >> 4;  // B loader
    const int ldb0 = split, ldb1 = Ncols - split;
    float acc[4][4] = {};
    for (int k0 = 0; k0 < K; k0 += BK) {
#pragma unroll
        for (int half = 0; half < 2; ++half) {
            int m = mrow + half * 32;
            int row = bm + m;
            int kk = k0 + kq * 4;
            float4 v = {0, 0, 0, 0};
            if (row < Nrows) {
                if (kk + 3 < K) v = *(const float4*)&A[(size_t)row * lda + kk];
                else if (kk < K) {
                    float t[4] = {0, 0, 0, 0};
                    for (int i = 0; i < 4; ++i) if (kk + i < K) t[i] = A[(size_t)row * lda + kk + i];
                    v.x = t[0]; v.y = t[1]; v.z = t[2]; v.w = t[3];
                }
            }
            As[(kq * 4 + 0) * BMp + m] = v.x;
            As[(kq * 4 + 1) * BMp + m] = v.y;
            As[(kq * 4 + 2) * BMp + m] = v.z;
            As[(kq * 4 + 3) * BMp + m] = v.w;
        }
#pragma unroll
        for (int half = 0; half < 2; ++half) {
            int k = krow + half * 16;
            int kk = k0 + k;
            int col = bn + nq * 4;
            float4 v = {0, 0, 0, 0};
            if (kk < K && col < Ncols) {
                if (col < split) v = *(const float4*)&B0[(size_t)kk * ldb0 + col];
                else             v = *(const float4*)&B1[(size_t)kk * ldb1 + (col - split)];
            }
            *(float4*)&Bs[k * BNp + nq * 4] = v;
        }
        __syncthreads();
#pragma unroll
        for (int k = 0; k < BK; ++k) {
            float4 av = *(const float4*)&As[k * BMp + ty * 4];
            float4 bv = *(const float4*)&Bs[k * BNp + tx * 4];
            acc[0][0] += av.x * bv.x; acc[0][1] += av.x * bv.y; acc[0][2] += av.x * bv.z; acc[0][3] += av.x * bv.w;
            acc[1][0] += av.y * bv.x; acc[1][1] += av.y * bv.y; acc[1][2] += av.y * bv.z; acc[1][3] += av.y * bv.w;
            acc[2][0] += av.z * bv.x; acc[2][1] += av.z * bv.y; acc[2][2] += av.z * bv.z; acc[2][3] += av.z * bv.w;
            acc[3][0] += av.w * bv.x; acc[3][1] += av.w * bv.y; acc[3][2] += av.w * bv.z; acc[3][3] += av.w * bv.w;
        }
        __syncthreads();
    }
    const int c = bn + tx * 4;
    if (c >= Ncols) return;
    float bvals[4];
#pragma unroll
    for (int j = 0; j < 4; ++j) {
        int cj = c + j;
        bvals[j] = (cj < split) ? (bias0 ? bias0[cj] : 0.0f)
                                : (bias1 ? bias1[cj - split] : 0.0f);
    }
#pragma unroll
    for (int i = 0; i < 4; ++i) {
        int r = bm + ty * 4 + i;
        if (r >= Nrows) break;
        float4 o;
        o.x = acc[i][0] + bvals[0];
        o.y = acc[i][1] + bvals[1];
        o.z = acc[i][2] + bvals[2];
        o.w = acc[i][3] + bvals[3];
        if (relu) {
            o.x = fmaxf(o.x, 0.0f); o.y = fmaxf(o.y, 0.0f);
            o.z = fmaxf(o.z, 0.0f); o.w = fmaxf(o.w, 0.0f);
        }
        *(float4*)&C[(size_t)r * Ncols + c] = o;
    }
}

// pack src[:, off:off+w] (f32, stride ld) -> dst bf16 rows padded to 128 (zeros)
__global__ void pack_bf16_kernel(const float* __restrict__ src, int ld, int off, int w,
                                 ushort_t* __restrict__ dst, int n) {
    int idx = blockIdx.x * blockDim.x + threadIdx.x;
    if (idx >= n * 32) return;
    int i = idx >> 5, q = idx & 31;
    uint2 p = {0u, 0u};
    if (q * 4 < w) {
        float4 v = *(const float4*)&src[(size_t)i * ld + off + q * 4];
        p.x = (unsigned)f2bf(v.x) | ((unsigned)f2bf(v.y) << 16);
        p.y = (unsigned)f2bf(v.z) | ((unsigned)f2bf(v.w) << 16);
    }
    *(uint2*)&dst[(size_t)i * 128 + q * 4] = p;
}

// t[node,0:100] = sum_j wnorm[j] * hb[colidx[j], :] — bf16 rows of 128 (256B),
// one wave per node, 4 edges in flight (16-lane groups), cross-group reduce.
__global__ void csr_segsum_bf16_kernel(const ushort_t* __restrict__ hb,
                                       const int* __restrict__ rowptr, const int* __restrict__ colidx,
                                       const float* __restrict__ wnorm, float* __restrict__ t, int n) {
    int node = (blockIdx.x * blockDim.x + threadIdx.x) >> 6;
    if (node >= n) return;
    int lane = threadIdx.x & 63;
    int grp = lane >> 4;
    int l = lane & 15;
    int j0 = rowptr[node], j1 = rowptr[node + 1];
    float acc[8] = {};
    for (int j = j0 + grp; j < j1; j += 4) {
        int c = colidx[j];
        float w = wnorm[j];
        uint4 v = ((const uint4*)(hb + (size_t)c * 128))[l];
        acc[0] += w * bflo(v.x); acc[1] += w * bfhi(v.x);
        acc[2] += w * bflo(v.y); acc[3] += w * bfhi(v.y);
        acc[4] += w * bflo(v.z); acc[5] += w * bfhi(v.z);
        acc[6] += w * bflo(v.w); acc[7] += w * bfhi(v.w);
    }
#pragma unroll
    for (int k = 0; k < 8; ++k) {
        acc[k] += __shfl_xor(acc[k], 16, 64);
        acc[k] += __shfl_xor(acc[k], 32, 64);
    }
    if (grp == 0) {
        int f = l * 8;
        if (f + 8 <= 100) {
            float4 lo = {acc[0], acc[1], acc[2], acc[3]};
            float4 hi = {acc[4], acc[5], acc[6], acc[7]};
            *(float4*)&t[(size_t)node * 100 + f] = lo;
            *(float4*)&t[(size_t)node * 100 + f + 4] = hi;
        } else if (f < 100) {
            for (int k = 0; k < 8 && f + k < 100; ++k)
                t[(size_t)node * 100 + f + k] = acc[k];
        }
    }
}

// x1 = relu(G2[:,0:100] + t + b2)
__global__ void combine1_kernel(const float* __restrict__ G2, const float* __restrict__ t,
                                const float* __restrict__ b2, float* __restrict__ x1, int n) {
    int idx = blockIdx.x * blockDim.x + threadIdx.x;
    if (idx >= n * 25) return;
    int i = idx / 25, q = idx % 25;
    float4 g = *(const float4*)&G2[(size_t)i * 200 + q * 4];
    float4 tv = *(const float4*)&t[(size_t)i * 100 + q * 4];
    float4 bv = *(const float4*)&b2[q * 4];
    float4 o;
    o.x = fmaxf(g.x + tv.x + bv.x, 0.0f);
    o.y = fmaxf(g.y + tv.y + bv.y, 0.0f);
    o.z = fmaxf(g.z + tv.z + bv.z, 0.0f);
    o.w = fmaxf(g.w + tv.w + bv.w, 0.0f);
    *(float4*)&x1[(size_t)i * 100 + q * 4] = o;
}

// xo = x1 + relu(S[:,0:100]) (f32); zf = fp8(x1 + relu(S[:,100:200])), rows of
// 32 words (128 fp8 = 128B), padded with zeros.
__global__ void combine2_kernel(const float* __restrict__ S, const float* __restrict__ x1,
                                float* __restrict__ xo, unsigned* __restrict__ zf, int n) {
    int idx = blockIdx.x * blockDim.x + threadIdx.x;
    if (idx >= n * 32) return;
    int i = idx >> 5, q = idx & 31;
    unsigned w = 0u;
    if (q < 25) {
        float4 s1 = *(const float4*)&S[(size_t)i * 200 + q * 4];
        float4 s2 = *(const float4*)&S[(size_t)i * 200 + 100 + q * 4];
        float4 xv = *(const float4*)&x1[(size_t)i * 100 + q * 4];
        float4 a, b;
        a.x = xv.x + fmaxf(s1.x, 0.0f); a.y = xv.y + fmaxf(s1.y, 0.0f);
        a.z = xv.z + fmaxf(s1.z, 0.0f); a.w = xv.w + fmaxf(s1.w, 0.0f);
        b.x = xv.x + fmaxf(s2.x, 0.0f); b.y = xv.y + fmaxf(s2.y, 0.0f);
        b.z = xv.z + fmaxf(s2.z, 0.0f); b.w = xv.w + fmaxf(s2.w, 0.0f);
        *(float4*)&xo[(size_t)i * 100 + q * 4] = a;
        w = (unsigned)__builtin_amdgcn_cvt_pk_fp8_f32(b.x, b.y, 0, false);
        w = (unsigned)__builtin_amdgcn_cvt_pk_fp8_f32(b.z, b.w, (int)w, true);
    }
    zf[(size_t)i * 32 + q] = w;
}

// fused pos/neg loss on fp8 z rows: 8 lanes/edge, uint4/lane = 16 fp8 ->
// 8*16 = 128 elems = full row. depth-2 index + depth-1 row prefetch.
__global__ __launch_bounds__(256) void edge_loss_fp8_kernel(
    const unsigned* __restrict__ zf, const int2* __restrict__ pp,
    const int2* __restrict__ pn, int E, float* __restrict__ accv) {
    const int y = blockIdx.y;
    const int2* __restrict__ pairs = y ? pn : pp;
    const int l = threadIdx.x & 7;
    const int g = (blockIdx.x * blockDim.x + threadIdx.x) >> 3;
    const int ng = (gridDim.x * blockDim.x) >> 3;
    float s = 0.0f;
    int niter = (g < E) ? ((E - 1 - g) / ng + 1) : 0;
    if (niter > 0) {
        int eclamp1 = (g + ng < E) ? (g + ng) : (E - 1);
        int2 p0 = pairs[g];
        int2 p1 = pairs[eclamp1];
        uint4 ra0 = *(const uint4*)&zf[(size_t)p0.x * 32 + l * 4];
        uint4 rb0 = *(const uint4*)&zf[(size_t)p0.y * 32 + l * 4];
        for (int t = 0; t < niter; ++t) {
            int e2 = g + (t + 2) * ng;
            e2 = (e2 < E) ? e2 : (E - 1);
            int2 p2 = pairs[e2];
            uint4 ra1 = *(const uint4*)&zf[(size_t)p1.x * 32 + l * 4];
            uint4 rb1 = *(const uint4*)&zf[(size_t)p1.y * 32 + l * 4];
            // dot over 16 fp8 per lane (HW cvt_pk decode)
            float dot = 0.0f;
            v2f fa, fb;
            fa = __builtin_amdgcn_cvt_pk_f32_fp8(ra0.x, false);
            fb = __builtin_amdgcn_cvt_pk_f32_fp8(rb0.x, false);
            dot += fa.x * fb.x + fa.y * fb.y;
            fa = __builtin_amdgcn_cvt_pk_f32_fp8(ra0.x, true);
            fb = __builtin_amdgcn_cvt_pk_f32_fp8(rb0.x, true);
            dot += fa.x * fb.x + fa.y * fb.y;
            fa = __builtin_amdgcn_cvt_pk_f32_fp8(ra0.y, false);
            fb = __builtin_amdgcn_cvt_pk_f32_fp8(rb0.y, false);
            dot += fa.x * fb.x + fa.y * fb.y;
            fa = __builtin_amdgcn_cvt_pk_f32_fp8(ra0.y, true);
            fb = __builtin_amdgcn_cvt_pk_f32_fp8(rb0.y, true);
            dot += fa.x * fb.x + fa.y * fb.y;
            fa = __builtin_amdgcn_cvt_pk_f32_fp8(ra0.z, false);
            fb = __builtin_amdgcn_cvt_pk_f32_fp8(rb0.z, false);
            dot += fa.x * fb.x + fa.y * fb.y;
            fa = __builtin_amdgcn_cvt_pk_f32_fp8(ra0.z, true);
            fb = __builtin_amdgcn_cvt_pk_f32_fp8(rb0.z, true);
            dot += fa.x * fb.x + fa.y * fb.y;
            fa = __builtin_amdgcn_cvt_pk_f32_fp8(ra0.w, false);
            fb = __builtin_amdgcn_cvt_pk_f32_fp8(rb0.w, false);
            dot += fa.x * fb.x + fa.y * fb.y;
            fa = __builtin_amdgcn_cvt_pk_f32_fp8(ra0.w, true);
            fb = __builtin_amdgcn_cvt_pk_f32_fp8(rb0.w, true);
            dot += fa.x * fb.x + fa.y * fb.y;
            dot += __shfl_xor(dot, 1, 8);
            dot += __shfl_xor(dot, 2, 8);
            dot += __shfl_xor(dot, 4, 8);
            if (l == 0) {
                float sg = 1.0f / (1.0f + expf(-dot));
                s += y ? logf(1.0f - sg + 1e-15f) : logf(sg + 1e-15f);
            }
            p1 = p2; ra0 = ra1; rb0 = rb1;
        }
    }
    __shared__ float red[256];
    red[threadIdx.x] = s;
    __syncthreads();
    for (int st = 128; st > 0; st >>= 1) {
        if (threadIdx.x < st) red[threadIdx.x] += red[threadIdx.x + st];
        __syncthreads();
    }
    if (threadIdx.x == 0) atomicAdd(&accv[y], red[0]);
}

// sv[i] = xo[i,:] @ w (100-dim)
__global__ void rowdot_kernel(const float* __restrict__ xo, const float* __restrict__ w,
                              float* __restrict__ s, int n) {
    int i = blockIdx.x * blockDim.x + threadIdx.x;
    if (i >= n) return;
    const float4* a = (const float4*)(xo + (size_t)i * 100);
    const float4* wv = (const float4*)w;
    float acc = 0.0f;
#pragma unroll
    for (int q = 0; q < 25; ++q) {
        float4 va = a[q], vw = wv[q];
        acc += va.x * vw.x + va.y * vw.y + va.z * vw.z + va.w * vw.w;
    }
    s[i] = acc;
}

// out[i] = xo[i,:]@W3[0] + b3 + sum_j wnorm[j]*sv[colidx[j]]
__global__ void out_kernel(const float* __restrict__ xo, const float* __restrict__ W3,
                           const float* __restrict__ b3, const int* __restrict__ rowptr,
                           const int* __restrict__ colidx, const float* __restrict__ wnorm,
                           const float* __restrict__ sv, float* __restrict__ out, int n) {
    int i = blockIdx.x * blockDim.x + threadIdx.x;
    if (i >= n) return;
    const float4* a = (const float4*)(xo + (size_t)i * 100);
    const float4* wv = (const float4*)W3;
    float acc = b3[0];
#pragma unroll
    for (int q = 0; q < 25; ++q) {
        float4 va = a[q], vw = wv[q];
        acc += va.x * vw.x + va.y * vw.y + va.z * vw.z + va.w * vw.w;
    }
    int j1 = rowptr[i + 1];
    for (int j = rowptr[i]; j < j1; ++j)
        acc += wnorm[j] * sv[colidx[j]];
    out[i] = acc;
}

__global__ void finalize_kernel(float* __restrict__ out, const float* __restrict__ acc,
                                const float* __restrict__ c1, const float* __restrict__ c2,
                                int Nn, int E) {
    out[Nn]     = -(acc[0] + acc[1]) / (float)E;
    out[Nn + 1] = c1[0];
    out[Nn + 2] = c2[0];
}

extern "C" void kernel_launch(void* const* d_in, const int* in_sizes, int n_in,
                              void* d_out, int out_size, void* d_ws, size_t ws_size,
                              hipStream_t stream) {
    (void)n_in; (void)out_size; (void)ws_size;
    const float* x   = (const float*)d_in[0];
    const int*   ei  = (const int*)d_in[1];
    const int*   nei = (const int*)d_in[2];
    const float* W1  = (const float*)d_in[3];
    const float* b1  = (const float*)d_in[4];
    const float* W2  = (const float*)d_in[5];
    const float* b2  = (const float*)d_in[6];
    const float* W3  = (const float*)d_in[7];
    const float* b3  = (const float*)d_in[8];
    const float* lw1 = (const float*)d_in[9];
    const float* lb1 = (const float*)d_in[10];
    const float* lw2 = (const float*)d_in[11];
    const float* lb2 = (const float*)d_in[12];
    const float* c1  = (const float*)d_in[13];
    const float* c2  = (const float*)d_in[14];

    const int Nn = in_sizes[0] / 64;   // 13627
    const int E  = in_sizes[1] / 2;    // 504378

    const size_t Nal = ((size_t)Nn + 5) & ~(size_t)3;   // >= N+1, mult of 4
    const size_t Eal = ((size_t)E + 3) & ~(size_t)3;

    float* ws     = (float*)d_ws;
    float* dinv   = ws;                           // Nal floats
    int*   rowptr = (int*)(dinv + Nal);           // Nal ints (N+1 used)
    float* acc    = (float*)(rowptr + Nal);       // 4 floats
    int*   cursor = (int*)(acc + 4);              // Nal ints
    int*   colidx = cursor + Nal;                 // Eal ints
    float* wnorm  = (float*)(colidx + Eal);       // Eal floats
    int2*  pp     = (int2*)(wnorm + Eal);         // Eal int2 (2*Eal ints)
    int2*  pn     = pp + Eal;                     // Eal int2
    float* XT     = (float*)(pn + Eal);           // N*128 (reused as t: N*100)
    float* h      = XT + (size_t)Nn * 128;        // N*300 (reused as S: N*200)
    float* G2     = h  + (size_t)Nn * 300;        // N*200
    float* x1     = G2 + (size_t)Nn * 200;        // N*100
    float* xo     = x1 + (size_t)Nn * 100;        // N*100
    size_t zoff   = (size_t)(xo + (size_t)Nn * 100 - ws);
    zoff = (zoff + 31) & ~(size_t)31;             // 128B align
    unsigned* zf  = (unsigned*)(ws + zoff);       // N*32 words (fp8 rows, 128B)
    size_t hoff   = zoff + (size_t)Nn * 32 + 63;
    hoff &= ~(size_t)63;                          // 256B align
    ushort_t* hWb = (ushort_t*)(ws + hoff);       // N*128 bf16 (256B rows)
    float* sv     = ws + hoff + (size_t)Nn * 64;  // Nal
    float* t      = XT;                           // alias (XT dead after conv1)
    float* S      = h;                            // alias (h dead after conv2 gemm)

    // --- zero dinv + rowptr + acc in one memset ---
    hipMemsetAsync(dinv, 0, (2 * Nal + 4) * sizeof(float), stream);

    // --- CSR build + norm + edge-pair packing ---
    deg_hist_pairs_kernel<<<1024, 256, 0, stream>>>(ei, nei, dinv, rowptr, pp, pn, E);
    dinv_kernel<<<(Nn + 255) / 256, 256, 0, stream>>>(dinv, Nn);
    scan_kernel<<<1, 1024, 0, stream>>>(rowptr, cursor, Nn);
    fill_kernel<<<1024, 256, 0, stream>>>(ei, dinv, cursor, colidx, wnorm, E);

    // --- conv1: XT = [x | segsum64(x)]; h = relu(XT @ W1cat + b1) ---
    xt_kernel<<<(Nn + 3) / 4, 256, 0, stream>>>(x, rowptr, colidx, wnorm, XT, Nn);
    gemm_tiled<<<dim3(5, (Nn + BM - 1) / BM), 256, 0, stream>>>(
        XT, 128, W1, nullptr, b1, nullptr, h, Nn, 128, 300, 300, 1);

    // --- conv2 fused: G2 = h @ [W2[0] | W2[1]] ---
    gemm_tiled<<<dim3(4, (Nn + BM - 1) / BM), 256, 0, stream>>>(
        h, 300, W2, W2 + 300 * 100, nullptr, nullptr, G2, Nn, 300, 200, 100, 0);
    // hWb = bf16(G2[:,100:200]) L2-resident; t = segsum(hWb); x1 = relu(G2[:,0:100]+t+b2)
    pack_bf16_kernel<<<(Nn * 32 + 255) / 256, 256, 0, stream>>>(G2, 200, 100, 100, hWb, Nn);
    csr_segsum_bf16_kernel<<<(Nn + 3) / 4, 256, 0, stream>>>(hWb, rowptr, colidx, wnorm, t, Nn);
    combine1_kernel<<<(Nn * 25 + 255) / 256, 256, 0, stream>>>(G2, t, b2, x1, Nn);

    // --- skips fused: S = x @ [lw1|lw2] + [lb1|lb2]; xo = x1+relu(S0), zf = fp8(x1+relu(S1)) ---
    gemm_tiled<<<dim3(4, (Nn + BM - 1) / BM), 256, 0, stream>>>(
        x, 64, lw1, lw2, lb1, lb2, S, Nn, 64, 200, 100, 0);
    combine2_kernel<<<(Nn * 32 + 255) / 256, 256, 0, stream>>>(S, x1, xo, zf, Nn);

    // --- edge reconstruction losses (pos: y=0, neg: y=1), fp8 z, pipelined ---
    edge_loss_fp8_kernel<<<dim3(1024, 2), 256, 0, stream>>>(zf, pp, pn, E, acc);

    // --- conv3 (width 1): sv = xo@W3[1]; out = xo@W3[0] + segsum(sv) + b3 ---
    rowdot_kernel<<<(Nn + 255) / 256, 256, 0, stream>>>(xo, W3 + 100, sv, Nn);
    out_kernel<<<(Nn + 255) / 256, 256, 0, stream>>>(xo, W3, b3, rowptr, colidx, wnorm,
                                                     sv, (float*)d_out, Nn);

    finalize_kernel<<<1, 1, 0, stream>>>((float*)d_out, acc, c1, c2, Nn, E);
}

// Round 9
// 307.953 us; speedup vs baseline: 4.7204x; 1.1252x over previous
//
#include <hip/hip_runtime.h>
#include <math.h>

// ---------------------------------------------------------------------------
// Net_1503238553644: 2-layer ChebConv(K=2) GNN + linear skips + edge recon loss
// N=13627, E=504378, F=64, H1=300, H2=100, LIN=100
// R9: GEMMs moved to bf16 MFMA (mfma_f32_16x16x32_bf16), 64x64x32 tile,
//     4 waves 2x2, A[m][k] / B[n][k] bf16 LDS (stride 72 = 144B). Rest = R8.
// ---------------------------------------------------------------------------

typedef unsigned short ushort_t;
typedef float v2f __attribute__((ext_vector_type(2)));
typedef short bf16x8 __attribute__((ext_vector_type(8)));
typedef float f32x4 __attribute__((ext_vector_type(4)));

#define GBM 64
#define GBN 64
#define GBK 32
#define LDK 72   // bf16 per LDS row: 144B, 16B-aligned, 2-way bank alias (free)

__device__ inline short f2bf(float f) {              // RNE float->bf16
    unsigned u = __float_as_uint(f);
    u += 0x7fff + ((u >> 16) & 1);
    return (short)(u >> 16);
}
__device__ inline float bflo(unsigned w) { return __uint_as_float(w << 16); }
__device__ inline float bfhi(unsigned w) { return __uint_as_float(w & 0xffff0000u); }

// deg[ei0[e]] += 1 (float); cnt[ei1[e]+1] += 1 (CSR histogram);
// pack edge pairs: pp[e] = (ei0[e], ei1[e]), pn[e] = (nei0[e], nei1[e])
__global__ void deg_hist_pairs_kernel(const int* __restrict__ ei, const int* __restrict__ nei,
                                      float* __restrict__ deg, int* __restrict__ cnt,
                                      int2* __restrict__ pp, int2* __restrict__ pn, int E) {
    int stride = gridDim.x * blockDim.x;
    for (int e = blockIdx.x * blockDim.x + threadIdx.x; e < E; e += stride) {
        int a = ei[e], b = ei[E + e];
        atomicAdd(&deg[a], 1.0f);
        atomicAdd(&cnt[b + 1], 1);
        pp[e] = make_int2(a, b);
        pn[e] = make_int2(nei[e], nei[E + e]);
    }
}

__global__ void dinv_kernel(float* __restrict__ deg, int n) {
    int i = blockIdx.x * blockDim.x + threadIdx.x;
    if (i < n) {
        float d = deg[i];
        deg[i] = (d > 0.0f) ? (1.0f / sqrtf(fmaxf(d, 1.0f))) : 0.0f;
    }
}

// single-block scan: rowptr[i+1] = inclusive sum; cursor[i] = exclusive sum
__global__ void scan_kernel(int* __restrict__ rowptr, int* __restrict__ cursor, int n) {
    __shared__ int wsum[16];
    __shared__ int carry_s;
    if (threadIdx.x == 0) carry_s = 0;
    __syncthreads();
    int nchunk = (n + 1023) / 1024;
    int wid = threadIdx.x >> 6, lane = threadIdx.x & 63;
    for (int c = 0; c < nchunk; ++c) {
        int i = c * 1024 + threadIdx.x;
        int v = (i < n) ? rowptr[i + 1] : 0;
        int s = v;
        for (int off = 1; off < 64; off <<= 1) {
            int t = __shfl_up(s, off, 64);
            if (lane >= off) s += t;
        }
        if (lane == 63) wsum[wid] = s;
        __syncthreads();
        if (wid == 0 && lane < 16) {
            int wsv = wsum[lane];
            for (int off = 1; off < 16; off <<= 1) {
                int t = __shfl_up(wsv, off, 64);
                if (lane >= off) wsv += t;
            }
            wsum[lane] = wsv;
        }
        __syncthreads();
        int base = carry_s + (wid > 0 ? wsum[wid - 1] : 0);
        int inc = base + s;
        if (i < n) { rowptr[i + 1] = inc; cursor[i] = inc - v; }
        __syncthreads();
        if (threadIdx.x == 1023) carry_s = inc;
        __syncthreads();
    }
}

// scatter edges into dst-sorted CSR slots; wnorm = -dinv[src]*dinv[dst]
__global__ void fill_kernel(const int* __restrict__ ei, const float* __restrict__ dinv,
                            int* __restrict__ cursor, int* __restrict__ colidx,
                            float* __restrict__ wnorm, int E) {
    int stride = gridDim.x * blockDim.x;
    for (int e = blockIdx.x * blockDim.x + threadIdx.x; e < E; e += stride) {
        int s = ei[e];
        int d = ei[E + e];
        int slot = atomicAdd(&cursor[d], 1);
        colidx[slot] = s;
        wnorm[slot] = -dinv[s] * dinv[d];
    }
}

// XT[node] = [ x[node] (64) | segsum64(x)[node] (64) ]  — one wave per node
__global__ void xt_kernel(const float* __restrict__ x, const int* __restrict__ rowptr,
                          const int* __restrict__ colidx, const float* __restrict__ wnorm,
                          float* __restrict__ XT, int n) {
    int node = (blockIdx.x * blockDim.x + threadIdx.x) >> 6;
    int lane = threadIdx.x & 63;
    if (node >= n) return;
    int j0 = rowptr[node], j1 = rowptr[node + 1];
    float a = 0.0f;
    for (int j = j0; j < j1; ++j)
        a += wnorm[j] * x[(size_t)colidx[j] * 64 + lane];
    XT[(size_t)node * 128 + lane] = x[(size_t)node * 64 + lane];
    XT[(size_t)node * 128 + 64 + lane] = a;
}

// C[Nrows x Ncols] = relu?( A @ Bcat + biascat ), bf16 MFMA 64x64x32.
// Bcat cols [0,split) from B0 (K x split), [split,Ncols) from B1.
__global__ __launch_bounds__(256) void gemm_mfma(
    const float* __restrict__ A, int lda,
    const float* __restrict__ B0, const float* __restrict__ B1,
    const float* __restrict__ bias0, const float* __restrict__ bias1,
    float* __restrict__ C, int Nrows, int K, int Ncols, int split, int relu) {
    __shared__ short As[GBM * LDK];   // [m][k] bf16
    __shared__ short Bs[GBN * LDK];   // [n][k] bf16 (B transposed)
    const int bm = blockIdx.y * GBM, bn = blockIdx.x * GBN;
    const int tid = threadIdx.x;
    const int w = tid >> 6, l = tid & 63;
    const int wm = (w >> 1) * 32, wn = (w & 1) * 32;
    const int lr = l & 15;     // A-row / B-col within frag
    const int kg = l >> 4;     // k-group (8 elems each)
    const int arow = tid >> 2, aseg = tid & 3;       // A stager
    const int bcol = tid & 63, bk2 = (tid >> 6) * 2; // B stager
    const int ldb0 = split, ldb1 = Ncols - split;

    const int arowg = bm + arow;
    const int bcolg = bn + bcol;
    const float* Bsrc = (bcolg < split) ? (B0 + bcolg)
                       : ((bcolg < Ncols) ? (B1 + (bcolg - split)) : nullptr);
    const int ldb = (bcolg < split) ? ldb0 : ldb1;

    f32x4 acc00 = {0,0,0,0}, acc01 = {0,0,0,0}, acc10 = {0,0,0,0}, acc11 = {0,0,0,0};

    for (int k0 = 0; k0 < K; k0 += GBK) {
        // stage A: thread -> 8 consecutive k of one row
        {
            int kk = k0 + aseg * 8;
            bf16x8 v;
            if (arowg < Nrows && kk + 7 < K) {
                float4 f0 = *(const float4*)&A[(size_t)arowg * lda + kk];
                float4 f1 = *(const float4*)&A[(size_t)arowg * lda + kk + 4];
                v[0] = f2bf(f0.x); v[1] = f2bf(f0.y); v[2] = f2bf(f0.z); v[3] = f2bf(f0.w);
                v[4] = f2bf(f1.x); v[5] = f2bf(f1.y); v[6] = f2bf(f1.z); v[7] = f2bf(f1.w);
            } else {
#pragma unroll
                for (int i = 0; i < 8; ++i)
                    v[i] = (arowg < Nrows && kk + i < K)
                         ? f2bf(A[(size_t)arowg * lda + kk + i]) : (short)0;
            }
            *(bf16x8*)&As[arow * LDK + aseg * 8] = v;
        }
        // stage B transposed: thread -> k-pairs (k even) of one column
#pragma unroll
        for (int q = 0; q < 4; ++q) {
            int k = q * 8 + bk2;
            unsigned pw = 0u;
            if (Bsrc) {
                float f0 = (k0 + k < K) ? Bsrc[(size_t)(k0 + k) * ldb] : 0.0f;
                float f1 = (k0 + k + 1 < K) ? Bsrc[(size_t)(k0 + k + 1) * ldb] : 0.0f;
                pw = (unsigned)(unsigned short)f2bf(f0)
                   | ((unsigned)(unsigned short)f2bf(f1) << 16);
            }
            *(unsigned*)&Bs[bcol * LDK + k] = pw;
        }
        __syncthreads();
        bf16x8 a0 = *(const bf16x8*)&As[(wm + lr) * LDK + kg * 8];
        bf16x8 a1 = *(const bf16x8*)&As[(wm + 16 + lr) * LDK + kg * 8];
        bf16x8 b0 = *(const bf16x8*)&Bs[(wn + lr) * LDK + kg * 8];
        bf16x8 b1 = *(const bf16x8*)&Bs[(wn + 16 + lr) * LDK + kg * 8];
        acc00 = __builtin_amdgcn_mfma_f32_16x16x32_bf16(a0, b0, acc00, 0, 0, 0);
        acc01 = __builtin_amdgcn_mfma_f32_16x16x32_bf16(a0, b1, acc01, 0, 0, 0);
        acc10 = __builtin_amdgcn_mfma_f32_16x16x32_bf16(a1, b0, acc10, 0, 0, 0);
        acc11 = __builtin_amdgcn_mfma_f32_16x16x32_bf16(a1, b1, acc11, 0, 0, 0);
        __syncthreads();
    }
    // epilogue: C/D frag = col(lane&15), row((lane>>4)*4 + r)
#pragma unroll
    for (int i = 0; i < 2; ++i) {
        int rbase = bm + wm + i * 16 + kg * 4;
#pragma unroll
        for (int j = 0; j < 2; ++j) {
            int col = bn + wn + j * 16 + lr;
            if (col >= Ncols) continue;
            float bv = (col < split) ? (bias0 ? bias0[col] : 0.0f)
                                     : (bias1 ? bias1[col - split] : 0.0f);
            f32x4 a = (i == 0) ? (j == 0 ? acc00 : acc01) : (j == 0 ? acc10 : acc11);
#pragma unroll
            for (int r = 0; r < 4; ++r) {
                int row = rbase + r;
                if (row < Nrows) {
                    float o = a[r] + bv;
                    if (relu) o = fmaxf(o, 0.0f);
                    C[(size_t)row * Ncols + col] = o;
                }
            }
        }
    }
}

// pack src[:, off:off+w] (f32, stride ld) -> dst bf16 rows padded to 128 (zeros)
__global__ void pack_bf16_kernel(const float* __restrict__ src, int ld, int off, int w,
                                 ushort_t* __restrict__ dst, int n) {
    int idx = blockIdx.x * blockDim.x + threadIdx.x;
    if (idx >= n * 32) return;
    int i = idx >> 5, q = idx & 31;
    uint2 p = {0u, 0u};
    if (q * 4 < w) {
        float4 v = *(const float4*)&src[(size_t)i * ld + off + q * 4];
        p.x = (unsigned)(unsigned short)f2bf(v.x) | ((unsigned)(unsigned short)f2bf(v.y) << 16);
        p.y = (unsigned)(unsigned short)f2bf(v.z) | ((unsigned)(unsigned short)f2bf(v.w) << 16);
    }
    *(uint2*)&dst[(size_t)i * 128 + q * 4] = p;
}

// t[node,0:100] = sum_j wnorm[j] * hb[colidx[j], :] — bf16 rows of 128 (256B),
// one wave per node, 4 edges in flight (16-lane groups), cross-group reduce.
__global__ void csr_segsum_bf16_kernel(const ushort_t* __restrict__ hb,
                                       const int* __restrict__ rowptr, const int* __restrict__ colidx,
                                       const float* __restrict__ wnorm, float* __restrict__ t, int n) {
    int node = (blockIdx.x * blockDim.x + threadIdx.x) >> 6;
    if (node >= n) return;
    int lane = threadIdx.x & 63;
    int grp = lane >> 4;
    int l = lane & 15;
    int j0 = rowptr[node], j1 = rowptr[node + 1];
    float acc[8] = {};
    for (int j = j0 + grp; j < j1; j += 4) {
        int c = colidx[j];
        float w = wnorm[j];
        uint4 v = ((const uint4*)(hb + (size_t)c * 128))[l];
        acc[0] += w * bflo(v.x); acc[1] += w * bfhi(v.x);
        acc[2] += w * bflo(v.y); acc[3] += w * bfhi(v.y);
        acc[4] += w * bflo(v.z); acc[5] += w * bfhi(v.z);
        acc[6] += w * bflo(v.w); acc[7] += w * bfhi(v.w);
    }
#pragma unroll
    for (int k = 0; k < 8; ++k) {
        acc[k] += __shfl_xor(acc[k], 16, 64);
        acc[k] += __shfl_xor(acc[k], 32, 64);
    }
    if (grp == 0) {
        int f = l * 8;
        if (f + 8 <= 100) {
            float4 lo = {acc[0], acc[1], acc[2], acc[3]};
            float4 hi = {acc[4], acc[5], acc[6], acc[7]};
            *(float4*)&t[(size_t)node * 100 + f] = lo;
            *(float4*)&t[(size_t)node * 100 + f + 4] = hi;
        } else if (f < 100) {
            for (int k = 0; k < 8 && f + k < 100; ++k)
                t[(size_t)node * 100 + f + k] = acc[k];
        }
    }
}

// x1 = relu(G2[:,0:100] + t + b2)
__global__ void combine1_kernel(const float* __restrict__ G2, const float* __restrict__ t,
                                const float* __restrict__ b2, float* __restrict__ x1, int n) {
    int idx = blockIdx.x * blockDim.x + threadIdx.x;
    if (idx >= n * 25) return;
    int i = idx / 25, q = idx % 25;
    float4 g = *(const float4*)&G2[(size_t)i * 200 + q * 4];
    float4 tv = *(const float4*)&t[(size_t)i * 100 + q * 4];
    float4 bv = *(const float4*)&b2[q * 4];
    float4 o;
    o.x = fmaxf(g.x + tv.x + bv.x, 0.0f);
    o.y = fmaxf(g.y + tv.y + bv.y, 0.0f);
    o.z = fmaxf(g.z + tv.z + bv.z, 0.0f);
    o.w = fmaxf(g.w + tv.w + bv.w, 0.0f);
    *(float4*)&x1[(size_t)i * 100 + q * 4] = o;
}

// xo = x1 + relu(S[:,0:100]) (f32); zf = fp8(x1 + relu(S[:,100:200])), rows of
// 32 words (128 fp8 = 128B), padded with zeros.
__global__ void combine2_kernel(const float* __restrict__ S, const float* __restrict__ x1,
                                float* __restrict__ xo, unsigned* __restrict__ zf, int n) {
    int idx = blockIdx.x * blockDim.x + threadIdx.x;
    if (idx >= n * 32) return;
    int i = idx >> 5, q = idx & 31;
    unsigned w = 0u;
    if (q < 25) {
        float4 s1 = *(const float4*)&S[(size_t)i * 200 + q * 4];
        float4 s2 = *(const float4*)&S[(size_t)i * 200 + 100 + q * 4];
        float4 xv = *(const float4*)&x1[(size_t)i * 100 + q * 4];
        float4 a, b;
        a.x = xv.x + fmaxf(s1.x, 0.0f); a.y = xv.y + fmaxf(s1.y, 0.0f);
        a.z = xv.z + fmaxf(s1.z, 0.0f); a.w = xv.w + fmaxf(s1.w, 0.0f);
        b.x = xv.x + fmaxf(s2.x, 0.0f); b.y = xv.y + fmaxf(s2.y, 0.0f);
        b.z = xv.z + fmaxf(s2.z, 0.0f); b.w = xv.w + fmaxf(s2.w, 0.0f);
        *(float4*)&xo[(size_t)i * 100 + q * 4] = a;
        w = (unsigned)__builtin_amdgcn_cvt_pk_fp8_f32(b.x, b.y, 0, false);
        w = (unsigned)__builtin_amdgcn_cvt_pk_fp8_f32(b.z, b.w, (int)w, true);
    }
    zf[(size_t)i * 32 + q] = w;
}

// fused pos/neg loss on fp8 z rows: 8 lanes/edge, uint4/lane = 16 fp8 ->
// 8*16 = 128 elems = full row. depth-2 index + depth-1 row prefetch.
__global__ __launch_bounds__(256) void edge_loss_fp8_kernel(
    const unsigned* __restrict__ zf, const int2* __restrict__ pp,
    const int2* __restrict__ pn, int E, float* __restrict__ accv) {
    const int y = blockIdx.y;
    const int2* __restrict__ pairs = y ? pn : pp;
    const int l = threadIdx.x & 7;
    const int g = (blockIdx.x * blockDim.x + threadIdx.x) >> 3;
    const int ng = (gridDim.x * blockDim.x) >> 3;
    float s = 0.0f;
    int niter = (g < E) ? ((E - 1 - g) / ng + 1) : 0;
    if (niter > 0) {
        int eclamp1 = (g + ng < E) ? (g + ng) : (E - 1);
        int2 p0 = pairs[g];
        int2 p1 = pairs[eclamp1];
        uint4 ra0 = *(const uint4*)&zf[(size_t)p0.x * 32 + l * 4];
        uint4 rb0 = *(const uint4*)&zf[(size_t)p0.y * 32 + l * 4];
        for (int t = 0; t < niter; ++t) {
            int e2 = g + (t + 2) * ng;
            e2 = (e2 < E) ? e2 : (E - 1);
            int2 p2 = pairs[e2];
            uint4 ra1 = *(const uint4*)&zf[(size_t)p1.x * 32 + l * 4];
            uint4 rb1 = *(const uint4*)&zf[(size_t)p1.y * 32 + l * 4];
            float dot = 0.0f;
            v2f fa, fb;
            fa = __builtin_amdgcn_cvt_pk_f32_fp8(ra0.x, false);
            fb = __builtin_amdgcn_cvt_pk_f32_fp8(rb0.x, false);
            dot += fa.x * fb.x + fa.y * fb.y;
            fa = __builtin_amdgcn_cvt_pk_f32_fp8(ra0.x, true);
            fb = __builtin_amdgcn_cvt_pk_f32_fp8(rb0.x, true);
            dot += fa.x * fb.x + fa.y * fb.y;
            fa = __builtin_amdgcn_cvt_pk_f32_fp8(ra0.y, false);
            fb = __builtin_amdgcn_cvt_pk_f32_fp8(rb0.y, false);
            dot += fa.x * fb.x + fa.y * fb.y;
            fa = __builtin_amdgcn_cvt_pk_f32_fp8(ra0.y, true);
            fb = __builtin_amdgcn_cvt_pk_f32_fp8(rb0.y, true);
            dot += fa.x * fb.x + fa.y * fb.y;
            fa = __builtin_amdgcn_cvt_pk_f32_fp8(ra0.z, false);
            fb = __builtin_amdgcn_cvt_pk_f32_fp8(rb0.z, false);
            dot += fa.x * fb.x + fa.y * fb.y;
            fa = __builtin_amdgcn_cvt_pk_f32_fp8(ra0.z, true);
            fb = __builtin_amdgcn_cvt_pk_f32_fp8(rb0.z, true);
            dot += fa.x * fb.x + fa.y * fb.y;
            fa = __builtin_amdgcn_cvt_pk_f32_fp8(ra0.w, false);
            fb = __builtin_amdgcn_cvt_pk_f32_fp8(rb0.w, false);
            dot += fa.x * fb.x + fa.y * fb.y;
            fa = __builtin_amdgcn_cvt_pk_f32_fp8(ra0.w, true);
            fb = __builtin_amdgcn_cvt_pk_f32_fp8(rb0.w, true);
            dot += fa.x * fb.x + fa.y * fb.y;
            dot += __shfl_xor(dot, 1, 8);
            dot += __shfl_xor(dot, 2, 8);
            dot += __shfl_xor(dot, 4, 8);
            if (l == 0) {
                float sg = 1.0f / (1.0f + expf(-dot));
                s += y ? logf(1.0f - sg + 1e-15f) : logf(sg + 1e-15f);
            }
            p1 = p2; ra0 = ra1; rb0 = rb1;
        }
    }
    __shared__ float red[256];
    red[threadIdx.x] = s;
    __syncthreads();
    for (int st = 128; st > 0; st >>= 1) {
        if (threadIdx.x < st) red[threadIdx.x] += red[threadIdx.x + st];
        __syncthreads();
    }
    if (threadIdx.x == 0) atomicAdd(&accv[y], red[0]);
}

// sv[i] = xo[i,:] @ w (100-dim)
__global__ void rowdot_kernel(const float* __restrict__ xo, const float* __restrict__ w,
                              float* __restrict__ s, int n) {
    int i = blockIdx.x * blockDim.x + threadIdx.x;
    if (i >= n) return;
    const float4* a = (const float4*)(xo + (size_t)i * 100);
    const float4* wv = (const float4*)w;
    float acc = 0.0f;
#pragma unroll
    for (int q = 0; q < 25; ++q) {
        float4 va = a[q], vw = wv[q];
        acc += va.x * vw.x + va.y * vw.y + va.z * vw.z + va.w * vw.w;
    }
    s[i] = acc;
}

// out[i] = xo[i,:]@W3[0] + b3 + sum_j wnorm[j]*sv[colidx[j]]
__global__ void out_kernel(const float* __restrict__ xo, const float* __restrict__ W3,
                           const float* __restrict__ b3, const int* __restrict__ rowptr,
                           const int* __restrict__ colidx, const float* __restrict__ wnorm,
                           const float* __restrict__ sv, float* __restrict__ out, int n) {
    int i = blockIdx.x * blockDim.x + threadIdx.x;
    if (i >= n) return;
    const float4* a = (const float4*)(xo + (size_t)i * 100);
    const float4* wv = (const float4*)W3;
    float acc = b3[0];
#pragma unroll
    for (int q = 0; q < 25; ++q) {
        float4 va = a[q], vw = wv[q];
        acc += va.x * vw.x + va.y * vw.y + va.z * vw.z + va.w * vw.w;
    }
    int j1 = rowptr[i + 1];
    for (int j = rowptr[i]; j < j1; ++j)
        acc += wnorm[j] * sv[colidx[j]];
    out[i] = acc;
}

__global__ void finalize_kernel(float* __restrict__ out, const float* __restrict__ acc,
                                const float* __restrict__ c1, const float* __restrict__ c2,
                                int Nn, int E) {
    out[Nn]     = -(acc[0] + acc[1]) / (float)E;
    out[Nn + 1] = c1[0];
    out[Nn + 2] = c2[0];
}

extern "C" void kernel_launch(void* const* d_in, const int* in_sizes, int n_in,
                              void* d_out, int out_size, void* d_ws, size_t ws_size,
                              hipStream_t stream) {
    (void)n_in; (void)out_size; (void)ws_size;
    const float* x   = (const float*)d_in[0];
    const int*   ei  = (const int*)d_in[1];
    const int*   nei = (const int*)d_in[2];
    const float* W1  = (const float*)d_in[3];
    const float* b1  = (const float*)d_in[4];
    const float* W2  = (const float*)d_in[5];
    const float* b2  = (const float*)d_in[6];
    const float* W3  = (const float*)d_in[7];
    const float* b3  = (const float*)d_in[8];
    const float* lw1 = (const float*)d_in[9];
    const float* lb1 = (const float*)d_in[10];
    const float* lw2 = (const float*)d_in[11];
    const float* lb2 = (const float*)d_in[12];
    const float* c1  = (const float*)d_in[13];
    const float* c2  = (const float*)d_in[14];

    const int Nn = in_sizes[0] / 64;   // 13627
    const int E  = in_sizes[1] / 2;    // 504378

    const size_t Nal = ((size_t)Nn + 5) & ~(size_t)3;   // >= N+1, mult of 4
    const size_t Eal = ((size_t)E + 3) & ~(size_t)3;

    float* ws     = (float*)d_ws;
    float* dinv   = ws;                           // Nal floats
    int*   rowptr = (int*)(dinv + Nal);           // Nal ints (N+1 used)
    float* acc    = (float*)(rowptr + Nal);       // 4 floats
    int*   cursor = (int*)(acc + 4);              // Nal ints
    int*   colidx = cursor + Nal;                 // Eal ints
    float* wnorm  = (float*)(colidx + Eal);       // Eal floats
    int2*  pp     = (int2*)(wnorm + Eal);         // Eal int2
    int2*  pn     = pp + Eal;                     // Eal int2
    float* XT     = (float*)(pn + Eal);           // N*128 (reused as t: N*100)
    float* h      = XT + (size_t)Nn * 128;        // N*300 (reused as S: N*200)
    float* G2     = h  + (size_t)Nn * 300;        // N*200
    float* x1     = G2 + (size_t)Nn * 200;        // N*100
    float* xo     = x1 + (size_t)Nn * 100;        // N*100
    size_t zoff   = (size_t)(xo + (size_t)Nn * 100 - ws);
    zoff = (zoff + 31) & ~(size_t)31;             // 128B align
    unsigned* zf  = (unsigned*)(ws + zoff);       // N*32 words (fp8 rows, 128B)
    size_t hoff   = zoff + (size_t)Nn * 32 + 63;
    hoff &= ~(size_t)63;                          // 256B align
    ushort_t* hWb = (ushort_t*)(ws + hoff);       // N*128 bf16 (256B rows)
    float* sv     = ws + hoff + (size_t)Nn * 64;  // Nal
    float* t      = XT;                           // alias (XT dead after conv1)
    float* S      = h;                            // alias (h dead after conv2 gemm)

    const int MB = (Nn + GBM - 1) / GBM;          // 213 row-tiles

    // --- zero dinv + rowptr + acc in one memset ---
    hipMemsetAsync(dinv, 0, (2 * Nal + 4) * sizeof(float), stream);

    // --- CSR build + norm + edge-pair packing ---
    deg_hist_pairs_kernel<<<1024, 256, 0, stream>>>(ei, nei, dinv, rowptr, pp, pn, E);
    dinv_kernel<<<(Nn + 255) / 256, 256, 0, stream>>>(dinv, Nn);
    scan_kernel<<<1, 1024, 0, stream>>>(rowptr, cursor, Nn);
    fill_kernel<<<1024, 256, 0, stream>>>(ei, dinv, cursor, colidx, wnorm, E);

    // --- conv1: XT = [x | segsum64(x)]; h = relu(XT @ W1cat + b1) ---
    xt_kernel<<<(Nn + 3) / 4, 256, 0, stream>>>(x, rowptr, colidx, wnorm, XT, Nn);
    gemm_mfma<<<dim3(5, MB), 256, 0, stream>>>(
        XT, 128, W1, nullptr, b1, nullptr, h, Nn, 128, 300, 300, 1);

    // --- conv2 fused: G2 = h @ [W2[0] | W2[1]] ---
    gemm_mfma<<<dim3(4, MB), 256, 0, stream>>>(
        h, 300, W2, W2 + 300 * 100, nullptr, nullptr, G2, Nn, 300, 200, 100, 0);
    // hWb = bf16(G2[:,100:200]) L2-resident; t = segsum(hWb); x1 = relu(G2[:,0:100]+t+b2)
    pack_bf16_kernel<<<(Nn * 32 + 255) / 256, 256, 0, stream>>>(G2, 200, 100, 100, hWb, Nn);
    csr_segsum_bf16_kernel<<<(Nn + 3) / 4, 256, 0, stream>>>(hWb, rowptr, colidx, wnorm, t, Nn);
    combine1_kernel<<<(Nn * 25 + 255) / 256, 256, 0, stream>>>(G2, t, b2, x1, Nn);

    // --- skips fused: S = x @ [lw1|lw2] + [lb1|lb2]; xo = x1+relu(S0), zf = fp8(x1+relu(S1)) ---
    gemm_mfma<<<dim3(4, MB), 256, 0, stream>>>(
        x, 64, lw1, lw2, lb1, lb2, S, Nn, 64, 200, 100, 0);
    combine2_kernel<<<(Nn * 32 + 255) / 256, 256, 0, stream>>>(S, x1, xo, zf, Nn);

    // --- edge reconstruction losses (pos: y=0, neg: y=1), fp8 z, pipelined ---
    edge_loss_fp8_kernel<<<dim3(1024, 2), 256, 0, stream>>>(zf, pp, pn, E, acc);

    // --- conv3 (width 1): sv = xo@W3[1]; out = xo@W3[0] + segsum(sv) + b3 ---
    rowdot_kernel<<<(Nn + 255) / 256, 256, 0, stream>>>(xo, W3 + 100, sv, Nn);
    out_kernel<<<(Nn + 255) / 256, 256, 0, stream>>>(xo, W3, b3, rowptr, colidx, wnorm,
                                                     sv, (float*)d_out, Nn);

    finalize_kernel<<<1, 1, 0, stream>>>((float*)d_out, acc, c1, c2, Nn, E);
}

// Round 10
// 273.526 us; speedup vs baseline: 5.3146x; 1.1259x over previous
//
#include <hip/hip_runtime.h>
#include <math.h>

// ---------------------------------------------------------------------------
// Net_1503238553644: 2-layer ChebConv(K=2) GNN + linear skips + edge recon loss
// N=13627, E=504378, F=64, H1=300, H2=100, LIN=100
// R10: 4-replica int histograms (contention /4) + merge kernel; xt 4-edge ILP;
//      combine1 fused into segsum epilogue. MFMA GEMM + fp8 loss from R9.
// ---------------------------------------------------------------------------

typedef unsigned short ushort_t;
typedef float v2f __attribute__((ext_vector_type(2)));
typedef short bf16x8 __attribute__((ext_vector_type(8)));
typedef float f32x4 __attribute__((ext_vector_type(4)));

#define GBM 64
#define GBN 64
#define GBK 32
#define LDK 72   // bf16 per LDS row: 144B, 16B-aligned, 2-way bank alias (free)

__device__ inline short f2bf(float f) {              // RNE float->bf16
    unsigned u = __float_as_uint(f);
    u += 0x7fff + ((u >> 16) & 1);
    return (short)(u >> 16);
}
__device__ inline float bflo(unsigned w) { return __uint_as_float(w << 16); }
__device__ inline float bfhi(unsigned w) { return __uint_as_float(w & 0xffff0000u); }

// 4-replica histograms (int): hist[rep][v] deg-by-src, hist[4+rep][v] cnt-by-dst.
// Also packs edge pairs pp/pn.
__global__ void deg_hist_pairs_kernel(const int* __restrict__ ei, const int* __restrict__ nei,
                                      int* __restrict__ hist, int Nal,
                                      int2* __restrict__ pp, int2* __restrict__ pn, int E) {
    int* hd = hist + (size_t)(blockIdx.x & 3) * Nal;
    int* hc = hist + (size_t)(4 + (blockIdx.x & 3)) * Nal;
    int stride = gridDim.x * blockDim.x;
    for (int e = blockIdx.x * blockDim.x + threadIdx.x; e < E; e += stride) {
        int a = ei[e], b = ei[E + e];
        atomicAdd(&hd[a], 1);
        atomicAdd(&hc[b], 1);
        pp[e] = make_int2(a, b);
        pn[e] = make_int2(nei[e], nei[E + e]);
    }
}

// merge replicas -> dinv[v], rowptr[v+1] = cnt (pre-scan); rowptr[0] = 0
__global__ void merge_hist_kernel(const int* __restrict__ hist, int Nal,
                                  float* __restrict__ dinv, int* __restrict__ rowptr, int n) {
    int i = blockIdx.x * blockDim.x + threadIdx.x;
    if (i < n) {
        int d = hist[i] + hist[Nal + i] + hist[2 * Nal + i] + hist[3 * Nal + i];
        dinv[i] = (d > 0) ? (1.0f / sqrtf((float)d)) : 0.0f;
        int c = hist[4 * Nal + i] + hist[5 * Nal + i] + hist[6 * Nal + i] + hist[7 * Nal + i];
        rowptr[i + 1] = c;
    }
    if (i == 0) rowptr[0] = 0;
}

// single-block scan: rowptr[i+1] = inclusive sum; cursor[i] = exclusive sum
__global__ void scan_kernel(int* __restrict__ rowptr, int* __restrict__ cursor, int n) {
    __shared__ int wsum[16];
    __shared__ int carry_s;
    if (threadIdx.x == 0) carry_s = 0;
    __syncthreads();
    int nchunk = (n + 1023) / 1024;
    int wid = threadIdx.x >> 6, lane = threadIdx.x & 63;
    for (int c = 0; c < nchunk; ++c) {
        int i = c * 1024 + threadIdx.x;
        int v = (i < n) ? rowptr[i + 1] : 0;
        int s = v;
        for (int off = 1; off < 64; off <<= 1) {
            int t = __shfl_up(s, off, 64);
            if (lane >= off) s += t;
        }
        if (lane == 63) wsum[wid] = s;
        __syncthreads();
        if (wid == 0 && lane < 16) {
            int wsv = wsum[lane];
            for (int off = 1; off < 16; off <<= 1) {
                int t = __shfl_up(wsv, off, 64);
                if (lane >= off) wsv += t;
            }
            wsum[lane] = wsv;
        }
        __syncthreads();
        int base = carry_s + (wid > 0 ? wsum[wid - 1] : 0);
        int inc = base + s;
        if (i < n) { rowptr[i + 1] = inc; cursor[i] = inc - v; }
        __syncthreads();
        if (threadIdx.x == 1023) carry_s = inc;
        __syncthreads();
    }
}

// scatter edges into dst-sorted CSR slots; wnorm = -dinv[src]*dinv[dst]
__global__ void fill_kernel(const int* __restrict__ ei, const float* __restrict__ dinv,
                            int* __restrict__ cursor, int* __restrict__ colidx,
                            float* __restrict__ wnorm, int E) {
    int stride = gridDim.x * blockDim.x;
    for (int e = blockIdx.x * blockDim.x + threadIdx.x; e < E; e += stride) {
        int s = ei[e];
        int d = ei[E + e];
        int slot = atomicAdd(&cursor[d], 1);
        colidx[slot] = s;
        wnorm[slot] = -dinv[s] * dinv[d];
    }
}

// XT[node] = [ x[node] (64) | segsum64(x)[node] (64) ] — one wave per node,
// 4 edges in flight (16-lane groups, float4/lane = full 64-f32 row).
__global__ void xt_kernel(const float* __restrict__ x, const int* __restrict__ rowptr,
                          const int* __restrict__ colidx, const float* __restrict__ wnorm,
                          float* __restrict__ XT, int n) {
    int node = (blockIdx.x * blockDim.x + threadIdx.x) >> 6;
    if (node >= n) return;
    int lane = threadIdx.x & 63;
    int grp = lane >> 4;
    int l = lane & 15;
    int j0 = rowptr[node], j1 = rowptr[node + 1];
    float4 a = {0, 0, 0, 0};
    for (int j = j0 + grp; j < j1; j += 4) {
        int c = colidx[j];
        float w = wnorm[j];
        float4 v = ((const float4*)(x + (size_t)c * 64))[l];
        a.x += w * v.x; a.y += w * v.y; a.z += w * v.z; a.w += w * v.w;
    }
#pragma unroll
    for (int off = 16; off <= 32; off <<= 1) {
        a.x += __shfl_xor(a.x, off, 64);
        a.y += __shfl_xor(a.y, off, 64);
        a.z += __shfl_xor(a.z, off, 64);
        a.w += __shfl_xor(a.w, off, 64);
    }
    if (grp == 0) {
        float4 xv = ((const float4*)(x + (size_t)node * 64))[l];
        *(float4*)&XT[(size_t)node * 128 + l * 4] = xv;
        *(float4*)&XT[(size_t)node * 128 + 64 + l * 4] = a;
    }
}

// C[Nrows x Ncols] = relu?( A @ Bcat + biascat ), bf16 MFMA 64x64x32.
__global__ __launch_bounds__(256) void gemm_mfma(
    const float* __restrict__ A, int lda,
    const float* __restrict__ B0, const float* __restrict__ B1,
    const float* __restrict__ bias0, const float* __restrict__ bias1,
    float* __restrict__ C, int Nrows, int K, int Ncols, int split, int relu) {
    __shared__ short As[GBM * LDK];   // [m][k] bf16
    __shared__ short Bs[GBN * LDK];   // [n][k] bf16 (B transposed)
    const int bm = blockIdx.y * GBM, bn = blockIdx.x * GBN;
    const int tid = threadIdx.x;
    const int w = tid >> 6, l = tid & 63;
    const int wm = (w >> 1) * 32, wn = (w & 1) * 32;
    const int lr = l & 15;
    const int kg = l >> 4;
    const int arow = tid >> 2, aseg = tid & 3;
    const int bcol = tid & 63, bk2 = (tid >> 6) * 2;
    const int ldb0 = split, ldb1 = Ncols - split;

    const int arowg = bm + arow;
    const int bcolg = bn + bcol;
    const float* Bsrc = (bcolg < split) ? (B0 + bcolg)
                       : ((bcolg < Ncols) ? (B1 + (bcolg - split)) : nullptr);
    const int ldb = (bcolg < split) ? ldb0 : ldb1;

    f32x4 acc00 = {0,0,0,0}, acc01 = {0,0,0,0}, acc10 = {0,0,0,0}, acc11 = {0,0,0,0};

    for (int k0 = 0; k0 < K; k0 += GBK) {
        {
            int kk = k0 + aseg * 8;
            bf16x8 v;
            if (arowg < Nrows && kk + 7 < K) {
                float4 f0 = *(const float4*)&A[(size_t)arowg * lda + kk];
                float4 f1 = *(const float4*)&A[(size_t)arowg * lda + kk + 4];
                v[0] = f2bf(f0.x); v[1] = f2bf(f0.y); v[2] = f2bf(f0.z); v[3] = f2bf(f0.w);
                v[4] = f2bf(f1.x); v[5] = f2bf(f1.y); v[6] = f2bf(f1.z); v[7] = f2bf(f1.w);
            } else {
#pragma unroll
                for (int i = 0; i < 8; ++i)
                    v[i] = (arowg < Nrows && kk + i < K)
                         ? f2bf(A[(size_t)arowg * lda + kk + i]) : (short)0;
            }
            *(bf16x8*)&As[arow * LDK + aseg * 8] = v;
        }
#pragma unroll
        for (int q = 0; q < 4; ++q) {
            int k = q * 8 + bk2;
            unsigned pw = 0u;
            if (Bsrc) {
                float f0 = (k0 + k < K) ? Bsrc[(size_t)(k0 + k) * ldb] : 0.0f;
                float f1 = (k0 + k + 1 < K) ? Bsrc[(size_t)(k0 + k + 1) * ldb] : 0.0f;
                pw = (unsigned)(unsigned short)f2bf(f0)
                   | ((unsigned)(unsigned short)f2bf(f1) << 16);
            }
            *(unsigned*)&Bs[bcol * LDK + k] = pw;
        }
        __syncthreads();
        bf16x8 a0 = *(const bf16x8*)&As[(wm + lr) * LDK + kg * 8];
        bf16x8 a1 = *(const bf16x8*)&As[(wm + 16 + lr) * LDK + kg * 8];
        bf16x8 b0 = *(const bf16x8*)&Bs[(wn + lr) * LDK + kg * 8];
        bf16x8 b1 = *(const bf16x8*)&Bs[(wn + 16 + lr) * LDK + kg * 8];
        acc00 = __builtin_amdgcn_mfma_f32_16x16x32_bf16(a0, b0, acc00, 0, 0, 0);
        acc01 = __builtin_amdgcn_mfma_f32_16x16x32_bf16(a0, b1, acc01, 0, 0, 0);
        acc10 = __builtin_amdgcn_mfma_f32_16x16x32_bf16(a1, b0, acc10, 0, 0, 0);
        acc11 = __builtin_amdgcn_mfma_f32_16x16x32_bf16(a1, b1, acc11, 0, 0, 0);
        __syncthreads();
    }
#pragma unroll
    for (int i = 0; i < 2; ++i) {
        int rbase = bm + wm + i * 16 + kg * 4;
#pragma unroll
        for (int j = 0; j < 2; ++j) {
            int col = bn + wn + j * 16 + lr;
            if (col >= Ncols) continue;
            float bv = (col < split) ? (bias0 ? bias0[col] : 0.0f)
                                     : (bias1 ? bias1[col - split] : 0.0f);
            f32x4 a = (i == 0) ? (j == 0 ? acc00 : acc01) : (j == 0 ? acc10 : acc11);
#pragma unroll
            for (int r = 0; r < 4; ++r) {
                int row = rbase + r;
                if (row < Nrows) {
                    float o = a[r] + bv;
                    if (relu) o = fmaxf(o, 0.0f);
                    C[(size_t)row * Ncols + col] = o;
                }
            }
        }
    }
}

// pack src[:, off:off+w] (f32, stride ld) -> dst bf16 rows padded to 128 (zeros)
__global__ void pack_bf16_kernel(const float* __restrict__ src, int ld, int off, int w,
                                 ushort_t* __restrict__ dst, int n) {
    int idx = blockIdx.x * blockDim.x + threadIdx.x;
    if (idx >= n * 32) return;
    int i = idx >> 5, q = idx & 31;
    uint2 p = {0u, 0u};
    if (q * 4 < w) {
        float4 v = *(const float4*)&src[(size_t)i * ld + off + q * 4];
        p.x = (unsigned)(unsigned short)f2bf(v.x) | ((unsigned)(unsigned short)f2bf(v.y) << 16);
        p.y = (unsigned)(unsigned short)f2bf(v.z) | ((unsigned)(unsigned short)f2bf(v.w) << 16);
    }
    *(uint2*)&dst[(size_t)i * 128 + q * 4] = p;
}

// t = segsum(hWb); x1 = relu(G2[:,0:100] + t + b2) — fused epilogue.
// One wave per node, 4 edges in flight, cross-group reduce.
__global__ void segsum_combine1_kernel(const ushort_t* __restrict__ hb,
                                       const int* __restrict__ rowptr, const int* __restrict__ colidx,
                                       const float* __restrict__ wnorm,
                                       const float* __restrict__ G2, const float* __restrict__ b2,
                                       float* __restrict__ x1, int n) {
    int node = (blockIdx.x * blockDim.x + threadIdx.x) >> 6;
    if (node >= n) return;
    int lane = threadIdx.x & 63;
    int grp = lane >> 4;
    int l = lane & 15;
    int j0 = rowptr[node], j1 = rowptr[node + 1];
    float acc[8] = {};
    for (int j = j0 + grp; j < j1; j += 4) {
        int c = colidx[j];
        float w = wnorm[j];
        uint4 v = ((const uint4*)(hb + (size_t)c * 128))[l];
        acc[0] += w * bflo(v.x); acc[1] += w * bfhi(v.x);
        acc[2] += w * bflo(v.y); acc[3] += w * bfhi(v.y);
        acc[4] += w * bflo(v.z); acc[5] += w * bfhi(v.z);
        acc[6] += w * bflo(v.w); acc[7] += w * bfhi(v.w);
    }
#pragma unroll
    for (int k = 0; k < 8; ++k) {
        acc[k] += __shfl_xor(acc[k], 16, 64);
        acc[k] += __shfl_xor(acc[k], 32, 64);
    }
    if (grp == 0) {
        int f = l * 8;
        if (f < 100) {
            float4 g0 = *(const float4*)&G2[(size_t)node * 200 + f];
            float4 bv0 = *(const float4*)&b2[f];
            float4 o0;
            o0.x = fmaxf(g0.x + acc[0] + bv0.x, 0.0f);
            o0.y = fmaxf(g0.y + acc[1] + bv0.y, 0.0f);
            o0.z = fmaxf(g0.z + acc[2] + bv0.z, 0.0f);
            o0.w = fmaxf(g0.w + acc[3] + bv0.w, 0.0f);
            *(float4*)&x1[(size_t)node * 100 + f] = o0;
            if (f + 8 <= 100) {
                float4 g1 = *(const float4*)&G2[(size_t)node * 200 + f + 4];
                float4 bv1 = *(const float4*)&b2[f + 4];
                float4 o1;
                o1.x = fmaxf(g1.x + acc[4] + bv1.x, 0.0f);
                o1.y = fmaxf(g1.y + acc[5] + bv1.y, 0.0f);
                o1.z = fmaxf(g1.z + acc[6] + bv1.z, 0.0f);
                o1.w = fmaxf(g1.w + acc[7] + bv1.w, 0.0f);
                *(float4*)&x1[(size_t)node * 100 + f + 4] = o1;
            }
        }
    }
}

// xo = x1 + relu(S[:,0:100]) (f32); zf = fp8(x1 + relu(S[:,100:200]))
__global__ void combine2_kernel(const float* __restrict__ S, const float* __restrict__ x1,
                                float* __restrict__ xo, unsigned* __restrict__ zf, int n) {
    int idx = blockIdx.x * blockDim.x + threadIdx.x;
    if (idx >= n * 32) return;
    int i = idx >> 5, q = idx & 31;
    unsigned w = 0u;
    if (q < 25) {
        float4 s1 = *(const float4*)&S[(size_t)i * 200 + q * 4];
        float4 s2 = *(const float4*)&S[(size_t)i * 200 + 100 + q * 4];
        float4 xv = *(const float4*)&x1[(size_t)i * 100 + q * 4];
        float4 a, b;
        a.x = xv.x + fmaxf(s1.x, 0.0f); a.y = xv.y + fmaxf(s1.y, 0.0f);
        a.z = xv.z + fmaxf(s1.z, 0.0f); a.w = xv.w + fmaxf(s1.w, 0.0f);
        b.x = xv.x + fmaxf(s2.x, 0.0f); b.y = xv.y + fmaxf(s2.y, 0.0f);
        b.z = xv.z + fmaxf(s2.z, 0.0f); b.w = xv.w + fmaxf(s2.w, 0.0f);
        *(float4*)&xo[(size_t)i * 100 + q * 4] = a;
        w = (unsigned)__builtin_amdgcn_cvt_pk_fp8_f32(b.x, b.y, 0, false);
        w = (unsigned)__builtin_amdgcn_cvt_pk_fp8_f32(b.z, b.w, (int)w, true);
    }
    zf[(size_t)i * 32 + q] = w;
}

// fused pos/neg loss on fp8 z rows: 8 lanes/edge, uint4/lane = full 128B row.
__global__ __launch_bounds__(256) void edge_loss_fp8_kernel(
    const unsigned* __restrict__ zf, const int2* __restrict__ pp,
    const int2* __restrict__ pn, int E, float* __restrict__ accv) {
    const int y = blockIdx.y;
    const int2* __restrict__ pairs = y ? pn : pp;
    const int l = threadIdx.x & 7;
    const int g = (blockIdx.x * blockDim.x + threadIdx.x) >> 3;
    const int ng = (gridDim.x * blockDim.x) >> 3;
    float s = 0.0f;
    int niter = (g < E) ? ((E - 1 - g) / ng + 1) : 0;
    if (niter > 0) {
        int eclamp1 = (g + ng < E) ? (g + ng) : (E - 1);
        int2 p0 = pairs[g];
        int2 p1 = pairs[eclamp1];
        uint4 ra0 = *(const uint4*)&zf[(size_t)p0.x * 32 + l * 4];
        uint4 rb0 = *(const uint4*)&zf[(size_t)p0.y * 32 + l * 4];
        for (int t = 0; t < niter; ++t) {
            int e2 = g + (t + 2) * ng;
            e2 = (e2 < E) ? e2 : (E - 1);
            int2 p2 = pairs[e2];
            uint4 ra1 = *(const uint4*)&zf[(size_t)p1.x * 32 + l * 4];
            uint4 rb1 = *(const uint4*)&zf[(size_t)p1.y * 32 + l * 4];
            float dot = 0.0f;
            v2f fa, fb;
            fa = __builtin_amdgcn_cvt_pk_f32_fp8(ra0.x, false);
            fb = __builtin_amdgcn_cvt_pk_f32_fp8(rb0.x, false);
            dot += fa.x * fb.x + fa.y * fb.y;
            fa = __builtin_amdgcn_cvt_pk_f32_fp8(ra0.x, true);
            fb = __builtin_amdgcn_cvt_pk_f32_fp8(rb0.x, true);
            dot += fa.x * fb.x + fa.y * fb.y;
            fa = __builtin_amdgcn_cvt_pk_f32_fp8(ra0.y, false);
            fb = __builtin_amdgcn_cvt_pk_f32_fp8(rb0.y, false);
            dot += fa.x * fb.x + fa.y * fb.y;
            fa = __builtin_amdgcn_cvt_pk_f32_fp8(ra0.y, true);
            fb = __builtin_amdgcn_cvt_pk_f32_fp8(rb0.y, true);
            dot += fa.x * fb.x + fa.y * fb.y;
            fa = __builtin_amdgcn_cvt_pk_f32_fp8(ra0.z, false);
            fb = __builtin_amdgcn_cvt_pk_f32_fp8(rb0.z, false);
            dot += fa.x * fb.x + fa.y * fb.y;
            fa = __builtin_amdgcn_cvt_pk_f32_fp8(ra0.z, true);
            fb = __builtin_amdgcn_cvt_pk_f32_fp8(rb0.z, true);
            dot += fa.x * fb.x + fa.y * fb.y;
            fa = __builtin_amdgcn_cvt_pk_f32_fp8(ra0.w, false);
            fb = __builtin_amdgcn_cvt_pk_f32_fp8(rb0.w, false);
            dot += fa.x * fb.x + fa.y * fb.y;
            fa = __builtin_amdgcn_cvt_pk_f32_fp8(ra0.w, true);
            fb = __builtin_amdgcn_cvt_pk_f32_fp8(rb0.w, true);
            dot += fa.x * fb.x + fa.y * fb.y;
            dot += __shfl_xor(dot, 1, 8);
            dot += __shfl_xor(dot, 2, 8);
            dot += __shfl_xor(dot, 4, 8);
            if (l == 0) {
                float sg = 1.0f / (1.0f + expf(-dot));
                s += y ? logf(1.0f - sg + 1e-15f) : logf(sg + 1e-15f);
            }
            p1 = p2; ra0 = ra1; rb0 = rb1;
        }
    }
    __shared__ float red[256];
    red[threadIdx.x] = s;
    __syncthreads();
    for (int st = 128; st > 0; st >>= 1) {
        if (threadIdx.x < st) red[threadIdx.x] += red[threadIdx.x + st];
        __syncthreads();
    }
    if (threadIdx.x == 0) atomicAdd(&accv[y], red[0]);
}

// sv[i] = xo[i,:] @ w (100-dim)
__global__ void rowdot_kernel(const float* __restrict__ xo, const float* __restrict__ w,
                              float* __restrict__ s, int n) {
    int i = blockIdx.x * blockDim.x + threadIdx.x;
    if (i >= n) return;
    const float4* a = (const float4*)(xo + (size_t)i * 100);
    const float4* wv = (const float4*)w;
    float acc = 0.0f;
#pragma unroll
    for (int q = 0; q < 25; ++q) {
        float4 va = a[q], vw = wv[q];
        acc += va.x * vw.x + va.y * vw.y + va.z * vw.z + va.w * vw.w;
    }
    s[i] = acc;
}

// out[i] = xo[i,:]@W3[0] + b3 + sum_j wnorm[j]*sv[colidx[j]]
__global__ void out_kernel(const float* __restrict__ xo, const float* __restrict__ W3,
                           const float* __restrict__ b3, const int* __restrict__ rowptr,
                           const int* __restrict__ colidx, const float* __restrict__ wnorm,
                           const float* __restrict__ sv, float* __restrict__ out, int n) {
    int i = blockIdx.x * blockDim.x + threadIdx.x;
    if (i >= n) return;
    const float4* a = (const float4*)(xo + (size_t)i * 100);
    const float4* wv = (const float4*)W3;
    float acc = b3[0];
#pragma unroll
    for (int q = 0; q < 25; ++q) {
        float4 va = a[q], vw = wv[q];
        acc += va.x * vw.x + va.y * vw.y + va.z * vw.z + va.w * vw.w;
    }
    int j1 = rowptr[i + 1];
    for (int j = rowptr[i]; j < j1; ++j)
        acc += wnorm[j] * sv[colidx[j]];
    out[i] = acc;
}

__global__ void finalize_kernel(float* __restrict__ out, const float* __restrict__ acc,
                                const float* __restrict__ c1, const float* __restrict__ c2,
                                int Nn, int E) {
    out[Nn]     = -(acc[0] + acc[1]) / (float)E;
    out[Nn + 1] = c1[0];
    out[Nn + 2] = c2[0];
}

extern "C" void kernel_launch(void* const* d_in, const int* in_sizes, int n_in,
                              void* d_out, int out_size, void* d_ws, size_t ws_size,
                              hipStream_t stream) {
    (void)n_in; (void)out_size; (void)ws_size;
    const float* x   = (const float*)d_in[0];
    const int*   ei  = (const int*)d_in[1];
    const int*   nei = (const int*)d_in[2];
    const float* W1  = (const float*)d_in[3];
    const float* b1  = (const float*)d_in[4];
    const float* W2  = (const float*)d_in[5];
    const float* b2  = (const float*)d_in[6];
    const float* W3  = (const float*)d_in[7];
    const float* b3  = (const float*)d_in[8];
    const float* lw1 = (const float*)d_in[9];
    const float* lb1 = (const float*)d_in[10];
    const float* lw2 = (const float*)d_in[11];
    const float* lb2 = (const float*)d_in[12];
    const float* c1  = (const float*)d_in[13];
    const float* c2  = (const float*)d_in[14];

    const int Nn = in_sizes[0] / 64;   // 13627
    const int E  = in_sizes[1] / 2;    // 504378

    const size_t Nal = ((size_t)Nn + 5) & ~(size_t)3;   // >= N+1, mult of 4
    const size_t Eal = ((size_t)E + 3) & ~(size_t)3;

    float* ws     = (float*)d_ws;
    int*   hist   = (int*)ws;                     // 8*Nal ints (4 deg + 4 cnt)
    float* dinv   = ws + 8 * Nal;                 // Nal floats
    int*   rowptr = (int*)(dinv + Nal);           // Nal ints (N+1 used)
    float* acc    = (float*)(rowptr + Nal);       // 4 floats
    int*   cursor = (int*)(acc + 4);              // Nal ints
    int*   colidx = cursor + Nal;                 // Eal ints
    float* wnorm  = (float*)(colidx + Eal);       // Eal floats
    int2*  pp     = (int2*)(wnorm + Eal);         // Eal int2
    int2*  pn     = pp + Eal;                     // Eal int2
    float* XT     = (float*)(pn + Eal);           // N*128
    float* h      = XT + (size_t)Nn * 128;        // N*300 (alias S: N*200)
    float* G2     = h  + (size_t)Nn * 300;        // N*200
    float* x1     = G2 + (size_t)Nn * 200;        // N*100
    float* xo     = x1 + (size_t)Nn * 100;        // N*100
    size_t zoff   = (size_t)(xo + (size_t)Nn * 100 - ws);
    zoff = (zoff + 31) & ~(size_t)31;             // 128B align
    unsigned* zf  = (unsigned*)(ws + zoff);       // N*32 words (fp8 rows, 128B)
    size_t hoff   = zoff + (size_t)Nn * 32 + 63;
    hoff &= ~(size_t)63;                          // 256B align
    ushort_t* hWb = (ushort_t*)(ws + hoff);       // N*128 bf16 (256B rows)
    float* sv     = ws + hoff + (size_t)Nn * 64;  // Nal
    float* S      = h;                            // alias (h dead after conv2 gemm)

    const int MB = (Nn + GBM - 1) / GBM;

    // --- zero hist replicas + acc ---
    hipMemsetAsync(hist, 0, 8 * Nal * sizeof(int), stream);
    hipMemsetAsync(acc, 0, 4 * sizeof(float), stream);

    // --- CSR build + norm + edge-pair packing ---
    deg_hist_pairs_kernel<<<2048, 256, 0, stream>>>(ei, nei, hist, (int)Nal, pp, pn, E);
    merge_hist_kernel<<<(Nn + 255) / 256, 256, 0, stream>>>(hist, (int)Nal, dinv, rowptr, Nn);
    scan_kernel<<<1, 1024, 0, stream>>>(rowptr, cursor, Nn);
    fill_kernel<<<1024, 256, 0, stream>>>(ei, dinv, cursor, colidx, wnorm, E);

    // --- conv1: XT = [x | segsum64(x)]; h = relu(XT @ W1cat + b1) ---
    xt_kernel<<<(Nn + 3) / 4, 256, 0, stream>>>(x, rowptr, colidx, wnorm, XT, Nn);
    gemm_mfma<<<dim3(5, MB), 256, 0, stream>>>(
        XT, 128, W1, nullptr, b1, nullptr, h, Nn, 128, 300, 300, 1);

    // --- conv2 fused: G2 = h @ [W2[0] | W2[1]] ---
    gemm_mfma<<<dim3(4, MB), 256, 0, stream>>>(
        h, 300, W2, W2 + 300 * 100, nullptr, nullptr, G2, Nn, 300, 200, 100, 0);
    // hWb = bf16(G2[:,100:200]); x1 = relu(G2[:,0:100] + segsum(hWb) + b2) fused
    pack_bf16_kernel<<<(Nn * 32 + 255) / 256, 256, 0, stream>>>(G2, 200, 100, 100, hWb, Nn);
    segsum_combine1_kernel<<<(Nn + 3) / 4, 256, 0, stream>>>(hWb, rowptr, colidx, wnorm,
                                                             G2, b2, x1, Nn);

    // --- skips fused: S = x @ [lw1|lw2] + [lb1|lb2]; xo = x1+relu(S0), zf = fp8(x1+relu(S1)) ---
    gemm_mfma<<<dim3(4, MB), 256, 0, stream>>>(
        x, 64, lw1, lw2, lb1, lb2, S, Nn, 64, 200, 100, 0);
    combine2_kernel<<<(Nn * 32 + 255) / 256, 256, 0, stream>>>(S, x1, xo, zf, Nn);

    // --- edge reconstruction losses (pos: y=0, neg: y=1), fp8 z, pipelined ---
    edge_loss_fp8_kernel<<<dim3(1024, 2), 256, 0, stream>>>(zf, pp, pn, E, acc);

    // --- conv3 (width 1): sv = xo@W3[1]; out = xo@W3[0] + segsum(sv) + b3 ---
    rowdot_kernel<<<(Nn + 255) / 256, 256, 0, stream>>>(xo, W3 + 100, sv, Nn);
    out_kernel<<<(Nn + 255) / 256, 256, 0, stream>>>(xo, W3, b3, rowptr, colidx, wnorm,
                                                     sv, (float*)d_out, Nn);

    finalize_kernel<<<1, 1, 0, stream>>>((float*)d_out, acc, c1, c2, Nn, E);
}